// Round 1
// 2170.651 us; speedup vs baseline: 1.1001x; 1.1001x over previous
//
#include <hip/hip_runtime.h>
#include <hip/hip_bf16.h>
#include <math.h>

// ---------------------------------------------------------------------------
// TextTransformer forward on MI355X — Round 5: 256x256 8-phase GEMM
// (T1 XCD swizzle + T2 st_16x32 LDS swizzle + T3/T4 counted-vmcnt 8-phase +
//  T5 setprio), replacing the m97-class 128x128 GEMM.
// B=32 S=512 D=768 H=12 DH=64 FF=3072 L=4.
// ---------------------------------------------------------------------------

#define B_  32
#define S_  512
#define D_  768
#define H_  12
#define DH_ 64
#define FF_ 3072
#define L_  4
#define QKVSTR 2304

typedef __attribute__((ext_vector_type(8))) short short8;   // 8 x bf16
typedef __attribute__((ext_vector_type(4))) float f32x4;

__device__ __forceinline__ void async16(const void* g, void* l) {
    __builtin_amdgcn_global_load_lds(
        (const __attribute__((address_space(1))) void*)g,
        (__attribute__((address_space(3))) void*)l, 16, 0, 0);
}

__device__ __forceinline__ ushort f2bf(float f) {
    __hip_bfloat16 h = __float2bfloat16(f);
    return __builtin_bit_cast(ushort, h);
}

// multiply a bf16 by 0.125 exactly: exponent -= 3 (flush tiny to signed 0)
__device__ __forceinline__ short8 scale8_eighth(short8 v) {
    short8 r;
#pragma unroll
    for (int e = 0; e < 8; e++) {
        ushort u = (ushort)v[e];
        ushort ex = u & 0x7f80;
        r[e] = (short)(ex > 0x0180 ? (ushort)(u - 0x0180) : (ushort)(u & 0x8000));
    }
    return r;
}

// ----------------------------- positional encoding -------------------------
__global__ void pe_kernel(float* __restrict__ pe) {
    int idx = blockIdx.x * 256 + threadIdx.x;
    if (idx >= S_ * D_) return;
    int s = idx / D_, j = idx % D_;
    double e = (2.0 * (double)(j >> 1)) / (double)D_;
    double denom = pow(10000.0, e);
    double ang = (double)s / denom;
    pe[idx] = (j & 1) ? (float)cos(ang) : (float)sin(ang);
}

// ----------------------------- embedding + PE ------------------------------
__global__ void embed_kernel(const int* __restrict__ tokens,
                             const float* __restrict__ emb,
                             const float* __restrict__ pe,
                             float* __restrict__ x,
                             __hip_bfloat16* __restrict__ xb) {
    int row = blockIdx.x;              // b*S + s
    int s = row & (S_ - 1);
    int tok = tokens[row];
    float scale = sqrtf((float)D_);
    for (int i = threadIdx.x; i < D_; i += 256) {
        float v = emb[(size_t)tok * D_ + i] * scale + pe[s * D_ + i];
        x[(size_t)row * D_ + i] = v;
        xb[(size_t)row * D_ + i] = __float2bfloat16(v);
    }
}

// ----------------------------- batched weight transpose fp32->bf16 ---------
// out[z][c][r] = (bf16) in[z][r][c].  Grid (C/32, R/32, L).
__global__ __launch_bounds__(256) void transpose_bf16_l(
    const float* __restrict__ in, __hip_bfloat16* __restrict__ out,
    int R, int C, size_t inL, size_t outL)
{
    __shared__ float tile[32][33];
    in  += (size_t)blockIdx.z * inL;
    out += (size_t)blockIdx.z * outL;
    int tx = threadIdx.x & 31, ty = threadIdx.x >> 5;   // 32 x 8
    int c0 = blockIdx.x * 32, r0 = blockIdx.y * 32;
#pragma unroll
    for (int d = 0; d < 32; d += 8)
        tile[ty + d][tx] = in[(size_t)(r0 + ty + d) * C + c0 + tx];
    __syncthreads();
#pragma unroll
    for (int d = 0; d < 32; d += 8)
        out[(size_t)(c0 + ty + d) * R + r0 + tx] = __float2bfloat16(tile[tx][ty + d]);
}

// ----------------------------- qkv bias concat -----------------------------
__global__ void biascat(const float* __restrict__ bq, const float* __restrict__ bk,
                        const float* __restrict__ bv, float* __restrict__ o) {
    int i = blockIdx.x * 256 + threadIdx.x;          // [L_*2304)
    int ll = i / QKVSTR, j = i % QKVSTR;
    o[i] = j < 768 ? bq[ll * 768 + j]
         : j < 1536 ? bk[ll * 768 + j - 768]
                    : bv[ll * 768 + j - 1536];
}

// ----------------------------- 256x256 8-phase bf16 MFMA GEMM --------------
// C[M,N] = A[M,K] @ Bt[N,K]^T + bias[N].  M%256==0, N%256==0, K%128==0.
// 512 threads = 8 waves (2Mx4N); per-wave output 128x64; BK=64, dbuf LDS 128KB.
// st_16x32 swizzle: byte ^= ((byte>>9)&1)<<5 within each 32KB [256][64] tile,
// applied via inverse-swizzled global source (linear global_load_lds dest) +
// swizzled ds_read addresses (rule #21: both-sides-or-neither).
#define BAR()   __builtin_amdgcn_s_barrier()
#define LGKM0() asm volatile("s_waitcnt lgkmcnt(0)" ::: "memory")
#define VM4()   asm volatile("s_waitcnt vmcnt(4)" ::: "memory")

#define STAGE_A(buf, h, kt) do { \
    async16(aSrc[h][0] + (kt) * 64, &lds[(buf) * 2][dOff[h][0]]); \
    async16(aSrc[h][1] + (kt) * 64, &lds[(buf) * 2][dOff[h][1]]); } while (0)
#define STAGE_B(buf, h, kt) do { \
    async16(bSrc[h][0] + (kt) * 64, &lds[(buf) * 2 + 1][dOff[h][0]]); \
    async16(bSrc[h][1] + (kt) * 64, &lds[(buf) * 2 + 1][dOff[h][1]]); } while (0)

#define LDA(buf, m, ks) (*(const short8*)((const char*)(&lds[(buf) * 2][0]) + \
    (size_t)((arow + (m) * 16) * 128 + (ks) * 64 + cA)))
#define LDB(buf, n, ks) (*(const short8*)((const char*)(&lds[(buf) * 2 + 1][0]) + \
    (size_t)((brow + (n) * 16) * 128 + (ks) * 64 + cA)))

#define MFMA_Q(mh, nh) do { \
    __builtin_amdgcn_s_setprio(1); \
    _Pragma("unroll") \
    for (int ks_ = 0; ks_ < 2; ks_++) { \
      _Pragma("unroll") \
      for (int n_ = 0; n_ < 2; n_++) { \
        _Pragma("unroll") \
        for (int m_ = 0; m_ < 4; m_++) { \
          acc[(mh) * 4 + m_][(nh) * 2 + n_] = \
              __builtin_amdgcn_mfma_f32_16x16x32_bf16( \
                  a[m_][ks_], b[(nh) * 2 + n_][ks_], \
                  acc[(mh) * 4 + m_][(nh) * 2 + n_], 0, 0, 0); \
        } } } \
    __builtin_amdgcn_s_setprio(0); \
} while (0)

template<int RELU>
__global__ __launch_bounds__(512, 2) void gemm256(
    const ushort* __restrict__ A,   // bf16 [M][K]
    const ushort* __restrict__ Bt,  // bf16 [N][K]
    const float* __restrict__ bias, // fp32 [N]
    __hip_bfloat16* __restrict__ C, // bf16 [M][N]
    int M, int N, int K, int NX)    // NX = N/256
{
    __shared__ alignas(16) ushort lds[4][16384];  // [buf*2 + (0=A,1=B)][256*64]

    int t = threadIdx.x;
    int l = t & 63, w = t >> 6;
    int wmi = w >> 2, wni = w & 3;            // 2 x 4 wave grid
    int lm = l & 15, lo = l >> 4;

    // T1: XCD-aware block swizzle (all our grids are %8 == 0)
    int nwg = gridDim.x;
    int bid = blockIdx.x;
    int lid = (nwg & 7) ? bid : ((bid & 7) * (nwg >> 3) + (bid >> 3));
    int bn = lid % NX, bm = lid / NX;
    int row0 = bm << 8, col0 = bn << 8;

    // staging geometry: thread t stages 16B chunks; LDS dest is linear,
    // global source is inverse-swizzled (involution: ^ ((p>>9)&1)<<5).
    const ushort* aSrc[2][2];
    const ushort* bSrc[2][2];
    int dOff[2][2];
#pragma unroll
    for (int h = 0; h < 2; h++) {
#pragma unroll
        for (int c = 0; c < 2; c++) {
            int p = h * 16384 + c * 8192 + t * 16;     // byte off in 32KB tile
            int q = p ^ (((p >> 9) & 1) << 5);
            int srow = q >> 7;
            int scol = (q & 127) >> 1;
            dOff[h][c] = p >> 1;
            aSrc[h][c] = A  + (size_t)(row0 + srow) * K + scol;
            bSrc[h][c] = Bt + (size_t)(col0 + srow) * K + scol;
        }
    }

    // ds_read addressing: row bit2 comes only from lm -> lane-constant swz bit
    int arow = wmi * 128 + lm;
    int brow = wni * 64 + lm;
    int cA = (lo * 16) ^ ((lm & 4) << 3);

    f32x4 acc[8][4];
#pragma unroll
    for (int i = 0; i < 8; i++)
#pragma unroll
        for (int j = 0; j < 4; j++) acc[i][j] = (f32x4){0.f, 0.f, 0.f, 0.f};
    short8 a[4][2], b[4][2];

    const int NK = K >> 6;        // 64-wide K-tiles (even; K%128==0)
    const int NI = NK >> 1;

    // prologue: kt0 fully into buf0; kt1's B-halves into buf1 (12 loads)
    STAGE_A(0, 0, 0); STAGE_A(0, 1, 0);
    STAGE_B(0, 0, 0); STAGE_B(0, 1, 0);
    STAGE_B(1, 0, 1); STAGE_B(1, 1, 1);
    VM4();            // kt0's 8 loads landed; kt1 B (4) still in flight
    BAR();

    for (int i = 0; i < NI; i++) {
        int kt  = 2 * i;
        int ktA = (kt + 2 <= NK - 2) ? kt + 2 : NK - 2;   // clamp: last iter
        int ktB = (kt + 3 <= NK - 1) ? kt + 3 : NK - 1;   // re-stages same data

        // ---- phase 1: Q(0,0) of buf0 | stage A-half0(kt+1) -> buf1
#pragma unroll
        for (int m = 0; m < 4; m++) { a[m][0] = LDA(0, m, 0); a[m][1] = LDA(0, m, 1); }
#pragma unroll
        for (int n = 0; n < 2; n++) { b[n][0] = LDB(0, n, 0); b[n][1] = LDB(0, n, 1); }
        STAGE_A(1, 0, kt + 1);
        BAR(); LGKM0();
        MFMA_Q(0, 0);
        BAR();

        // ---- phase 2: Q(0,1) | stage A-half1(kt+1) -> buf1
#pragma unroll
        for (int n = 0; n < 2; n++) { b[2 + n][0] = LDB(0, 2 + n, 0); b[2 + n][1] = LDB(0, 2 + n, 1); }
        STAGE_A(1, 1, kt + 1);
        BAR(); LGKM0();
        MFMA_Q(0, 1);
        BAR();

        // ---- phase 3: Q(1,0) | stage B-half0(kt+2) -> buf0 (B reads done ph2)
#pragma unroll
        for (int m = 0; m < 4; m++) { a[m][0] = LDA(0, 4 + m, 0); a[m][1] = LDA(0, 4 + m, 1); }
        STAGE_B(0, 0, ktA);
        BAR(); LGKM0();
        MFMA_Q(1, 0);
        BAR();

        // ---- phase 4: Q(1,1) | stage B-half1(kt+2); gate buf1 (kt+1) ready
        STAGE_B(0, 1, ktA);
        BAR(); LGKM0();
        MFMA_Q(1, 1);
        VM4();        // all but ph3/ph4's 4 loads landed -> buf1 complete
        BAR();

        // ---- phase 5: Q(0,0) of buf1 | stage A-half0(kt+2) -> buf0
#pragma unroll
        for (int m = 0; m < 4; m++) { a[m][0] = LDA(1, m, 0); a[m][1] = LDA(1, m, 1); }
#pragma unroll
        for (int n = 0; n < 2; n++) { b[n][0] = LDB(1, n, 0); b[n][1] = LDB(1, n, 1); }
        STAGE_A(0, 0, ktA);
        BAR(); LGKM0();
        MFMA_Q(0, 0);
        BAR();

        // ---- phase 6: Q(0,1) | stage A-half1(kt+2) -> buf0
#pragma unroll
        for (int n = 0; n < 2; n++) { b[2 + n][0] = LDB(1, 2 + n, 0); b[2 + n][1] = LDB(1, 2 + n, 1); }
        STAGE_A(0, 1, ktA);
        BAR(); LGKM0();
        MFMA_Q(0, 1);
        BAR();

        // ---- phase 7: Q(1,0) | stage B-half0(kt+3) -> buf1 (B reads done ph6)
#pragma unroll
        for (int m = 0; m < 4; m++) { a[m][0] = LDA(1, 4 + m, 0); a[m][1] = LDA(1, 4 + m, 1); }
        STAGE_B(1, 0, ktB);
        BAR(); LGKM0();
        MFMA_Q(1, 0);
        BAR();

        // ---- phase 8: Q(1,1) | stage B-half1(kt+3); gate buf0 (kt+2) ready
        STAGE_B(1, 1, ktB);
        BAR(); LGKM0();
        MFMA_Q(1, 1);
        VM4();        // all but ph7/ph8's 4 loads landed -> buf0 complete
        BAR();
    }

    // epilogue: bias + optional relu, bf16 out
    int crow = row0 + wmi * 128;
    int ccol = col0 + wni * 64;
#pragma unroll
    for (int n = 0; n < 4; n++) {
        int c = ccol + n * 16 + lm;
        float bs = bias[c];
#pragma unroll
        for (int m = 0; m < 8; m++) {
#pragma unroll
            for (int r = 0; r < 4; r++) {
                float v = acc[m][n][r] + bs;
                if (RELU) v = fmaxf(v, 0.f);
                C[(size_t)(crow + m * 16 + lo * 4 + r) * N + c] = __float2bfloat16(v);
            }
        }
    }
    (void)M;
}

// ----------------------------- MFMA flash attention ------------------------
// Block: (qt of 128 rows, h, b); 4 waves; wave w owns q-rows wm=w*32..+32.
// qkv is the fused [B*S][2304] buffer: q at col 0, k at 768, v at 1536.
// sP aliases sQ (Q is register-resident after the prologue). LDS ~36.9 KB.
#define PSTR 72
__global__ __launch_bounds__(256) void attn_mfma(
    const ushort* __restrict__ qkv,
    __hip_bfloat16* __restrict__ av)
{
    __shared__ alignas(16) ushort sQP[128 * PSTR];   // Q tile, then P (per-wave)
    __shared__ alignas(16) ushort sK[64 * PSTR];
    __shared__ alignas(16) ushort sVt[64 * PSTR];    // Vt[d][s]

    int t = threadIdx.x;
    int qt = blockIdx.x, h = blockIdx.y, b = blockIdx.z;
    int w = t >> 6, l = t & 63;
    int lm = l & 15, lq = l >> 4;
    int wm = w * 32;

    const ushort* qbase = qkv + (size_t)(b * S_ + qt * 128) * QKVSTR + h * DH_;
    const ushort* kbase = qkv + (size_t)b * S_ * QKVSTR + 768 + h * DH_;
    const ushort* vbase = qkv + (size_t)b * S_ * QKVSTR + 1536 + h * DH_;

    // stage Q tile [128][64]
    {
        int r = t >> 1, c0 = (t & 1) * 32;
        const ushort* src = qbase + (size_t)r * QKVSTR + c0;
        ushort* dst = &sQP[r * PSTR + c0];
        *(uint4*)(dst + 0)  = *(const uint4*)(src + 0);
        *(uint4*)(dst + 8)  = *(const uint4*)(src + 8);
        *(uint4*)(dst + 16) = *(const uint4*)(src + 16);
        *(uint4*)(dst + 24) = *(const uint4*)(src + 24);
    }
    __syncthreads();
    short8 qf[2][2];
#pragma unroll
    for (int i = 0; i < 2; i++)
#pragma unroll
        for (int ks = 0; ks < 2; ks++)
            qf[i][ks] = scale8_eighth(
                *(const short8*)&sQP[(wm + i * 16 + lm) * PSTR + ks * 32 + lq * 8]);

    ushort* sPw = &sQP[(size_t)wm * PSTR];           // wave-local P region

    f32x4 accO[2][4];
    float mrun[2][4], lrun[2][4];
#pragma unroll
    for (int i = 0; i < 2; i++)
#pragma unroll
        for (int j = 0; j < 4; j++) accO[i][j] = (f32x4){0.f, 0.f, 0.f, 0.f};
#pragma unroll
    for (int i = 0; i < 2; i++)
#pragma unroll
        for (int r = 0; r < 4; r++) { mrun[i][r] = -1e30f; lrun[i][r] = 0.f; }

    for (int kt = 0; kt < S_ / 64; kt++) {
        __syncthreads();   // prior reads of sK/sVt done; first iter: qf loads done
        {
            int r = t >> 2, c0 = (t & 3) * 16;
            const ushort* ksrc = kbase + (size_t)(kt * 64 + r) * QKVSTR + c0;
            ushort* kdst = &sK[r * PSTR + c0];
            *(uint4*)(kdst + 0) = *(const uint4*)(ksrc + 0);
            *(uint4*)(kdst + 8) = *(const uint4*)(ksrc + 8);
            const ushort* vsrc = vbase + (size_t)(kt * 64 + r) * QKVSTR + c0;
            ushort vv[16];
            *(uint4*)&vv[0] = *(const uint4*)(vsrc + 0);
            *(uint4*)&vv[8] = *(const uint4*)(vsrc + 8);
#pragma unroll
            for (int j = 0; j < 16; j++) sVt[(c0 + j) * PSTR + r] = vv[j];
        }
        __syncthreads();

        // S = (Q/8) K^T
        f32x4 accS[2][4];
#pragma unroll
        for (int i = 0; i < 2; i++)
#pragma unroll
            for (int j = 0; j < 4; j++) accS[i][j] = (f32x4){0.f, 0.f, 0.f, 0.f};
#pragma unroll
        for (int ks = 0; ks < 2; ks++) {
#pragma unroll
            for (int j = 0; j < 4; j++) {
                short8 kf = *(const short8*)&sK[(j * 16 + lm) * PSTR + ks * 32 + lq * 8];
#pragma unroll
                for (int i = 0; i < 2; i++)
                    accS[i][j] = __builtin_amdgcn_mfma_f32_16x16x32_bf16(
                        qf[i][ks], kf, accS[i][j], 0, 0, 0);
            }
        }

        // online softmax
        float rmax[2][4];
#pragma unroll
        for (int i = 0; i < 2; i++)
#pragma unroll
            for (int r = 0; r < 4; r++)
                rmax[i][r] = fmaxf(fmaxf(accS[i][0][r], accS[i][1][r]),
                                   fmaxf(accS[i][2][r], accS[i][3][r]));
#pragma unroll
        for (int d = 1; d < 16; d <<= 1)
#pragma unroll
            for (int i = 0; i < 2; i++)
#pragma unroll
                for (int r = 0; r < 4; r++)
                    rmax[i][r] = fmaxf(rmax[i][r], __shfl_xor(rmax[i][r], d));

        float alpha[2][4];
#pragma unroll
        for (int i = 0; i < 2; i++)
#pragma unroll
            for (int r = 0; r < 4; r++) {
                float mn = fmaxf(mrun[i][r], rmax[i][r]);
                alpha[i][r] = __expf(mrun[i][r] - mn);
                mrun[i][r] = mn;
            }
        float rsum[2][4];
#pragma unroll
        for (int i = 0; i < 2; i++)
#pragma unroll
            for (int r = 0; r < 4; r++) rsum[i][r] = 0.f;
#pragma unroll
        for (int i = 0; i < 2; i++)
#pragma unroll
            for (int j = 0; j < 4; j++)
#pragma unroll
                for (int r = 0; r < 4; r++) {
                    float p = __expf(accS[i][j][r] - mrun[i][r]);
                    accS[i][j][r] = p;
                    rsum[i][r] += p;
                }
#pragma unroll
        for (int d = 1; d < 16; d <<= 1)
#pragma unroll
            for (int i = 0; i < 2; i++)
#pragma unroll
                for (int r = 0; r < 4; r++)
                    rsum[i][r] += __shfl_xor(rsum[i][r], d);
#pragma unroll
        for (int i = 0; i < 2; i++)
#pragma unroll
            for (int r = 0; r < 4; r++)
                lrun[i][r] = lrun[i][r] * alpha[i][r] + rsum[i][r];

        // rescale O
#pragma unroll
        for (int i = 0; i < 2; i++)
#pragma unroll
            for (int j = 0; j < 4; j++)
#pragma unroll
                for (int r = 0; r < 4; r++) accO[i][j][r] *= alpha[i][r];

        // P -> wave-local LDS (C-layout -> A-layout round trip; no barrier)
#pragma unroll
        for (int i = 0; i < 2; i++)
#pragma unroll
            for (int j = 0; j < 4; j++)
#pragma unroll
                for (int r = 0; r < 4; r++)
                    sPw[(i * 16 + lq * 4 + r) * PSTR + j * 16 + lm] =
                        f2bf(accS[i][j][r]);

        // O += P V   (B-frags from Vt[d][s])
#pragma unroll
        for (int ks = 0; ks < 2; ks++) {
            short8 pf[2];
#pragma unroll
            for (int i = 0; i < 2; i++)
                pf[i] = *(const short8*)&sPw[(i * 16 + lm) * PSTR + ks * 32 + lq * 8];
#pragma unroll
            for (int j = 0; j < 4; j++) {
                short8 vf = *(const short8*)&sVt[(j * 16 + lm) * PSTR + ks * 32 + lq * 8];
#pragma unroll
                for (int i = 0; i < 2; i++)
                    accO[i][j] = __builtin_amdgcn_mfma_f32_16x16x32_bf16(
                        pf[i], vf, accO[i][j], 0, 0, 0);
            }
        }
    }

    // epilogue
    float invl[2][4];
#pragma unroll
    for (int i = 0; i < 2; i++)
#pragma unroll
        for (int r = 0; r < 4; r++) invl[i][r] = 1.0f / lrun[i][r];
#pragma unroll
    for (int i = 0; i < 2; i++)
#pragma unroll
        for (int j = 0; j < 4; j++)
#pragma unroll
            for (int r = 0; r < 4; r++) {
                int row = qt * 128 + wm + i * 16 + lq * 4 + r;
                int col = h * DH_ + j * 16 + lm;
                av[(size_t)(b * S_ + row) * D_ + col] =
                    __float2bfloat16(accO[i][j][r] * invl[i][r]);
            }
}

// ----------------------------- residual + layernorm ------------------------
__global__ __launch_bounds__(256) void add_ln(float* __restrict__ x,
    __hip_bfloat16* __restrict__ xb,
    const __hip_bfloat16* __restrict__ r, const float* __restrict__ g,
    const float* __restrict__ bta)
{
    __shared__ float sred[256];
    int row = blockIdx.x, t = threadIdx.x;
    size_t base = (size_t)row * D_;
    float v0 = x[base + t]       + __bfloat162float(r[base + t]);
    float v1 = x[base + t + 256] + __bfloat162float(r[base + t + 256]);
    float v2 = x[base + t + 512] + __bfloat162float(r[base + t + 512]);
    sred[t] = v0 + v1 + v2;
    __syncthreads();
    for (int o = 128; o > 0; o >>= 1) { if (t < o) sred[t] += sred[t + o]; __syncthreads(); }
    float mean = sred[0] * (1.0f / D_);
    __syncthreads();
    float d0 = v0 - mean, d1 = v1 - mean, d2 = v2 - mean;
    sred[t] = d0 * d0 + d1 * d1 + d2 * d2;
    __syncthreads();
    for (int o = 128; o > 0; o >>= 1) { if (t < o) sred[t] += sred[t + o]; __syncthreads(); }
    float rstd = rsqrtf(sred[0] * (1.0f / D_) + 1e-6f);
    float o0 = g[t]       * d0 * rstd + bta[t];
    float o1 = g[t + 256] * d1 * rstd + bta[t + 256];
    float o2 = g[t + 512] * d2 * rstd + bta[t + 512];
    x[base + t]       = o0;
    x[base + t + 256] = o1;
    x[base + t + 512] = o2;
    xb[base + t]       = __float2bfloat16(o0);
    xb[base + t + 256] = __float2bfloat16(o1);
    xb[base + t + 512] = __float2bfloat16(o2);
}

// ----------------------------- mean pool over S ----------------------------
__global__ void pool_kernel(const float* __restrict__ x, float* __restrict__ pooled) {
    int idx = blockIdx.x * 256 + threadIdx.x;   // b*768 + d
    int b = idx / D_, d = idx % D_;
    float acc = 0.f;
    const float* p = x + (size_t)b * S_ * D_ + d;
    for (int s = 0; s < S_; s++) acc += p[(size_t)s * D_];
    pooled[idx] = acc * (1.0f / S_);
}

// ----------------------------- classifier head -----------------------------
__global__ void head_kernel(const float* __restrict__ pooled,
                            const float* __restrict__ wl,
                            const float* __restrict__ bl,
                            const float* __restrict__ wout,
                            const float* __restrict__ bout,
                            float* __restrict__ out)
{
    __shared__ float hb[32];
    int b = blockIdx.x, t = threadIdx.x;
    if (t < 32) {
        float z = bl[t];
        for (int d = 0; d < D_; d++) z += pooled[b * D_ + d] * wl[d * 32 + t];
        hb[t] = 0.5f * z * (1.0f + erff(z * 0.70710678118654752f));
    }
    __syncthreads();
    if (t == 0) {
        float z = bout[0];
        for (int j = 0; j < 32; j++) z += hb[j] * wout[j];
        out[b] = 1.0f / (1.0f + expf(-z));
    }
}

// ---------------------------------------------------------------------------
extern "C" void kernel_launch(void* const* d_in, const int* in_sizes, int n_in,
                              void* d_out, int out_size, void* d_ws, size_t ws_size,
                              hipStream_t stream)
{
    (void)in_sizes; (void)n_in; (void)out_size; (void)ws_size;
    const int*   tokens = (const int*)  d_in[0];
    const float* emb    = (const float*)d_in[1];
    const float* wq     = (const float*)d_in[2];
    const float* bq     = (const float*)d_in[3];
    const float* wk     = (const float*)d_in[4];
    const float* bk     = (const float*)d_in[5];
    const float* wv     = (const float*)d_in[6];
    const float* bv     = (const float*)d_in[7];
    const float* wo     = (const float*)d_in[8];
    const float* bo     = (const float*)d_in[9];
    const float* w1     = (const float*)d_in[10];
    const float* b1     = (const float*)d_in[11];
    const float* w2     = (const float*)d_in[12];
    const float* b2     = (const float*)d_in[13];
    const float* ln1g   = (const float*)d_in[14];
    const float* ln1b   = (const float*)d_in[15];
    const float* ln2g   = (const float*)d_in[16];
    const float* ln2b   = (const float*)d_in[17];
    const float* wl     = (const float*)d_in[18];
    const float* bl     = (const float*)d_in[19];
    const float* wout   = (const float*)d_in[20];
    const float* bout   = (const float*)d_in[21];
    float* out = (float*)d_out;

    char* ws = (char*)d_ws;
    size_t off = 0;
    auto alloc = [&](size_t n) -> void* {
        char* p = ws + off;
        off = (off + n + 255) & ~(size_t)255;
        return (void*)p;
    };
    const size_t XBYTES = (size_t)B_ * S_ * D_ * 4;        // 50.33 MB
    const size_t XBF    = XBYTES / 2;                      // 25.17 MB
    float*          pe     = (float*)alloc((size_t)S_ * D_ * 4);
    float*          x      = (float*)alloc(XBYTES);
    __hip_bfloat16* xb     = (__hip_bfloat16*)alloc(XBF);
    __hip_bfloat16* r_bf   = (__hip_bfloat16*)alloc(XBF);  // residual branch
    char*           arena  = (char*)alloc(4 * XBF);        // 100.66 MB
    __hip_bfloat16* qkv_bf = (__hip_bfloat16*)arena;       // [M][2304]
    __hip_bfloat16* av_bf  = (__hip_bfloat16*)(arena + 3 * XBF);
    __hip_bfloat16* h_bf   = (__hip_bfloat16*)arena;       // [M][3072] aliases qkv+av
    __hip_bfloat16* wT     = (__hip_bfloat16*)alloc((size_t)L_ * 7077888 * 2);
    float*          qkvbias= (float*)alloc((size_t)L_ * QKVSTR * 4);
    float*          pooled = (float*)alloc((size_t)B_ * D_ * 4);
    // total ~260 MB

    const int M = B_ * S_;                                 // 16384
    const size_t DD = (size_t)D_ * D_;
    const size_t DF = (size_t)D_ * FF_;
    const size_t LSTRIDE = 4 * DD + 2 * DF;

    // weights: per layer [qkvT(3*DD) | woT(DD) | w1T(DF) | w2T(DF)]
    transpose_bf16_l<<<dim3(D_ / 32, D_ / 32, L_), 256, 0, stream>>>(
        wq, wT + 0 * DD, D_, D_, DD, LSTRIDE);
    transpose_bf16_l<<<dim3(D_ / 32, D_ / 32, L_), 256, 0, stream>>>(
        wk, wT + 1 * DD, D_, D_, DD, LSTRIDE);
    transpose_bf16_l<<<dim3(D_ / 32, D_ / 32, L_), 256, 0, stream>>>(
        wv, wT + 2 * DD, D_, D_, DD, LSTRIDE);
    transpose_bf16_l<<<dim3(D_ / 32, D_ / 32, L_), 256, 0, stream>>>(
        wo, wT + 3 * DD, D_, D_, DD, LSTRIDE);
    transpose_bf16_l<<<dim3(FF_ / 32, D_ / 32, L_), 256, 0, stream>>>(
        w1, wT + 4 * DD, D_, FF_, DF, LSTRIDE);
    transpose_bf16_l<<<dim3(D_ / 32, FF_ / 32, L_), 256, 0, stream>>>(
        w2, wT + 4 * DD + DF, FF_, D_, DF, LSTRIDE);
    biascat<<<(L_ * QKVSTR) / 256, 256, 0, stream>>>(bq, bk, bv, qkvbias);

    pe_kernel<<<(S_ * D_ + 255) / 256, 256, 0, stream>>>(pe);
    embed_kernel<<<M, 256, 0, stream>>>(tokens, emb, pe, x, xb);

    for (int l = 0; l < L_; l++) {
        __hip_bfloat16* wl_base = wT + (size_t)l * LSTRIDE;
        const ushort* qkvT = (const ushort*)(wl_base + 0 * DD);
        const ushort* woT  = (const ushort*)(wl_base + 3 * DD);
        const ushort* w1T  = (const ushort*)(wl_base + 4 * DD);
        const ushort* w2T  = (const ushort*)(wl_base + 4 * DD + DF);

        gemm256<0><<<dim3((QKVSTR / 256) * (M / 256)), 512, 0, stream>>>(
            (const ushort*)xb, qkvT, qkvbias + (size_t)l * QKVSTR, qkv_bf,
            M, QKVSTR, D_, QKVSTR / 256);

        attn_mfma<<<dim3(S_ / 128, H_, B_), 256, 0, stream>>>(
            (const ushort*)qkv_bf, av_bf);

        gemm256<0><<<dim3((D_ / 256) * (M / 256)), 512, 0, stream>>>(
            (const ushort*)av_bf, woT, bo + l * D_, r_bf, M, D_, D_, D_ / 256);
        add_ln<<<M, 256, 0, stream>>>(x, xb, r_bf, ln1g + l * D_, ln1b + l * D_);

        gemm256<1><<<dim3((FF_ / 256) * (M / 256)), 512, 0, stream>>>(
            (const ushort*)xb, w1T, b1 + l * FF_, h_bf, M, FF_, D_, FF_ / 256);
        gemm256<0><<<dim3((D_ / 256) * (M / 256)), 512, 0, stream>>>(
            (const ushort*)h_bf, w2T, b2 + l * D_, r_bf, M, D_, FF_, D_ / 256);
        add_ln<<<M, 256, 0, stream>>>(x, xb, r_bf, ln2g + l * D_, ln2b + l * D_);
    }

    pool_kernel<<<(B_ * D_) / 256, 256, 0, stream>>>(x, pooled);
    head_kernel<<<B_, 64, 0, stream>>>(pooled, wl, bl, wout, bout, out);
}

// Round 2
// 2073.098 us; speedup vs baseline: 1.1518x; 1.0471x over previous
//
#include <hip/hip_runtime.h>
#include <hip/hip_bf16.h>
#include <math.h>

// ---------------------------------------------------------------------------
// TextTransformer forward on MI355X — Round 6: fix T2 swizzle to 3-bit
// (row&7)<<4 involution (G4-verified geometry for 128B-row ds_read_b128).
// 256x256 8-phase GEMM (T1 XCD swizzle + T3/T4 counted vmcnt + T5 setprio).
// B=32 S=512 D=768 H=12 DH=64 FF=3072 L=4.
// ---------------------------------------------------------------------------

#define B_  32
#define S_  512
#define D_  768
#define H_  12
#define DH_ 64
#define FF_ 3072
#define L_  4
#define QKVSTR 2304

typedef __attribute__((ext_vector_type(8))) short short8;   // 8 x bf16
typedef __attribute__((ext_vector_type(4))) float f32x4;

__device__ __forceinline__ void async16(const void* g, void* l) {
    __builtin_amdgcn_global_load_lds(
        (const __attribute__((address_space(1))) void*)g,
        (__attribute__((address_space(3))) void*)l, 16, 0, 0);
}

__device__ __forceinline__ ushort f2bf(float f) {
    __hip_bfloat16 h = __float2bfloat16(f);
    return __builtin_bit_cast(ushort, h);
}

// multiply a bf16 by 0.125 exactly: exponent -= 3 (flush tiny to signed 0)
__device__ __forceinline__ short8 scale8_eighth(short8 v) {
    short8 r;
#pragma unroll
    for (int e = 0; e < 8; e++) {
        ushort u = (ushort)v[e];
        ushort ex = u & 0x7f80;
        r[e] = (short)(ex > 0x0180 ? (ushort)(u - 0x0180) : (ushort)(u & 0x8000));
    }
    return r;
}

// ----------------------------- positional encoding -------------------------
__global__ void pe_kernel(float* __restrict__ pe) {
    int idx = blockIdx.x * 256 + threadIdx.x;
    if (idx >= S_ * D_) return;
    int s = idx / D_, j = idx % D_;
    double e = (2.0 * (double)(j >> 1)) / (double)D_;
    double denom = pow(10000.0, e);
    double ang = (double)s / denom;
    pe[idx] = (j & 1) ? (float)cos(ang) : (float)sin(ang);
}

// ----------------------------- embedding + PE ------------------------------
__global__ void embed_kernel(const int* __restrict__ tokens,
                             const float* __restrict__ emb,
                             const float* __restrict__ pe,
                             float* __restrict__ x,
                             __hip_bfloat16* __restrict__ xb) {
    int row = blockIdx.x;              // b*S + s
    int s = row & (S_ - 1);
    int tok = tokens[row];
    float scale = sqrtf((float)D_);
    for (int i = threadIdx.x; i < D_; i += 256) {
        float v = emb[(size_t)tok * D_ + i] * scale + pe[s * D_ + i];
        x[(size_t)row * D_ + i] = v;
        xb[(size_t)row * D_ + i] = __float2bfloat16(v);
    }
}

// ----------------------------- batched weight transpose fp32->bf16 ---------
// out[z][c][r] = (bf16) in[z][r][c].  Grid (C/32, R/32, L).
__global__ __launch_bounds__(256) void transpose_bf16_l(
    const float* __restrict__ in, __hip_bfloat16* __restrict__ out,
    int R, int C, size_t inL, size_t outL)
{
    __shared__ float tile[32][33];
    in  += (size_t)blockIdx.z * inL;
    out += (size_t)blockIdx.z * outL;
    int tx = threadIdx.x & 31, ty = threadIdx.x >> 5;   // 32 x 8
    int c0 = blockIdx.x * 32, r0 = blockIdx.y * 32;
#pragma unroll
    for (int d = 0; d < 32; d += 8)
        tile[ty + d][tx] = in[(size_t)(r0 + ty + d) * C + c0 + tx];
    __syncthreads();
#pragma unroll
    for (int d = 0; d < 32; d += 8)
        out[(size_t)(c0 + ty + d) * R + r0 + tx] = __float2bfloat16(tile[tx][ty + d]);
}

// ----------------------------- qkv bias concat -----------------------------
__global__ void biascat(const float* __restrict__ bq, const float* __restrict__ bk,
                        const float* __restrict__ bv, float* __restrict__ o) {
    int i = blockIdx.x * 256 + threadIdx.x;          // [L_*2304)
    int ll = i / QKVSTR, j = i % QKVSTR;
    o[i] = j < 768 ? bq[ll * 768 + j]
         : j < 1536 ? bk[ll * 768 + j - 768]
                    : bv[ll * 768 + j - 1536];
}

// ----------------------------- 256x256 8-phase bf16 MFMA GEMM --------------
// C[M,N] = A[M,K] @ Bt[N,K]^T + bias[N].  M%256==0, N%256==0, K%128==0.
// 512 threads = 8 waves (2Mx4N); per-wave output 128x64; BK=64, dbuf LDS 128KB.
// T2 swizzle (3-bit, G4 geometry): within each 128B LDS row,
//   byte_col ^= ((row&7)<<4)  — involution, applied via inverse-swizzled
// global SOURCE (LDS dest stays linear for global_load_lds) + swizzled
// ds_read columns (rule #21: both-sides-or-neither).
// Fragment read slot = (ks*4+lo) ^ (lm&7): all 8 16B-slots balanced
// -> 2 lanes/bank/cycle = conflict-free minimum (m136).
#define BAR()   __builtin_amdgcn_s_barrier()
#define LGKM0() asm volatile("s_waitcnt lgkmcnt(0)" ::: "memory")
#define VM4()   asm volatile("s_waitcnt vmcnt(4)" ::: "memory")

#define STAGE_A(buf, h, kt) do { \
    async16(aSrc[h][0] + (kt) * 64, &lds[(buf) * 2][dOff[h][0]]); \
    async16(aSrc[h][1] + (kt) * 64, &lds[(buf) * 2][dOff[h][1]]); } while (0)
#define STAGE_B(buf, h, kt) do { \
    async16(bSrc[h][0] + (kt) * 64, &lds[(buf) * 2 + 1][dOff[h][0]]); \
    async16(bSrc[h][1] + (kt) * 64, &lds[(buf) * 2 + 1][dOff[h][1]]); } while (0)

#define LDA(buf, m, ks) (*(const short8*)((const char*)(&lds[(buf) * 2][0]) + \
    (size_t)((arow + (m) * 16) * 128 + cswz[ks])))
#define LDB(buf, n, ks) (*(const short8*)((const char*)(&lds[(buf) * 2 + 1][0]) + \
    (size_t)((brow + (n) * 16) * 128 + cswz[ks])))

#define MFMA_Q(mh, nh) do { \
    __builtin_amdgcn_s_setprio(1); \
    _Pragma("unroll") \
    for (int ks_ = 0; ks_ < 2; ks_++) { \
      _Pragma("unroll") \
      for (int n_ = 0; n_ < 2; n_++) { \
        _Pragma("unroll") \
        for (int m_ = 0; m_ < 4; m_++) { \
          acc[(mh) * 4 + m_][(nh) * 2 + n_] = \
              __builtin_amdgcn_mfma_f32_16x16x32_bf16( \
                  a[m_][ks_], b[(nh) * 2 + n_][ks_], \
                  acc[(mh) * 4 + m_][(nh) * 2 + n_], 0, 0, 0); \
        } } } \
    __builtin_amdgcn_s_setprio(0); \
} while (0)

template<int RELU>
__global__ __launch_bounds__(512, 2) void gemm256(
    const ushort* __restrict__ A,   // bf16 [M][K]
    const ushort* __restrict__ Bt,  // bf16 [N][K]
    const float* __restrict__ bias, // fp32 [N]
    __hip_bfloat16* __restrict__ C, // bf16 [M][N]
    int M, int N, int K, int NX)    // NX = N/256
{
    __shared__ alignas(16) ushort lds[4][16384];  // [buf*2 + (0=A,1=B)][256*64]

    int t = threadIdx.x;
    int l = t & 63, w = t >> 6;
    int wmi = w >> 2, wni = w & 3;            // 2 x 4 wave grid
    int lm = l & 15, lo = l >> 4;

    // T1: XCD-aware block swizzle (all our grids are %8 == 0)
    int nwg = gridDim.x;
    int bid = blockIdx.x;
    int lid = (nwg & 7) ? bid : ((bid & 7) * (nwg >> 3) + (bid >> 3));
    int bn = lid % NX, bm = lid / NX;
    int row0 = bm << 8, col0 = bn << 8;

    // staging geometry: thread t stages 16B chunks; LDS dest is linear,
    // global source column is inverse-swizzled: col ^= ((row&7)<<4).
    const ushort* aSrc[2][2];
    const ushort* bSrc[2][2];
    int dOff[2][2];
#pragma unroll
    for (int h = 0; h < 2; h++) {
#pragma unroll
        for (int c = 0; c < 2; c++) {
            int p = h * 16384 + c * 8192 + t * 16;     // byte off in 32KB tile
            int prow = p >> 7;                         // tile row (0..255)
            int scolb = (p & 127) ^ ((prow & 7) << 4); // inverse-swz byte col
            dOff[h][c] = p >> 1;
            aSrc[h][c] = A  + (size_t)(row0 + prow) * K + (scolb >> 1);
            bSrc[h][c] = Bt + (size_t)(col0 + prow) * K + (scolb >> 1);
        }
    }

    // ds_read addressing: fragment rows are ...+lm (mod 16), so row&7 = lm&7
    // is lane-constant; precompute swizzled byte col per ks half.
    int arow = wmi * 128 + lm;
    int brow = wni * 64 + lm;
    int swz = (lm & 7) << 4;
    int cswz[2];
    cswz[0] = (lo * 16) ^ swz;
    cswz[1] = (64 + lo * 16) ^ swz;

    f32x4 acc[8][4];
#pragma unroll
    for (int i = 0; i < 8; i++)
#pragma unroll
        for (int j = 0; j < 4; j++) acc[i][j] = (f32x4){0.f, 0.f, 0.f, 0.f};
    short8 a[4][2], b[4][2];

    const int NK = K >> 6;        // 64-wide K-tiles (even; K%128==0)
    const int NI = NK >> 1;

    // prologue: kt0 fully into buf0; kt1's B-halves into buf1 (12 loads)
    STAGE_A(0, 0, 0); STAGE_A(0, 1, 0);
    STAGE_B(0, 0, 0); STAGE_B(0, 1, 0);
    STAGE_B(1, 0, 1); STAGE_B(1, 1, 1);
    VM4();            // kt0's 8 loads landed; kt1 B (4) still in flight
    BAR();

    for (int i = 0; i < NI; i++) {
        int kt  = 2 * i;
        int ktA = (kt + 2 <= NK - 2) ? kt + 2 : NK - 2;   // clamp: last iter
        int ktB = (kt + 3 <= NK - 1) ? kt + 3 : NK - 1;   // re-stages same data

        // ---- phase 1: Q(0,0) of buf0 | stage A-half0(kt+1) -> buf1
#pragma unroll
        for (int m = 0; m < 4; m++) { a[m][0] = LDA(0, m, 0); a[m][1] = LDA(0, m, 1); }
#pragma unroll
        for (int n = 0; n < 2; n++) { b[n][0] = LDB(0, n, 0); b[n][1] = LDB(0, n, 1); }
        STAGE_A(1, 0, kt + 1);
        BAR(); LGKM0();
        MFMA_Q(0, 0);
        BAR();

        // ---- phase 2: Q(0,1) | stage A-half1(kt+1) -> buf1
#pragma unroll
        for (int n = 0; n < 2; n++) { b[2 + n][0] = LDB(0, 2 + n, 0); b[2 + n][1] = LDB(0, 2 + n, 1); }
        STAGE_A(1, 1, kt + 1);
        BAR(); LGKM0();
        MFMA_Q(0, 1);
        BAR();

        // ---- phase 3: Q(1,0) | stage B-half0(kt+2) -> buf0 (B reads done ph2)
#pragma unroll
        for (int m = 0; m < 4; m++) { a[m][0] = LDA(0, 4 + m, 0); a[m][1] = LDA(0, 4 + m, 1); }
        STAGE_B(0, 0, ktA);
        BAR(); LGKM0();
        MFMA_Q(1, 0);
        BAR();

        // ---- phase 4: Q(1,1) | stage B-half1(kt+2); gate buf1 (kt+1) ready
        STAGE_B(0, 1, ktA);
        BAR(); LGKM0();
        MFMA_Q(1, 1);
        VM4();        // all but ph3/ph4's 4 loads landed -> buf1 complete
        BAR();

        // ---- phase 5: Q(0,0) of buf1 | stage A-half0(kt+2) -> buf0
#pragma unroll
        for (int m = 0; m < 4; m++) { a[m][0] = LDA(1, m, 0); a[m][1] = LDA(1, m, 1); }
#pragma unroll
        for (int n = 0; n < 2; n++) { b[n][0] = LDB(1, n, 0); b[n][1] = LDB(1, n, 1); }
        STAGE_A(0, 0, ktA);
        BAR(); LGKM0();
        MFMA_Q(0, 0);
        BAR();

        // ---- phase 6: Q(0,1) | stage A-half1(kt+2) -> buf0
#pragma unroll
        for (int n = 0; n < 2; n++) { b[2 + n][0] = LDB(1, 2 + n, 0); b[2 + n][1] = LDB(1, 2 + n, 1); }
        STAGE_A(0, 1, ktA);
        BAR(); LGKM0();
        MFMA_Q(0, 1);
        BAR();

        // ---- phase 7: Q(1,0) | stage B-half0(kt+3) -> buf1 (B reads done ph6)
#pragma unroll
        for (int m = 0; m < 4; m++) { a[m][0] = LDA(1, 4 + m, 0); a[m][1] = LDA(1, 4 + m, 1); }
        STAGE_B(1, 0, ktB);
        BAR(); LGKM0();
        MFMA_Q(1, 0);
        BAR();

        // ---- phase 8: Q(1,1) | stage B-half1(kt+3); gate buf0 (kt+2) ready
        STAGE_B(1, 1, ktB);
        BAR(); LGKM0();
        MFMA_Q(1, 1);
        VM4();        // all but ph7/ph8's 4 loads landed -> buf0 complete
        BAR();
    }

    // epilogue: bias + optional relu, bf16 out
    int crow = row0 + wmi * 128;
    int ccol = col0 + wni * 64;
#pragma unroll
    for (int n = 0; n < 4; n++) {
        int c = ccol + n * 16 + lm;
        float bs = bias[c];
#pragma unroll
        for (int m = 0; m < 8; m++) {
#pragma unroll
            for (int r = 0; r < 4; r++) {
                float v = acc[m][n][r] + bs;
                if (RELU) v = fmaxf(v, 0.f);
                C[(size_t)(crow + m * 16 + lo * 4 + r) * N + c] = __float2bfloat16(v);
            }
        }
    }
    (void)M;
}

// ----------------------------- MFMA flash attention ------------------------
// Block: (qt of 128 rows, h, b); 4 waves; wave w owns q-rows wm=w*32..+32.
// qkv is the fused [B*S][2304] buffer: q at col 0, k at 768, v at 1536.
// sP aliases sQ (Q is register-resident after the prologue). LDS ~36.9 KB.
#define PSTR 72
__global__ __launch_bounds__(256) void attn_mfma(
    const ushort* __restrict__ qkv,
    __hip_bfloat16* __restrict__ av)
{
    __shared__ alignas(16) ushort sQP[128 * PSTR];   // Q tile, then P (per-wave)
    __shared__ alignas(16) ushort sK[64 * PSTR];
    __shared__ alignas(16) ushort sVt[64 * PSTR];    // Vt[d][s]

    int t = threadIdx.x;
    int qt = blockIdx.x, h = blockIdx.y, b = blockIdx.z;
    int w = t >> 6, l = t & 63;
    int lm = l & 15, lq = l >> 4;
    int wm = w * 32;

    const ushort* qbase = qkv + (size_t)(b * S_ + qt * 128) * QKVSTR + h * DH_;
    const ushort* kbase = qkv + (size_t)b * S_ * QKVSTR + 768 + h * DH_;
    const ushort* vbase = qkv + (size_t)b * S_ * QKVSTR + 1536 + h * DH_;

    // stage Q tile [128][64]
    {
        int r = t >> 1, c0 = (t & 1) * 32;
        const ushort* src = qbase + (size_t)r * QKVSTR + c0;
        ushort* dst = &sQP[r * PSTR + c0];
        *(uint4*)(dst + 0)  = *(const uint4*)(src + 0);
        *(uint4*)(dst + 8)  = *(const uint4*)(src + 8);
        *(uint4*)(dst + 16) = *(const uint4*)(src + 16);
        *(uint4*)(dst + 24) = *(const uint4*)(src + 24);
    }
    __syncthreads();
    short8 qf[2][2];
#pragma unroll
    for (int i = 0; i < 2; i++)
#pragma unroll
        for (int ks = 0; ks < 2; ks++)
            qf[i][ks] = scale8_eighth(
                *(const short8*)&sQP[(wm + i * 16 + lm) * PSTR + ks * 32 + lq * 8]);

    ushort* sPw = &sQP[(size_t)wm * PSTR];           // wave-local P region

    f32x4 accO[2][4];
    float mrun[2][4], lrun[2][4];
#pragma unroll
    for (int i = 0; i < 2; i++)
#pragma unroll
        for (int j = 0; j < 4; j++) accO[i][j] = (f32x4){0.f, 0.f, 0.f, 0.f};
#pragma unroll
    for (int i = 0; i < 2; i++)
#pragma unroll
        for (int r = 0; r < 4; r++) { mrun[i][r] = -1e30f; lrun[i][r] = 0.f; }

    for (int kt = 0; kt < S_ / 64; kt++) {
        __syncthreads();   // prior reads of sK/sVt done; first iter: qf loads done
        {
            int r = t >> 2, c0 = (t & 3) * 16;
            const ushort* ksrc = kbase + (size_t)(kt * 64 + r) * QKVSTR + c0;
            ushort* kdst = &sK[r * PSTR + c0];
            *(uint4*)(kdst + 0) = *(const uint4*)(ksrc + 0);
            *(uint4*)(kdst + 8) = *(const uint4*)(ksrc + 8);
            const ushort* vsrc = vbase + (size_t)(kt * 64 + r) * QKVSTR + c0;
            ushort vv[16];
            *(uint4*)&vv[0] = *(const uint4*)(vsrc + 0);
            *(uint4*)&vv[8] = *(const uint4*)(vsrc + 8);
#pragma unroll
            for (int j = 0; j < 16; j++) sVt[(c0 + j) * PSTR + r] = vv[j];
        }
        __syncthreads();

        // S = (Q/8) K^T
        f32x4 accS[2][4];
#pragma unroll
        for (int i = 0; i < 2; i++)
#pragma unroll
            for (int j = 0; j < 4; j++) accS[i][j] = (f32x4){0.f, 0.f, 0.f, 0.f};
#pragma unroll
        for (int ks = 0; ks < 2; ks++) {
#pragma unroll
            for (int j = 0; j < 4; j++) {
                short8 kf = *(const short8*)&sK[(j * 16 + lm) * PSTR + ks * 32 + lq * 8];
#pragma unroll
                for (int i = 0; i < 2; i++)
                    accS[i][j] = __builtin_amdgcn_mfma_f32_16x16x32_bf16(
                        qf[i][ks], kf, accS[i][j], 0, 0, 0);
            }
        }

        // online softmax
        float rmax[2][4];
#pragma unroll
        for (int i = 0; i < 2; i++)
#pragma unroll
            for (int r = 0; r < 4; r++)
                rmax[i][r] = fmaxf(fmaxf(accS[i][0][r], accS[i][1][r]),
                                   fmaxf(accS[i][2][r], accS[i][3][r]));
#pragma unroll
        for (int d = 1; d < 16; d <<= 1)
#pragma unroll
            for (int i = 0; i < 2; i++)
#pragma unroll
                for (int r = 0; r < 4; r++)
                    rmax[i][r] = fmaxf(rmax[i][r], __shfl_xor(rmax[i][r], d));

        float alpha[2][4];
#pragma unroll
        for (int i = 0; i < 2; i++)
#pragma unroll
            for (int r = 0; r < 4; r++) {
                float mn = fmaxf(mrun[i][r], rmax[i][r]);
                alpha[i][r] = __expf(mrun[i][r] - mn);
                mrun[i][r] = mn;
            }
        float rsum[2][4];
#pragma unroll
        for (int i = 0; i < 2; i++)
#pragma unroll
            for (int r = 0; r < 4; r++) rsum[i][r] = 0.f;
#pragma unroll
        for (int i = 0; i < 2; i++)
#pragma unroll
            for (int j = 0; j < 4; j++)
#pragma unroll
                for (int r = 0; r < 4; r++) {
                    float p = __expf(accS[i][j][r] - mrun[i][r]);
                    accS[i][j][r] = p;
                    rsum[i][r] += p;
                }
#pragma unroll
        for (int d = 1; d < 16; d <<= 1)
#pragma unroll
            for (int i = 0; i < 2; i++)
#pragma unroll
                for (int r = 0; r < 4; r++)
                    rsum[i][r] += __shfl_xor(rsum[i][r], d);
#pragma unroll
        for (int i = 0; i < 2; i++)
#pragma unroll
            for (int r = 0; r < 4; r++)
                lrun[i][r] = lrun[i][r] * alpha[i][r] + rsum[i][r];

        // rescale O
#pragma unroll
        for (int i = 0; i < 2; i++)
#pragma unroll
            for (int j = 0; j < 4; j++)
#pragma unroll
                for (int r = 0; r < 4; r++) accO[i][j][r] *= alpha[i][r];

        // P -> wave-local LDS (C-layout -> A-layout round trip; no barrier)
#pragma unroll
        for (int i = 0; i < 2; i++)
#pragma unroll
            for (int j = 0; j < 4; j++)
#pragma unroll
                for (int r = 0; r < 4; r++)
                    sPw[(i * 16 + lq * 4 + r) * PSTR + j * 16 + lm] =
                        f2bf(accS[i][j][r]);

        // O += P V   (B-frags from Vt[d][s])
#pragma unroll
        for (int ks = 0; ks < 2; ks++) {
            short8 pf[2];
#pragma unroll
            for (int i = 0; i < 2; i++)
                pf[i] = *(const short8*)&sPw[(i * 16 + lm) * PSTR + ks * 32 + lq * 8];
#pragma unroll
            for (int j = 0; j < 4; j++) {
                short8 vf = *(const short8*)&sVt[(j * 16 + lm) * PSTR + ks * 32 + lq * 8];
#pragma unroll
                for (int i = 0; i < 2; i++)
                    accO[i][j] = __builtin_amdgcn_mfma_f32_16x16x32_bf16(
                        pf[i], vf, accO[i][j], 0, 0, 0);
            }
        }
    }

    // epilogue
    float invl[2][4];
#pragma unroll
    for (int i = 0; i < 2; i++)
#pragma unroll
        for (int r = 0; r < 4; r++) invl[i][r] = 1.0f / lrun[i][r];
#pragma unroll
    for (int i = 0; i < 2; i++)
#pragma unroll
        for (int j = 0; j < 4; j++)
#pragma unroll
            for (int r = 0; r < 4; r++) {
                int row = qt * 128 + wm + i * 16 + lq * 4 + r;
                int col = h * DH_ + j * 16 + lm;
                av[(size_t)(b * S_ + row) * D_ + col] =
                    __float2bfloat16(accO[i][j][r] * invl[i][r]);
            }
}

// ----------------------------- residual + layernorm ------------------------
__global__ __launch_bounds__(256) void add_ln(float* __restrict__ x,
    __hip_bfloat16* __restrict__ xb,
    const __hip_bfloat16* __restrict__ r, const float* __restrict__ g,
    const float* __restrict__ bta)
{
    __shared__ float sred[256];
    int row = blockIdx.x, t = threadIdx.x;
    size_t base = (size_t)row * D_;
    float v0 = x[base + t]       + __bfloat162float(r[base + t]);
    float v1 = x[base + t + 256] + __bfloat162float(r[base + t + 256]);
    float v2 = x[base + t + 512] + __bfloat162float(r[base + t + 512]);
    sred[t] = v0 + v1 + v2;
    __syncthreads();
    for (int o = 128; o > 0; o >>= 1) { if (t < o) sred[t] += sred[t + o]; __syncthreads(); }
    float mean = sred[0] * (1.0f / D_);
    __syncthreads();
    float d0 = v0 - mean, d1 = v1 - mean, d2 = v2 - mean;
    sred[t] = d0 * d0 + d1 * d1 + d2 * d2;
    __syncthreads();
    for (int o = 128; o > 0; o >>= 1) { if (t < o) sred[t] += sred[t + o]; __syncthreads(); }
    float rstd = rsqrtf(sred[0] * (1.0f / D_) + 1e-6f);
    float o0 = g[t]       * d0 * rstd + bta[t];
    float o1 = g[t + 256] * d1 * rstd + bta[t + 256];
    float o2 = g[t + 512] * d2 * rstd + bta[t + 512];
    x[base + t]       = o0;
    x[base + t + 256] = o1;
    x[base + t + 512] = o2;
    xb[base + t]       = __float2bfloat16(o0);
    xb[base + t + 256] = __float2bfloat16(o1);
    xb[base + t + 512] = __float2bfloat16(o2);
}

// ----------------------------- mean pool over S ----------------------------
__global__ void pool_kernel(const float* __restrict__ x, float* __restrict__ pooled) {
    int idx = blockIdx.x * 256 + threadIdx.x;   // b*768 + d
    int b = idx / D_, d = idx % D_;
    float acc = 0.f;
    const float* p = x + (size_t)b * S_ * D_ + d;
    for (int s = 0; s < S_; s++) acc += p[(size_t)s * D_];
    pooled[idx] = acc * (1.0f / S_);
}

// ----------------------------- classifier head -----------------------------
__global__ void head_kernel(const float* __restrict__ pooled,
                            const float* __restrict__ wl,
                            const float* __restrict__ bl,
                            const float* __restrict__ wout,
                            const float* __restrict__ bout,
                            float* __restrict__ out)
{
    __shared__ float hb[32];
    int b = blockIdx.x, t = threadIdx.x;
    if (t < 32) {
        float z = bl[t];
        for (int d = 0; d < D_; d++) z += pooled[b * D_ + d] * wl[d * 32 + t];
        hb[t] = 0.5f * z * (1.0f + erff(z * 0.70710678118654752f));
    }
    __syncthreads();
    if (t == 0) {
        float z = bout[0];
        for (int j = 0; j < 32; j++) z += hb[j] * wout[j];
        out[b] = 1.0f / (1.0f + expf(-z));
    }
}

// ---------------------------------------------------------------------------
extern "C" void kernel_launch(void* const* d_in, const int* in_sizes, int n_in,
                              void* d_out, int out_size, void* d_ws, size_t ws_size,
                              hipStream_t stream)
{
    (void)in_sizes; (void)n_in; (void)out_size; (void)ws_size;
    const int*   tokens = (const int*)  d_in[0];
    const float* emb    = (const float*)d_in[1];
    const float* wq     = (const float*)d_in[2];
    const float* bq     = (const float*)d_in[3];
    const float* wk     = (const float*)d_in[4];
    const float* bk     = (const float*)d_in[5];
    const float* wv     = (const float*)d_in[6];
    const float* bv     = (const float*)d_in[7];
    const float* wo     = (const float*)d_in[8];
    const float* bo     = (const float*)d_in[9];
    const float* w1     = (const float*)d_in[10];
    const float* b1     = (const float*)d_in[11];
    const float* w2     = (const float*)d_in[12];
    const float* b2     = (const float*)d_in[13];
    const float* ln1g   = (const float*)d_in[14];
    const float* ln1b   = (const float*)d_in[15];
    const float* ln2g   = (const float*)d_in[16];
    const float* ln2b   = (const float*)d_in[17];
    const float* wl     = (const float*)d_in[18];
    const float* bl     = (const float*)d_in[19];
    const float* wout   = (const float*)d_in[20];
    const float* bout   = (const float*)d_in[21];
    float* out = (float*)d_out;

    char* ws = (char*)d_ws;
    size_t off = 0;
    auto alloc = [&](size_t n) -> void* {
        char* p = ws + off;
        off = (off + n + 255) & ~(size_t)255;
        return (void*)p;
    };
    const size_t XBYTES = (size_t)B_ * S_ * D_ * 4;        // 50.33 MB
    const size_t XBF    = XBYTES / 2;                      // 25.17 MB
    float*          pe     = (float*)alloc((size_t)S_ * D_ * 4);
    float*          x      = (float*)alloc(XBYTES);
    __hip_bfloat16* xb     = (__hip_bfloat16*)alloc(XBF);
    __hip_bfloat16* r_bf   = (__hip_bfloat16*)alloc(XBF);  // residual branch
    char*           arena  = (char*)alloc(4 * XBF);        // 100.66 MB
    __hip_bfloat16* qkv_bf = (__hip_bfloat16*)arena;       // [M][2304]
    __hip_bfloat16* av_bf  = (__hip_bfloat16*)(arena + 3 * XBF);
    __hip_bfloat16* h_bf   = (__hip_bfloat16*)arena;       // [M][3072] aliases qkv+av
    __hip_bfloat16* wT     = (__hip_bfloat16*)alloc((size_t)L_ * 7077888 * 2);
    float*          qkvbias= (float*)alloc((size_t)L_ * QKVSTR * 4);
    float*          pooled = (float*)alloc((size_t)B_ * D_ * 4);
    // total ~260 MB

    const int M = B_ * S_;                                 // 16384
    const size_t DD = (size_t)D_ * D_;
    const size_t DF = (size_t)D_ * FF_;
    const size_t LSTRIDE = 4 * DD + 2 * DF;

    // weights: per layer [qkvT(3*DD) | woT(DD) | w1T(DF) | w2T(DF)]
    transpose_bf16_l<<<dim3(D_ / 32, D_ / 32, L_), 256, 0, stream>>>(
        wq, wT + 0 * DD, D_, D_, DD, LSTRIDE);
    transpose_bf16_l<<<dim3(D_ / 32, D_ / 32, L_), 256, 0, stream>>>(
        wk, wT + 1 * DD, D_, D_, DD, LSTRIDE);
    transpose_bf16_l<<<dim3(D_ / 32, D_ / 32, L_), 256, 0, stream>>>(
        wv, wT + 2 * DD, D_, D_, DD, LSTRIDE);
    transpose_bf16_l<<<dim3(D_ / 32, D_ / 32, L_), 256, 0, stream>>>(
        wo, wT + 3 * DD, D_, D_, DD, LSTRIDE);
    transpose_bf16_l<<<dim3(FF_ / 32, D_ / 32, L_), 256, 0, stream>>>(
        w1, wT + 4 * DD, D_, FF_, DF, LSTRIDE);
    transpose_bf16_l<<<dim3(D_ / 32, FF_ / 32, L_), 256, 0, stream>>>(
        w2, wT + 4 * DD + DF, FF_, D_, DF, LSTRIDE);
    biascat<<<(L_ * QKVSTR) / 256, 256, 0, stream>>>(bq, bk, bv, qkvbias);

    pe_kernel<<<(S_ * D_ + 255) / 256, 256, 0, stream>>>(pe);
    embed_kernel<<<M, 256, 0, stream>>>(tokens, emb, pe, x, xb);

    for (int l = 0; l < L_; l++) {
        __hip_bfloat16* wl_base = wT + (size_t)l * LSTRIDE;
        const ushort* qkvT = (const ushort*)(wl_base + 0 * DD);
        const ushort* woT  = (const ushort*)(wl_base + 3 * DD);
        const ushort* w1T  = (const ushort*)(wl_base + 4 * DD);
        const ushort* w2T  = (const ushort*)(wl_base + 4 * DD + DF);

        gemm256<0><<<dim3((QKVSTR / 256) * (M / 256)), 512, 0, stream>>>(
            (const ushort*)xb, qkvT, qkvbias + (size_t)l * QKVSTR, qkv_bf,
            M, QKVSTR, D_, QKVSTR / 256);

        attn_mfma<<<dim3(S_ / 128, H_, B_), 256, 0, stream>>>(
            (const ushort*)qkv_bf, av_bf);

        gemm256<0><<<dim3((D_ / 256) * (M / 256)), 512, 0, stream>>>(
            (const ushort*)av_bf, woT, bo + l * D_, r_bf, M, D_, D_, D_ / 256);
        add_ln<<<M, 256, 0, stream>>>(x, xb, r_bf, ln1g + l * D_, ln1b + l * D_);

        gemm256<1><<<dim3((FF_ / 256) * (M / 256)), 512, 0, stream>>>(
            (const ushort*)xb, w1T, b1 + l * FF_, h_bf, M, FF_, D_, FF_ / 256);
        gemm256<0><<<dim3((D_ / 256) * (M / 256)), 512, 0, stream>>>(
            (const ushort*)h_bf, w2T, b2 + l * D_, r_bf, M, D_, FF_, D_ / 256);
        add_ln<<<M, 256, 0, stream>>>(x, xb, r_bf, ln2g + l * D_, ln2b + l * D_);
    }

    pool_kernel<<<(B_ * D_) / 256, 256, 0, stream>>>(x, pooled);
    head_kernel<<<B_, 64, 0, stream>>>(pooled, wl, bl, wout, bout, out);
}

// Round 3
// 1963.462 us; speedup vs baseline: 1.2162x; 1.0558x over previous
//
#include <hip/hip_runtime.h>
#include <hip/hip_bf16.h>
#include <math.h>

// ---------------------------------------------------------------------------
// TextTransformer forward on MI355X — Round 7: attention operand-swap rewrite
// (S^T = K·Q, O^T = V^T·P^T): lane-local softmax columns (2-round shfl),
// vector P stores (b64), vectorized V-transpose staging (b32, conflict-free),
// vector epilogue (b64). GEMM unchanged from Round 6.
// B=32 S=512 D=768 H=12 DH=64 FF=3072 L=4.
// ---------------------------------------------------------------------------

#define B_  32
#define S_  512
#define D_  768
#define H_  12
#define DH_ 64
#define FF_ 3072
#define L_  4
#define QKVSTR 2304

typedef __attribute__((ext_vector_type(8))) short short8;   // 8 x bf16
typedef __attribute__((ext_vector_type(4))) short short4v;  // 4 x bf16 (b64)
typedef __attribute__((ext_vector_type(4))) float f32x4;

__device__ __forceinline__ void async16(const void* g, void* l) {
    __builtin_amdgcn_global_load_lds(
        (const __attribute__((address_space(1))) void*)g,
        (__attribute__((address_space(3))) void*)l, 16, 0, 0);
}

__device__ __forceinline__ ushort f2bf(float f) {
    __hip_bfloat16 h = __float2bfloat16(f);
    return __builtin_bit_cast(ushort, h);
}

// multiply a bf16 by 0.125 exactly: exponent -= 3 (flush tiny to signed 0)
__device__ __forceinline__ short8 scale8_eighth(short8 v) {
    short8 r;
#pragma unroll
    for (int e = 0; e < 8; e++) {
        ushort u = (ushort)v[e];
        ushort ex = u & 0x7f80;
        r[e] = (short)(ex > 0x0180 ? (ushort)(u - 0x0180) : (ushort)(u & 0x8000));
    }
    return r;
}

// ----------------------------- positional encoding -------------------------
__global__ void pe_kernel(float* __restrict__ pe) {
    int idx = blockIdx.x * 256 + threadIdx.x;
    if (idx >= S_ * D_) return;
    int s = idx / D_, j = idx % D_;
    double e = (2.0 * (double)(j >> 1)) / (double)D_;
    double denom = pow(10000.0, e);
    double ang = (double)s / denom;
    pe[idx] = (j & 1) ? (float)cos(ang) : (float)sin(ang);
}

// ----------------------------- embedding + PE ------------------------------
__global__ void embed_kernel(const int* __restrict__ tokens,
                             const float* __restrict__ emb,
                             const float* __restrict__ pe,
                             float* __restrict__ x,
                             __hip_bfloat16* __restrict__ xb) {
    int row = blockIdx.x;              // b*S + s
    int s = row & (S_ - 1);
    int tok = tokens[row];
    float scale = sqrtf((float)D_);
    for (int i = threadIdx.x; i < D_; i += 256) {
        float v = emb[(size_t)tok * D_ + i] * scale + pe[s * D_ + i];
        x[(size_t)row * D_ + i] = v;
        xb[(size_t)row * D_ + i] = __float2bfloat16(v);
    }
}

// ----------------------------- batched weight transpose fp32->bf16 ---------
// out[z][c][r] = (bf16) in[z][r][c].  Grid (C/32, R/32, L).
__global__ __launch_bounds__(256) void transpose_bf16_l(
    const float* __restrict__ in, __hip_bfloat16* __restrict__ out,
    int R, int C, size_t inL, size_t outL)
{
    __shared__ float tile[32][33];
    in  += (size_t)blockIdx.z * inL;
    out += (size_t)blockIdx.z * outL;
    int tx = threadIdx.x & 31, ty = threadIdx.x >> 5;   // 32 x 8
    int c0 = blockIdx.x * 32, r0 = blockIdx.y * 32;
#pragma unroll
    for (int d = 0; d < 32; d += 8)
        tile[ty + d][tx] = in[(size_t)(r0 + ty + d) * C + c0 + tx];
    __syncthreads();
#pragma unroll
    for (int d = 0; d < 32; d += 8)
        out[(size_t)(c0 + ty + d) * R + r0 + tx] = __float2bfloat16(tile[tx][ty + d]);
}

// ----------------------------- qkv bias concat -----------------------------
__global__ void biascat(const float* __restrict__ bq, const float* __restrict__ bk,
                        const float* __restrict__ bv, float* __restrict__ o) {
    int i = blockIdx.x * 256 + threadIdx.x;          // [L_*2304)
    int ll = i / QKVSTR, j = i % QKVSTR;
    o[i] = j < 768 ? bq[ll * 768 + j]
         : j < 1536 ? bk[ll * 768 + j - 768]
                    : bv[ll * 768 + j - 1536];
}

// ----------------------------- 256x256 8-phase bf16 MFMA GEMM --------------
// C[M,N] = A[M,K] @ Bt[N,K]^T + bias[N].  M%256==0, N%256==0, K%128==0.
// 512 threads = 8 waves (2Mx4N); per-wave output 128x64; BK=64, dbuf LDS 128KB.
// T2 swizzle (3-bit): within each 128B LDS row, byte_col ^= ((row&7)<<4),
// applied via inverse-swizzled global SOURCE + swizzled ds_read columns.
#define BAR()   __builtin_amdgcn_s_barrier()
#define LGKM0() asm volatile("s_waitcnt lgkmcnt(0)" ::: "memory")
#define VM4()   asm volatile("s_waitcnt vmcnt(4)" ::: "memory")

#define STAGE_A(buf, h, kt) do { \
    async16(aSrc[h][0] + (kt) * 64, &lds[(buf) * 2][dOff[h][0]]); \
    async16(aSrc[h][1] + (kt) * 64, &lds[(buf) * 2][dOff[h][1]]); } while (0)
#define STAGE_B(buf, h, kt) do { \
    async16(bSrc[h][0] + (kt) * 64, &lds[(buf) * 2 + 1][dOff[h][0]]); \
    async16(bSrc[h][1] + (kt) * 64, &lds[(buf) * 2 + 1][dOff[h][1]]); } while (0)

#define LDA(buf, m, ks) (*(const short8*)((const char*)(&lds[(buf) * 2][0]) + \
    (size_t)((arow + (m) * 16) * 128 + cswz[ks])))
#define LDB(buf, n, ks) (*(const short8*)((const char*)(&lds[(buf) * 2 + 1][0]) + \
    (size_t)((brow + (n) * 16) * 128 + cswz[ks])))

#define MFMA_Q(mh, nh) do { \
    __builtin_amdgcn_s_setprio(1); \
    _Pragma("unroll") \
    for (int ks_ = 0; ks_ < 2; ks_++) { \
      _Pragma("unroll") \
      for (int n_ = 0; n_ < 2; n_++) { \
        _Pragma("unroll") \
        for (int m_ = 0; m_ < 4; m_++) { \
          acc[(mh) * 4 + m_][(nh) * 2 + n_] = \
              __builtin_amdgcn_mfma_f32_16x16x32_bf16( \
                  a[m_][ks_], b[(nh) * 2 + n_][ks_], \
                  acc[(mh) * 4 + m_][(nh) * 2 + n_], 0, 0, 0); \
        } } } \
    __builtin_amdgcn_s_setprio(0); \
} while (0)

template<int RELU>
__global__ __launch_bounds__(512, 2) void gemm256(
    const ushort* __restrict__ A,   // bf16 [M][K]
    const ushort* __restrict__ Bt,  // bf16 [N][K]
    const float* __restrict__ bias, // fp32 [N]
    __hip_bfloat16* __restrict__ C, // bf16 [M][N]
    int M, int N, int K, int NX)    // NX = N/256
{
    __shared__ alignas(16) ushort lds[4][16384];  // [buf*2 + (0=A,1=B)][256*64]

    int t = threadIdx.x;
    int l = t & 63, w = t >> 6;
    int wmi = w >> 2, wni = w & 3;            // 2 x 4 wave grid
    int lm = l & 15, lo = l >> 4;

    // T1: XCD-aware block swizzle (all our grids are %8 == 0)
    int nwg = gridDim.x;
    int bid = blockIdx.x;
    int lid = (nwg & 7) ? bid : ((bid & 7) * (nwg >> 3) + (bid >> 3));
    int bn = lid % NX, bm = lid / NX;
    int row0 = bm << 8, col0 = bn << 8;

    // staging geometry: thread t stages 16B chunks; LDS dest is linear,
    // global source column is inverse-swizzled: col ^= ((row&7)<<4).
    const ushort* aSrc[2][2];
    const ushort* bSrc[2][2];
    int dOff[2][2];
#pragma unroll
    for (int h = 0; h < 2; h++) {
#pragma unroll
        for (int c = 0; c < 2; c++) {
            int p = h * 16384 + c * 8192 + t * 16;     // byte off in 32KB tile
            int prow = p >> 7;                         // tile row (0..255)
            int scolb = (p & 127) ^ ((prow & 7) << 4); // inverse-swz byte col
            dOff[h][c] = p >> 1;
            aSrc[h][c] = A  + (size_t)(row0 + prow) * K + (scolb >> 1);
            bSrc[h][c] = Bt + (size_t)(col0 + prow) * K + (scolb >> 1);
        }
    }

    // ds_read addressing: fragment rows are ...+lm (mod 16), so row&7 = lm&7
    // is lane-constant; precompute swizzled byte col per ks half.
    int arow = wmi * 128 + lm;
    int brow = wni * 64 + lm;
    int swz = (lm & 7) << 4;
    int cswz[2];
    cswz[0] = (lo * 16) ^ swz;
    cswz[1] = (64 + lo * 16) ^ swz;

    f32x4 acc[8][4];
#pragma unroll
    for (int i = 0; i < 8; i++)
#pragma unroll
        for (int j = 0; j < 4; j++) acc[i][j] = (f32x4){0.f, 0.f, 0.f, 0.f};
    short8 a[4][2], b[4][2];

    const int NK = K >> 6;        // 64-wide K-tiles (even; K%128==0)
    const int NI = NK >> 1;

    // prologue: kt0 fully into buf0; kt1's B-halves into buf1 (12 loads)
    STAGE_A(0, 0, 0); STAGE_A(0, 1, 0);
    STAGE_B(0, 0, 0); STAGE_B(0, 1, 0);
    STAGE_B(1, 0, 1); STAGE_B(1, 1, 1);
    VM4();            // kt0's 8 loads landed; kt1 B (4) still in flight
    BAR();

    for (int i = 0; i < NI; i++) {
        int kt  = 2 * i;
        int ktA = (kt + 2 <= NK - 2) ? kt + 2 : NK - 2;   // clamp: last iter
        int ktB = (kt + 3 <= NK - 1) ? kt + 3 : NK - 1;   // re-stages same data

        // ---- phase 1: Q(0,0) of buf0 | stage A-half0(kt+1) -> buf1
#pragma unroll
        for (int m = 0; m < 4; m++) { a[m][0] = LDA(0, m, 0); a[m][1] = LDA(0, m, 1); }
#pragma unroll
        for (int n = 0; n < 2; n++) { b[n][0] = LDB(0, n, 0); b[n][1] = LDB(0, n, 1); }
        STAGE_A(1, 0, kt + 1);
        BAR(); LGKM0();
        MFMA_Q(0, 0);
        BAR();

        // ---- phase 2: Q(0,1) | stage A-half1(kt+1) -> buf1
#pragma unroll
        for (int n = 0; n < 2; n++) { b[2 + n][0] = LDB(0, 2 + n, 0); b[2 + n][1] = LDB(0, 2 + n, 1); }
        STAGE_A(1, 1, kt + 1);
        BAR(); LGKM0();
        MFMA_Q(0, 1);
        BAR();

        // ---- phase 3: Q(1,0) | stage B-half0(kt+2) -> buf0 (B reads done ph2)
#pragma unroll
        for (int m = 0; m < 4; m++) { a[m][0] = LDA(0, 4 + m, 0); a[m][1] = LDA(0, 4 + m, 1); }
        STAGE_B(0, 0, ktA);
        BAR(); LGKM0();
        MFMA_Q(1, 0);
        BAR();

        // ---- phase 4: Q(1,1) | stage B-half1(kt+2); gate buf1 (kt+1) ready
        STAGE_B(0, 1, ktA);
        BAR(); LGKM0();
        MFMA_Q(1, 1);
        VM4();        // all but ph3/ph4's 4 loads landed -> buf1 complete
        BAR();

        // ---- phase 5: Q(0,0) of buf1 | stage A-half0(kt+2) -> buf0
#pragma unroll
        for (int m = 0; m < 4; m++) { a[m][0] = LDA(1, m, 0); a[m][1] = LDA(1, m, 1); }
#pragma unroll
        for (int n = 0; n < 2; n++) { b[n][0] = LDB(1, n, 0); b[n][1] = LDB(1, n, 1); }
        STAGE_A(0, 0, ktA);
        BAR(); LGKM0();
        MFMA_Q(0, 0);
        BAR();

        // ---- phase 6: Q(0,1) | stage A-half1(kt+2) -> buf0
#pragma unroll
        for (int n = 0; n < 2; n++) { b[2 + n][0] = LDB(1, 2 + n, 0); b[2 + n][1] = LDB(1, 2 + n, 1); }
        STAGE_A(0, 1, ktA);
        BAR(); LGKM0();
        MFMA_Q(0, 1);
        BAR();

        // ---- phase 7: Q(1,0) | stage B-half0(kt+3) -> buf1 (B reads done ph6)
#pragma unroll
        for (int m = 0; m < 4; m++) { a[m][0] = LDA(1, 4 + m, 0); a[m][1] = LDA(1, 4 + m, 1); }
        STAGE_B(1, 0, ktB);
        BAR(); LGKM0();
        MFMA_Q(1, 0);
        BAR();

        // ---- phase 8: Q(1,1) | stage B-half1(kt+3); gate buf0 (kt+2) ready
        STAGE_B(1, 1, ktB);
        BAR(); LGKM0();
        MFMA_Q(1, 1);
        VM4();        // all but ph7/ph8's 4 loads landed -> buf0 complete
        BAR();
    }

    // epilogue: bias + optional relu, bf16 out
    int crow = row0 + wmi * 128;
    int ccol = col0 + wni * 64;
#pragma unroll
    for (int n = 0; n < 4; n++) {
        int c = ccol + n * 16 + lm;
        float bs = bias[c];
#pragma unroll
        for (int m = 0; m < 8; m++) {
#pragma unroll
            for (int r = 0; r < 4; r++) {
                float v = acc[m][n][r] + bs;
                if (RELU) v = fmaxf(v, 0.f);
                C[(size_t)(crow + m * 16 + lo * 4 + r) * N + c] = __float2bfloat16(v);
            }
        }
    }
    (void)M;
}

// ----------------------------- MFMA flash attention (operand-swapped) ------
// Block: (qt of 128 rows, h, b); 4 waves; wave w owns q-rows wm=w*32..+32.
// S^T = mfma(A=K, B=Q/8): lane(lm,lq) holds S^T[s=sblk*16+lq*4+r][q=qblk*16+lm]
//   -> softmax column q is lane-local across (sblk,r); cross-lane reduce is
//      shfl_xor 16/32 only (lanes sharing lm).
// P^T C-layout stores r-consecutive s -> sPw[q][s] via b64 writes.
// O^T = mfma(A=Vt, B=P): lane holds O^T[d=dblk*16+lq*4+r][q=qblk*16+lm]
//   -> epilogue writes 4 consecutive d per lane = global b64 stores.
// sP aliases sQ (Q register-resident after prologue). LDS ~36.9 KB.
#define PSTR 72
__global__ __launch_bounds__(256) void attn_mfma(
    const ushort* __restrict__ qkv,
    __hip_bfloat16* __restrict__ av)
{
    __shared__ alignas(16) ushort sQP[128 * PSTR];   // Q tile, then P (per-wave)
    __shared__ alignas(16) ushort sK[64 * PSTR];
    __shared__ alignas(16) ushort sVt[64 * PSTR];    // Vt[d][s]

    int t = threadIdx.x;
    int qt = blockIdx.x, h = blockIdx.y, b = blockIdx.z;
    int w = t >> 6, l = t & 63;
    int lm = l & 15, lq = l >> 4;
    int wm = w * 32;

    const ushort* qbase = qkv + (size_t)(b * S_ + qt * 128) * QKVSTR + h * DH_;
    const ushort* kbase = qkv + (size_t)b * S_ * QKVSTR + 768 + h * DH_;
    const ushort* vbase = qkv + (size_t)b * S_ * QKVSTR + 1536 + h * DH_;

    // stage Q tile [128][64]
    {
        int r = t >> 1, c0 = (t & 1) * 32;
        const ushort* src = qbase + (size_t)r * QKVSTR + c0;
        ushort* dst = &sQP[r * PSTR + c0];
        *(uint4*)(dst + 0)  = *(const uint4*)(src + 0);
        *(uint4*)(dst + 8)  = *(const uint4*)(src + 8);
        *(uint4*)(dst + 16) = *(const uint4*)(src + 16);
        *(uint4*)(dst + 24) = *(const uint4*)(src + 24);
    }
    __syncthreads();
    short8 qf[2][2];   // [qblk][ks] — B-fragments (Q/8)
#pragma unroll
    for (int i = 0; i < 2; i++)
#pragma unroll
        for (int ks = 0; ks < 2; ks++)
            qf[i][ks] = scale8_eighth(
                *(const short8*)&sQP[(wm + i * 16 + lm) * PSTR + ks * 32 + lq * 8]);

    ushort* sPw = &sQP[(size_t)wm * PSTR];           // wave-local P region [32q][64s]

    f32x4 accO[4][2];          // O^T: [dblk][qblk]
    float mrun[2], lrun[2];    // per q-col (q = qblk*16+lm)
#pragma unroll
    for (int dk = 0; dk < 4; dk++)
#pragma unroll
        for (int i = 0; i < 2; i++) accO[dk][i] = (f32x4){0.f, 0.f, 0.f, 0.f};
    mrun[0] = mrun[1] = -1e30f;
    lrun[0] = lrun[1] = 0.f;

    for (int kt = 0; kt < S_ / 64; kt++) {
        __syncthreads();   // prior reads of sK/sVt done; first iter: qf loads done
        {
            // K stage: thread t covers row r = t>>2, 32B chunk (t&3)
            int r = t >> 2, c0 = (t & 3) * 16;
            const ushort* ksrc = kbase + (size_t)(kt * 64 + r) * QKVSTR + c0;
            ushort* kdst = &sK[r * PSTR + c0];
            *(uint4*)(kdst + 0) = *(const uint4*)(ksrc + 0);
            *(uint4*)(kdst + 8) = *(const uint4*)(ksrc + 8);
            // V stage (transposed, vectorized): thread t covers s-pair p=t&31,
            // d-chunk d0=(t>>5)*8; writes 8 x b32 (ushort2), banks (4j+p)%32.
            int p = t & 31, d0 = (t >> 5) * 8;
            const ushort* vsrc = vbase + (size_t)(kt * 64 + 2 * p) * QKVSTR + d0;
            uint4 v0 = *(const uint4*)(vsrc);
            uint4 v1 = *(const uint4*)(vsrc + QKVSTR);
            const ushort* e0 = (const ushort*)&v0;
            const ushort* e1 = (const ushort*)&v1;
#pragma unroll
            for (int j = 0; j < 8; j++) {
                uint pk = (uint)e0[j] | ((uint)e1[j] << 16);
                *(uint*)&sVt[(d0 + j) * PSTR + 2 * p] = pk;
            }
        }
        __syncthreads();

        // S^T = K (Q/8):  accS[sblk][qblk]
        f32x4 accS[4][2];
#pragma unroll
        for (int sb = 0; sb < 4; sb++)
#pragma unroll
            for (int i = 0; i < 2; i++) accS[sb][i] = (f32x4){0.f, 0.f, 0.f, 0.f};
#pragma unroll
        for (int ks = 0; ks < 2; ks++) {
#pragma unroll
            for (int sb = 0; sb < 4; sb++) {
                short8 kf = *(const short8*)&sK[(sb * 16 + lm) * PSTR + ks * 32 + lq * 8];
#pragma unroll
                for (int i = 0; i < 2; i++)
                    accS[sb][i] = __builtin_amdgcn_mfma_f32_16x16x32_bf16(
                        kf, qf[i][ks], accS[sb][i], 0, 0, 0);
            }
        }

        // online softmax over s (lane-local + 2-round shfl across lq groups)
        float pmax[2];
#pragma unroll
        for (int i = 0; i < 2; i++) {
            float m0 = accS[0][i][0];
#pragma unroll
            for (int sb = 0; sb < 4; sb++)
#pragma unroll
                for (int r = 0; r < 4; r++) m0 = fmaxf(m0, accS[sb][i][r]);
            m0 = fmaxf(m0, __shfl_xor(m0, 16));
            m0 = fmaxf(m0, __shfl_xor(m0, 32));
            pmax[i] = m0;
        }
        float alpha[2];
#pragma unroll
        for (int i = 0; i < 2; i++) {
            float mn = fmaxf(mrun[i], pmax[i]);
            alpha[i] = __expf(mrun[i] - mn);
            mrun[i] = mn;
        }
        float rsum[2] = {0.f, 0.f};
#pragma unroll
        for (int sb = 0; sb < 4; sb++)
#pragma unroll
            for (int i = 0; i < 2; i++)
#pragma unroll
                for (int r = 0; r < 4; r++) {
                    float p = __expf(accS[sb][i][r] - mrun[i]);
                    accS[sb][i][r] = p;
                    rsum[i] += p;
                }
#pragma unroll
        for (int i = 0; i < 2; i++) {
            rsum[i] += __shfl_xor(rsum[i], 16);
            rsum[i] += __shfl_xor(rsum[i], 32);
            lrun[i] = lrun[i] * alpha[i] + rsum[i];
        }

        // rescale O^T
#pragma unroll
        for (int dk = 0; dk < 4; dk++)
#pragma unroll
            for (int i = 0; i < 2; i++)
#pragma unroll
                for (int r = 0; r < 4; r++) accO[dk][i][r] *= alpha[i];

        // P^T C-layout -> sPw[q][s]: 4 r-consecutive s per (qblk,sblk) = b64
#pragma unroll
        for (int i = 0; i < 2; i++)
#pragma unroll
            for (int sb = 0; sb < 4; sb++) {
                short4v pk;
#pragma unroll
                for (int r = 0; r < 4; r++) pk[r] = (short)f2bf(accS[sb][i][r]);
                *(short4v*)&sPw[(i * 16 + lm) * PSTR + sb * 16 + lq * 4] = pk;
            }

        // O^T += V^T P^T  (A = Vt rows, B = sPw rows; wave-local, no barrier)
#pragma unroll
        for (int ks = 0; ks < 2; ks++) {
            short8 pf[2];
#pragma unroll
            for (int i = 0; i < 2; i++)
                pf[i] = *(const short8*)&sPw[(i * 16 + lm) * PSTR + ks * 32 + lq * 8];
#pragma unroll
            for (int dk = 0; dk < 4; dk++) {
                short8 vf = *(const short8*)&sVt[(dk * 16 + lm) * PSTR + ks * 32 + lq * 8];
#pragma unroll
                for (int i = 0; i < 2; i++)
                    accO[dk][i] = __builtin_amdgcn_mfma_f32_16x16x32_bf16(
                        vf, pf[i], accO[dk][i], 0, 0, 0);
            }
        }
    }

    // epilogue: O = (O^T)^T / l, vector b64 stores (4 consecutive d per lane)
    float invl[2];
    invl[0] = 1.0f / lrun[0];
    invl[1] = 1.0f / lrun[1];
#pragma unroll
    for (int i = 0; i < 2; i++) {
        int row = qt * 128 + wm + i * 16 + lm;
        __hip_bfloat16* dst = av + (size_t)(b * S_ + row) * D_ + h * DH_;
#pragma unroll
        for (int dk = 0; dk < 4; dk++) {
            short4v ok;
#pragma unroll
            for (int r = 0; r < 4; r++) ok[r] = (short)f2bf(accO[dk][i][r] * invl[i]);
            *(short4v*)(dst + dk * 16 + lq * 4) = ok;
        }
    }
}

// ----------------------------- residual + layernorm ------------------------
__global__ __launch_bounds__(256) void add_ln(float* __restrict__ x,
    __hip_bfloat16* __restrict__ xb,
    const __hip_bfloat16* __restrict__ r, const float* __restrict__ g,
    const float* __restrict__ bta)
{
    __shared__ float sred[256];
    int row = blockIdx.x, t = threadIdx.x;
    size_t base = (size_t)row * D_;
    float v0 = x[base + t]       + __bfloat162float(r[base + t]);
    float v1 = x[base + t + 256] + __bfloat162float(r[base + t + 256]);
    float v2 = x[base + t + 512] + __bfloat162float(r[base + t + 512]);
    sred[t] = v0 + v1 + v2;
    __syncthreads();
    for (int o = 128; o > 0; o >>= 1) { if (t < o) sred[t] += sred[t + o]; __syncthreads(); }
    float mean = sred[0] * (1.0f / D_);
    __syncthreads();
    float d0 = v0 - mean, d1 = v1 - mean, d2 = v2 - mean;
    sred[t] = d0 * d0 + d1 * d1 + d2 * d2;
    __syncthreads();
    for (int o = 128; o > 0; o >>= 1) { if (t < o) sred[t] += sred[t + o]; __syncthreads(); }
    float rstd = rsqrtf(sred[0] * (1.0f / D_) + 1e-6f);
    float o0 = g[t]       * d0 * rstd + bta[t];
    float o1 = g[t + 256] * d1 * rstd + bta[t + 256];
    float o2 = g[t + 512] * d2 * rstd + bta[t + 512];
    x[base + t]       = o0;
    x[base + t + 256] = o1;
    x[base + t + 512] = o2;
    xb[base + t]       = __float2bfloat16(o0);
    xb[base + t + 256] = __float2bfloat16(o1);
    xb[base + t + 512] = __float2bfloat16(o2);
}

// ----------------------------- mean pool over S ----------------------------
__global__ void pool_kernel(const float* __restrict__ x, float* __restrict__ pooled) {
    int idx = blockIdx.x * 256 + threadIdx.x;   // b*768 + d
    int b = idx / D_, d = idx % D_;
    float acc = 0.f;
    const float* p = x + (size_t)b * S_ * D_ + d;
    for (int s = 0; s < S_; s++) acc += p[(size_t)s * D_];
    pooled[idx] = acc * (1.0f / S_);
}

// ----------------------------- classifier head -----------------------------
__global__ void head_kernel(const float* __restrict__ pooled,
                            const float* __restrict__ wl,
                            const float* __restrict__ bl,
                            const float* __restrict__ wout,
                            const float* __restrict__ bout,
                            float* __restrict__ out)
{
    __shared__ float hb[32];
    int b = blockIdx.x, t = threadIdx.x;
    if (t < 32) {
        float z = bl[t];
        for (int d = 0; d < D_; d++) z += pooled[b * D_ + d] * wl[d * 32 + t];
        hb[t] = 0.5f * z * (1.0f + erff(z * 0.70710678118654752f));
    }
    __syncthreads();
    if (t == 0) {
        float z = bout[0];
        for (int j = 0; j < 32; j++) z += hb[j] * wout[j];
        out[b] = 1.0f / (1.0f + expf(-z));
    }
}

// ---------------------------------------------------------------------------
extern "C" void kernel_launch(void* const* d_in, const int* in_sizes, int n_in,
                              void* d_out, int out_size, void* d_ws, size_t ws_size,
                              hipStream_t stream)
{
    (void)in_sizes; (void)n_in; (void)out_size; (void)ws_size;
    const int*   tokens = (const int*)  d_in[0];
    const float* emb    = (const float*)d_in[1];
    const float* wq     = (const float*)d_in[2];
    const float* bq     = (const float*)d_in[3];
    const float* wk     = (const float*)d_in[4];
    const float* bk     = (const float*)d_in[5];
    const float* wv     = (const float*)d_in[6];
    const float* bv     = (const float*)d_in[7];
    const float* wo     = (const float*)d_in[8];
    const float* bo     = (const float*)d_in[9];
    const float* w1     = (const float*)d_in[10];
    const float* b1     = (const float*)d_in[11];
    const float* w2     = (const float*)d_in[12];
    const float* b2     = (const float*)d_in[13];
    const float* ln1g   = (const float*)d_in[14];
    const float* ln1b   = (const float*)d_in[15];
    const float* ln2g   = (const float*)d_in[16];
    const float* ln2b   = (const float*)d_in[17];
    const float* wl     = (const float*)d_in[18];
    const float* bl     = (const float*)d_in[19];
    const float* wout   = (const float*)d_in[20];
    const float* bout   = (const float*)d_in[21];
    float* out = (float*)d_out;

    char* ws = (char*)d_ws;
    size_t off = 0;
    auto alloc = [&](size_t n) -> void* {
        char* p = ws + off;
        off = (off + n + 255) & ~(size_t)255;
        return (void*)p;
    };
    const size_t XBYTES = (size_t)B_ * S_ * D_ * 4;        // 50.33 MB
    const size_t XBF    = XBYTES / 2;                      // 25.17 MB
    float*          pe     = (float*)alloc((size_t)S_ * D_ * 4);
    float*          x      = (float*)alloc(XBYTES);
    __hip_bfloat16* xb     = (__hip_bfloat16*)alloc(XBF);
    __hip_bfloat16* r_bf   = (__hip_bfloat16*)alloc(XBF);  // residual branch
    char*           arena  = (char*)alloc(4 * XBF);        // 100.66 MB
    __hip_bfloat16* qkv_bf = (__hip_bfloat16*)arena;       // [M][2304]
    __hip_bfloat16* av_bf  = (__hip_bfloat16*)(arena + 3 * XBF);
    __hip_bfloat16* h_bf   = (__hip_bfloat16*)arena;       // [M][3072] aliases qkv+av
    __hip_bfloat16* wT     = (__hip_bfloat16*)alloc((size_t)L_ * 7077888 * 2);
    float*          qkvbias= (float*)alloc((size_t)L_ * QKVSTR * 4);
    float*          pooled = (float*)alloc((size_t)B_ * D_ * 4);
    // total ~260 MB

    const int M = B_ * S_;                                 // 16384
    const size_t DD = (size_t)D_ * D_;
    const size_t DF = (size_t)D_ * FF_;
    const size_t LSTRIDE = 4 * DD + 2 * DF;

    // weights: per layer [qkvT(3*DD) | woT(DD) | w1T(DF) | w2T(DF)]
    transpose_bf16_l<<<dim3(D_ / 32, D_ / 32, L_), 256, 0, stream>>>(
        wq, wT + 0 * DD, D_, D_, DD, LSTRIDE);
    transpose_bf16_l<<<dim3(D_ / 32, D_ / 32, L_), 256, 0, stream>>>(
        wk, wT + 1 * DD, D_, D_, DD, LSTRIDE);
    transpose_bf16_l<<<dim3(D_ / 32, D_ / 32, L_), 256, 0, stream>>>(
        wv, wT + 2 * DD, D_, D_, DD, LSTRIDE);
    transpose_bf16_l<<<dim3(D_ / 32, D_ / 32, L_), 256, 0, stream>>>(
        wo, wT + 3 * DD, D_, D_, DD, LSTRIDE);
    transpose_bf16_l<<<dim3(FF_ / 32, D_ / 32, L_), 256, 0, stream>>>(
        w1, wT + 4 * DD, D_, FF_, DF, LSTRIDE);
    transpose_bf16_l<<<dim3(D_ / 32, FF_ / 32, L_), 256, 0, stream>>>(
        w2, wT + 4 * DD + DF, FF_, D_, DF, LSTRIDE);
    biascat<<<(L_ * QKVSTR) / 256, 256, 0, stream>>>(bq, bk, bv, qkvbias);

    pe_kernel<<<(S_ * D_ + 255) / 256, 256, 0, stream>>>(pe);
    embed_kernel<<<M, 256, 0, stream>>>(tokens, emb, pe, x, xb);

    for (int l = 0; l < L_; l++) {
        __hip_bfloat16* wl_base = wT + (size_t)l * LSTRIDE;
        const ushort* qkvT = (const ushort*)(wl_base + 0 * DD);
        const ushort* woT  = (const ushort*)(wl_base + 3 * DD);
        const ushort* w1T  = (const ushort*)(wl_base + 4 * DD);
        const ushort* w2T  = (const ushort*)(wl_base + 4 * DD + DF);

        gemm256<0><<<dim3((QKVSTR / 256) * (M / 256)), 512, 0, stream>>>(
            (const ushort*)xb, qkvT, qkvbias + (size_t)l * QKVSTR, qkv_bf,
            M, QKVSTR, D_, QKVSTR / 256);

        attn_mfma<<<dim3(S_ / 128, H_, B_), 256, 0, stream>>>(
            (const ushort*)qkv_bf, av_bf);

        gemm256<0><<<dim3((D_ / 256) * (M / 256)), 512, 0, stream>>>(
            (const ushort*)av_bf, woT, bo + l * D_, r_bf, M, D_, D_, D_ / 256);
        add_ln<<<M, 256, 0, stream>>>(x, xb, r_bf, ln1g + l * D_, ln1b + l * D_);

        gemm256<1><<<dim3((FF_ / 256) * (M / 256)), 512, 0, stream>>>(
            (const ushort*)xb, w1T, b1 + l * FF_, h_bf, M, FF_, D_, FF_ / 256);
        gemm256<0><<<dim3((D_ / 256) * (M / 256)), 512, 0, stream>>>(
            (const ushort*)h_bf, w2T, b2 + l * D_, r_bf, M, D_, FF_, D_ / 256);
        add_ln<<<M, 256, 0, stream>>>(x, xb, r_bf, ln2g + l * D_, ln2b + l * D_);
    }

    pool_kernel<<<(B_ * D_) / 256, 256, 0, stream>>>(x, pooled);
    head_kernel<<<B_, 64, 0, stream>>>(pooled, wl, bl, wout, bout, out);
}

// Round 4
// 1935.757 us; speedup vs baseline: 1.2336x; 1.0143x over previous
//
#include <hip/hip_runtime.h>
#include <hip/hip_bf16.h>
#include <math.h>

// ---------------------------------------------------------------------------
// TextTransformer forward on MI355X — Round 8: coalesced GEMM epilogue via
// LDS repack (kills 1.85x HBM write amplification), bf16-only residual
// stream (add_ln/embed/pool traffic halved, vectorized bf16 loads).
// GEMM K-loop and attention unchanged from Round 7.
// B=32 S=512 D=768 H=12 DH=64 FF=3072 L=4.
// ---------------------------------------------------------------------------

#define B_  32
#define S_  512
#define D_  768
#define H_  12
#define DH_ 64
#define FF_ 3072
#define L_  4
#define QKVSTR 2304

typedef __attribute__((ext_vector_type(8))) short short8;   // 8 x bf16
typedef __attribute__((ext_vector_type(4))) short short4v;  // 4 x bf16 (b64)
typedef __attribute__((ext_vector_type(4))) float f32x4;

__device__ __forceinline__ void async16(const void* g, void* l) {
    __builtin_amdgcn_global_load_lds(
        (const __attribute__((address_space(1))) void*)g,
        (__attribute__((address_space(3))) void*)l, 16, 0, 0);
}

__device__ __forceinline__ ushort f2bf(float f) {
    __hip_bfloat16 h = __float2bfloat16(f);
    return __builtin_bit_cast(ushort, h);
}
__device__ __forceinline__ float bflo(uint u) { return __uint_as_float(u << 16); }
__device__ __forceinline__ float bfhi(uint u) { return __uint_as_float(u & 0xffff0000u); }

// multiply a bf16 by 0.125 exactly: exponent -= 3 (flush tiny to signed 0)
__device__ __forceinline__ short8 scale8_eighth(short8 v) {
    short8 r;
#pragma unroll
    for (int e = 0; e < 8; e++) {
        ushort u = (ushort)v[e];
        ushort ex = u & 0x7f80;
        r[e] = (short)(ex > 0x0180 ? (ushort)(u - 0x0180) : (ushort)(u & 0x8000));
    }
    return r;
}

// ----------------------------- positional encoding -------------------------
__global__ void pe_kernel(float* __restrict__ pe) {
    int idx = blockIdx.x * 256 + threadIdx.x;
    if (idx >= S_ * D_) return;
    int s = idx / D_, j = idx % D_;
    double e = (2.0 * (double)(j >> 1)) / (double)D_;
    double denom = pow(10000.0, e);
    double ang = (double)s / denom;
    pe[idx] = (j & 1) ? (float)cos(ang) : (float)sin(ang);
}

// ----------------------------- embedding + PE ------------------------------
__global__ void embed_kernel(const int* __restrict__ tokens,
                             const float* __restrict__ emb,
                             const float* __restrict__ pe,
                             __hip_bfloat16* __restrict__ xb) {
    int row = blockIdx.x;              // b*S + s
    int s = row & (S_ - 1);
    int tok = tokens[row];
    float scale = sqrtf((float)D_);
    for (int i = threadIdx.x; i < D_; i += 256) {
        float v = emb[(size_t)tok * D_ + i] * scale + pe[s * D_ + i];
        xb[(size_t)row * D_ + i] = __float2bfloat16(v);
    }
}

// ----------------------------- batched weight transpose fp32->bf16 ---------
// out[z][c][r] = (bf16) in[z][r][c].  Grid (C/32, R/32, L).
__global__ __launch_bounds__(256) void transpose_bf16_l(
    const float* __restrict__ in, __hip_bfloat16* __restrict__ out,
    int R, int C, size_t inL, size_t outL)
{
    __shared__ float tile[32][33];
    in  += (size_t)blockIdx.z * inL;
    out += (size_t)blockIdx.z * outL;
    int tx = threadIdx.x & 31, ty = threadIdx.x >> 5;   // 32 x 8
    int c0 = blockIdx.x * 32, r0 = blockIdx.y * 32;
#pragma unroll
    for (int d = 0; d < 32; d += 8)
        tile[ty + d][tx] = in[(size_t)(r0 + ty + d) * C + c0 + tx];
    __syncthreads();
#pragma unroll
    for (int d = 0; d < 32; d += 8)
        out[(size_t)(c0 + ty + d) * R + r0 + tx] = __float2bfloat16(tile[tx][ty + d]);
}

// ----------------------------- qkv bias concat -----------------------------
__global__ void biascat(const float* __restrict__ bq, const float* __restrict__ bk,
                        const float* __restrict__ bv, float* __restrict__ o) {
    int i = blockIdx.x * 256 + threadIdx.x;          // [L_*2304)
    int ll = i / QKVSTR, j = i % QKVSTR;
    o[i] = j < 768 ? bq[ll * 768 + j]
         : j < 1536 ? bk[ll * 768 + j - 768]
                    : bv[ll * 768 + j - 1536];
}

// ----------------------------- 256x256 8-phase bf16 MFMA GEMM --------------
// C[M,N] = A[M,K] @ Bt[N,K]^T + bias[N].  M%256==0, N%256==0, K%128==0.
// 512 threads = 8 waves (2Mx4N); per-wave output 128x64; BK=64, dbuf LDS 128KB.
// T2 swizzle (3-bit): within each 128B LDS row, byte_col ^= ((row&7)<<4),
// applied via inverse-swizzled global SOURCE + swizzled ds_read columns.
// Epilogue: acc -> LDS [256][256] bf16 repack -> coalesced dwordx4 stores
// (512B contiguous per 32-lane half-wave; no HBM write amplification).
#define BAR()   __builtin_amdgcn_s_barrier()
#define LGKM0() asm volatile("s_waitcnt lgkmcnt(0)" ::: "memory")
#define VM4()   asm volatile("s_waitcnt vmcnt(4)" ::: "memory")
#define VM0()   asm volatile("s_waitcnt vmcnt(0)" ::: "memory")

#define STAGE_A(buf, h, kt) do { \
    async16(aSrc[h][0] + (kt) * 64, &lds[(buf) * 2][dOff[h][0]]); \
    async16(aSrc[h][1] + (kt) * 64, &lds[(buf) * 2][dOff[h][1]]); } while (0)
#define STAGE_B(buf, h, kt) do { \
    async16(bSrc[h][0] + (kt) * 64, &lds[(buf) * 2 + 1][dOff[h][0]]); \
    async16(bSrc[h][1] + (kt) * 64, &lds[(buf) * 2 + 1][dOff[h][1]]); } while (0)

#define LDA(buf, m, ks) (*(const short8*)((const char*)(&lds[(buf) * 2][0]) + \
    (size_t)((arow + (m) * 16) * 128 + cswz[ks])))
#define LDB(buf, n, ks) (*(const short8*)((const char*)(&lds[(buf) * 2 + 1][0]) + \
    (size_t)((brow + (n) * 16) * 128 + cswz[ks])))

#define MFMA_Q(mh, nh) do { \
    __builtin_amdgcn_s_setprio(1); \
    _Pragma("unroll") \
    for (int ks_ = 0; ks_ < 2; ks_++) { \
      _Pragma("unroll") \
      for (int n_ = 0; n_ < 2; n_++) { \
        _Pragma("unroll") \
        for (int m_ = 0; m_ < 4; m_++) { \
          acc[(mh) * 4 + m_][(nh) * 2 + n_] = \
              __builtin_amdgcn_mfma_f32_16x16x32_bf16( \
                  a[m_][ks_], b[(nh) * 2 + n_][ks_], \
                  acc[(mh) * 4 + m_][(nh) * 2 + n_], 0, 0, 0); \
        } } } \
    __builtin_amdgcn_s_setprio(0); \
} while (0)

template<int RELU>
__global__ __launch_bounds__(512, 2) void gemm256(
    const ushort* __restrict__ A,   // bf16 [M][K]
    const ushort* __restrict__ Bt,  // bf16 [N][K]
    const float* __restrict__ bias, // fp32 [N]
    __hip_bfloat16* __restrict__ C, // bf16 [M][N]
    int M, int N, int K, int NX)    // NX = N/256
{
    __shared__ alignas(16) ushort lds[4][16384];  // [buf*2 + (0=A,1=B)][256*64]

    int t = threadIdx.x;
    int l = t & 63, w = t >> 6;
    int wmi = w >> 2, wni = w & 3;            // 2 x 4 wave grid
    int lm = l & 15, lo = l >> 4;

    // T1: XCD-aware block swizzle (all our grids are %8 == 0)
    int nwg = gridDim.x;
    int bid = blockIdx.x;
    int lid = (nwg & 7) ? bid : ((bid & 7) * (nwg >> 3) + (bid >> 3));
    int bn = lid % NX, bm = lid / NX;
    int row0 = bm << 8, col0 = bn << 8;

    // staging geometry: thread t stages 16B chunks; LDS dest is linear,
    // global source column is inverse-swizzled: col ^= ((row&7)<<4).
    const ushort* aSrc[2][2];
    const ushort* bSrc[2][2];
    int dOff[2][2];
#pragma unroll
    for (int h = 0; h < 2; h++) {
#pragma unroll
        for (int c = 0; c < 2; c++) {
            int p = h * 16384 + c * 8192 + t * 16;     // byte off in 32KB tile
            int prow = p >> 7;                         // tile row (0..255)
            int scolb = (p & 127) ^ ((prow & 7) << 4); // inverse-swz byte col
            dOff[h][c] = p >> 1;
            aSrc[h][c] = A  + (size_t)(row0 + prow) * K + (scolb >> 1);
            bSrc[h][c] = Bt + (size_t)(col0 + prow) * K + (scolb >> 1);
        }
    }

    // ds_read addressing: fragment rows are ...+lm (mod 16), so row&7 = lm&7
    // is lane-constant; precompute swizzled byte col per ks half.
    int arow = wmi * 128 + lm;
    int brow = wni * 64 + lm;
    int swz = (lm & 7) << 4;
    int cswz[2];
    cswz[0] = (lo * 16) ^ swz;
    cswz[1] = (64 + lo * 16) ^ swz;

    f32x4 acc[8][4];
#pragma unroll
    for (int i = 0; i < 8; i++)
#pragma unroll
        for (int j = 0; j < 4; j++) acc[i][j] = (f32x4){0.f, 0.f, 0.f, 0.f};
    short8 a[4][2], b[4][2];

    const int NK = K >> 6;        // 64-wide K-tiles (even; K%128==0)
    const int NI = NK >> 1;

    // prologue: kt0 fully into buf0; kt1's B-halves into buf1 (12 loads)
    STAGE_A(0, 0, 0); STAGE_A(0, 1, 0);
    STAGE_B(0, 0, 0); STAGE_B(0, 1, 0);
    STAGE_B(1, 0, 1); STAGE_B(1, 1, 1);
    VM4();            // kt0's 8 loads landed; kt1 B (4) still in flight
    BAR();

    for (int i = 0; i < NI; i++) {
        int kt  = 2 * i;
        int ktA = (kt + 2 <= NK - 2) ? kt + 2 : NK - 2;   // clamp: last iter
        int ktB = (kt + 3 <= NK - 1) ? kt + 3 : NK - 1;   // re-stages same data

        // ---- phase 1: Q(0,0) of buf0 | stage A-half0(kt+1) -> buf1
#pragma unroll
        for (int m = 0; m < 4; m++) { a[m][0] = LDA(0, m, 0); a[m][1] = LDA(0, m, 1); }
#pragma unroll
        for (int n = 0; n < 2; n++) { b[n][0] = LDB(0, n, 0); b[n][1] = LDB(0, n, 1); }
        STAGE_A(1, 0, kt + 1);
        BAR(); LGKM0();
        MFMA_Q(0, 0);
        BAR();

        // ---- phase 2: Q(0,1) | stage A-half1(kt+1) -> buf1
#pragma unroll
        for (int n = 0; n < 2; n++) { b[2 + n][0] = LDB(0, 2 + n, 0); b[2 + n][1] = LDB(0, 2 + n, 1); }
        STAGE_A(1, 1, kt + 1);
        BAR(); LGKM0();
        MFMA_Q(0, 1);
        BAR();

        // ---- phase 3: Q(1,0) | stage B-half0(kt+2) -> buf0 (B reads done ph2)
#pragma unroll
        for (int m = 0; m < 4; m++) { a[m][0] = LDA(0, 4 + m, 0); a[m][1] = LDA(0, 4 + m, 1); }
        STAGE_B(0, 0, ktA);
        BAR(); LGKM0();
        MFMA_Q(1, 0);
        BAR();

        // ---- phase 4: Q(1,1) | stage B-half1(kt+2); gate buf1 (kt+1) ready
        STAGE_B(0, 1, ktA);
        BAR(); LGKM0();
        MFMA_Q(1, 1);
        VM4();        // all but ph3/ph4's 4 loads landed -> buf1 complete
        BAR();

        // ---- phase 5: Q(0,0) of buf1 | stage A-half0(kt+2) -> buf0
#pragma unroll
        for (int m = 0; m < 4; m++) { a[m][0] = LDA(1, m, 0); a[m][1] = LDA(1, m, 1); }
#pragma unroll
        for (int n = 0; n < 2; n++) { b[n][0] = LDB(1, n, 0); b[n][1] = LDB(1, n, 1); }
        STAGE_A(0, 0, ktA);
        BAR(); LGKM0();
        MFMA_Q(0, 0);
        BAR();

        // ---- phase 6: Q(0,1) | stage A-half1(kt+2) -> buf0
#pragma unroll
        for (int n = 0; n < 2; n++) { b[2 + n][0] = LDB(1, 2 + n, 0); b[2 + n][1] = LDB(1, 2 + n, 1); }
        STAGE_A(0, 1, ktA);
        BAR(); LGKM0();
        MFMA_Q(0, 1);
        BAR();

        // ---- phase 7: Q(1,0) | stage B-half0(kt+3) -> buf1 (B reads done ph6)
#pragma unroll
        for (int m = 0; m < 4; m++) { a[m][0] = LDA(1, 4 + m, 0); a[m][1] = LDA(1, 4 + m, 1); }
        STAGE_B(1, 0, ktB);
        BAR(); LGKM0();
        MFMA_Q(1, 0);
        BAR();

        // ---- phase 8: Q(1,1) | stage B-half1(kt+3); gate buf0 (kt+2) ready
        STAGE_B(1, 1, ktB);
        BAR(); LGKM0();
        MFMA_Q(1, 1);
        VM0();        // drain ALL in-flight loads: LDS is reused by epilogue
        BAR();
    }

    // ---- epilogue: acc -> LDS bf16 [256][256] -> coalesced dwordx4 stores
    ushort* eL = &lds[0][0];                      // 128 KB, exactly the tile
    {
        int crow = wmi * 128;                     // tile-local
        int ccol = wni * 64;
#pragma unroll
        for (int n = 0; n < 4; n++) {
            int c = ccol + n * 16 + lm;
            float bs = bias[col0 + c];
#pragma unroll
            for (int m = 0; m < 8; m++) {
#pragma unroll
                for (int r = 0; r < 4; r++) {
                    float v = acc[m][n][r] + bs;
                    if (RELU) v = fmaxf(v, 0.f);
                    eL[(crow + m * 16 + lo * 4 + r) * 256 + c] = f2bf(v);
                }
            }
        }
    }
    __syncthreads();
#pragma unroll
    for (int i = 0; i < 16; i++) {
        int byteoff = i * 8192 + t * 16;          // 512 thr x 16B = 8KB/pass
        int rr = byteoff >> 9;                    // tile row (512B rows)
        int cc = (byteoff & 511) >> 1;            // ushort col
        uint4 v = *(const uint4*)((const char*)eL + byteoff);
        *(uint4*)(C + (size_t)(row0 + rr) * N + col0 + cc) = v;
    }
    (void)M;
}

// ----------------------------- MFMA flash attention (operand-swapped) ------
// Block: (qt of 128 rows, h, b); 4 waves; wave w owns q-rows wm=w*32..+32.
// S^T = mfma(A=K, B=Q/8): lane(lm,lq) holds S^T[s=sblk*16+lq*4+r][q=qblk*16+lm]
//   -> softmax column q is lane-local across (sblk,r); cross-lane reduce is
//      shfl_xor 16/32 only (lanes sharing lm).
// P^T C-layout stores r-consecutive s -> sPw[q][s] via b64 writes.
// O^T = mfma(A=Vt, B=P): lane holds O^T[d=dblk*16+lq*4+r][q=qblk*16+lm]
//   -> epilogue writes 4 consecutive d per lane = global b64 stores.
// sP aliases sQ (Q register-resident after prologue). LDS ~36.9 KB.
#define PSTR 72
__global__ __launch_bounds__(256) void attn_mfma(
    const ushort* __restrict__ qkv,
    __hip_bfloat16* __restrict__ av)
{
    __shared__ alignas(16) ushort sQP[128 * PSTR];   // Q tile, then P (per-wave)
    __shared__ alignas(16) ushort sK[64 * PSTR];
    __shared__ alignas(16) ushort sVt[64 * PSTR];    // Vt[d][s]

    int t = threadIdx.x;
    int qt = blockIdx.x, h = blockIdx.y, b = blockIdx.z;
    int w = t >> 6, l = t & 63;
    int lm = l & 15, lq = l >> 4;
    int wm = w * 32;

    const ushort* qbase = qkv + (size_t)(b * S_ + qt * 128) * QKVSTR + h * DH_;
    const ushort* kbase = qkv + (size_t)b * S_ * QKVSTR + 768 + h * DH_;
    const ushort* vbase = qkv + (size_t)b * S_ * QKVSTR + 1536 + h * DH_;

    // stage Q tile [128][64]
    {
        int r = t >> 1, c0 = (t & 1) * 32;
        const ushort* src = qbase + (size_t)r * QKVSTR + c0;
        ushort* dst = &sQP[r * PSTR + c0];
        *(uint4*)(dst + 0)  = *(const uint4*)(src + 0);
        *(uint4*)(dst + 8)  = *(const uint4*)(src + 8);
        *(uint4*)(dst + 16) = *(const uint4*)(src + 16);
        *(uint4*)(dst + 24) = *(const uint4*)(src + 24);
    }
    __syncthreads();
    short8 qf[2][2];   // [qblk][ks] — B-fragments (Q/8)
#pragma unroll
    for (int i = 0; i < 2; i++)
#pragma unroll
        for (int ks = 0; ks < 2; ks++)
            qf[i][ks] = scale8_eighth(
                *(const short8*)&sQP[(wm + i * 16 + lm) * PSTR + ks * 32 + lq * 8]);

    ushort* sPw = &sQP[(size_t)wm * PSTR];           // wave-local P region [32q][64s]

    f32x4 accO[4][2];          // O^T: [dblk][qblk]
    float mrun[2], lrun[2];    // per q-col (q = qblk*16+lm)
#pragma unroll
    for (int dk = 0; dk < 4; dk++)
#pragma unroll
        for (int i = 0; i < 2; i++) accO[dk][i] = (f32x4){0.f, 0.f, 0.f, 0.f};
    mrun[0] = mrun[1] = -1e30f;
    lrun[0] = lrun[1] = 0.f;

    for (int kt = 0; kt < S_ / 64; kt++) {
        __syncthreads();   // prior reads of sK/sVt done; first iter: qf loads done
        {
            // K stage: thread t covers row r = t>>2, 32B chunk (t&3)
            int r = t >> 2, c0 = (t & 3) * 16;
            const ushort* ksrc = kbase + (size_t)(kt * 64 + r) * QKVSTR + c0;
            ushort* kdst = &sK[r * PSTR + c0];
            *(uint4*)(kdst + 0) = *(const uint4*)(ksrc + 0);
            *(uint4*)(kdst + 8) = *(const uint4*)(ksrc + 8);
            // V stage (transposed, vectorized): thread t covers s-pair p=t&31,
            // d-chunk d0=(t>>5)*8; writes 8 x b32 (ushort2), banks (4j+p)%32.
            int p = t & 31, d0 = (t >> 5) * 8;
            const ushort* vsrc = vbase + (size_t)(kt * 64 + 2 * p) * QKVSTR + d0;
            uint4 v0 = *(const uint4*)(vsrc);
            uint4 v1 = *(const uint4*)(vsrc + QKVSTR);
            const ushort* e0 = (const ushort*)&v0;
            const ushort* e1 = (const ushort*)&v1;
#pragma unroll
            for (int j = 0; j < 8; j++) {
                uint pk = (uint)e0[j] | ((uint)e1[j] << 16);
                *(uint*)&sVt[(d0 + j) * PSTR + 2 * p] = pk;
            }
        }
        __syncthreads();

        // S^T = K (Q/8):  accS[sblk][qblk]
        f32x4 accS[4][2];
#pragma unroll
        for (int sb = 0; sb < 4; sb++)
#pragma unroll
            for (int i = 0; i < 2; i++) accS[sb][i] = (f32x4){0.f, 0.f, 0.f, 0.f};
#pragma unroll
        for (int ks = 0; ks < 2; ks++) {
#pragma unroll
            for (int sb = 0; sb < 4; sb++) {
                short8 kf = *(const short8*)&sK[(sb * 16 + lm) * PSTR + ks * 32 + lq * 8];
#pragma unroll
                for (int i = 0; i < 2; i++)
                    accS[sb][i] = __builtin_amdgcn_mfma_f32_16x16x32_bf16(
                        kf, qf[i][ks], accS[sb][i], 0, 0, 0);
            }
        }

        // online softmax over s (lane-local + 2-round shfl across lq groups)
        float pmax[2];
#pragma unroll
        for (int i = 0; i < 2; i++) {
            float m0 = accS[0][i][0];
#pragma unroll
            for (int sb = 0; sb < 4; sb++)
#pragma unroll
                for (int r = 0; r < 4; r++) m0 = fmaxf(m0, accS[sb][i][r]);
            m0 = fmaxf(m0, __shfl_xor(m0, 16));
            m0 = fmaxf(m0, __shfl_xor(m0, 32));
            pmax[i] = m0;
        }
        float alpha[2];
#pragma unroll
        for (int i = 0; i < 2; i++) {
            float mn = fmaxf(mrun[i], pmax[i]);
            alpha[i] = __expf(mrun[i] - mn);
            mrun[i] = mn;
        }
        float rsum[2] = {0.f, 0.f};
#pragma unroll
        for (int sb = 0; sb < 4; sb++)
#pragma unroll
            for (int i = 0; i < 2; i++)
#pragma unroll
                for (int r = 0; r < 4; r++) {
                    float p = __expf(accS[sb][i][r] - mrun[i]);
                    accS[sb][i][r] = p;
                    rsum[i] += p;
                }
#pragma unroll
        for (int i = 0; i < 2; i++) {
            rsum[i] += __shfl_xor(rsum[i], 16);
            rsum[i] += __shfl_xor(rsum[i], 32);
            lrun[i] = lrun[i] * alpha[i] + rsum[i];
        }

        // rescale O^T
#pragma unroll
        for (int dk = 0; dk < 4; dk++)
#pragma unroll
            for (int i = 0; i < 2; i++)
#pragma unroll
                for (int r = 0; r < 4; r++) accO[dk][i][r] *= alpha[i];

        // P^T C-layout -> sPw[q][s]: 4 r-consecutive s per (qblk,sblk) = b64
#pragma unroll
        for (int i = 0; i < 2; i++)
#pragma unroll
            for (int sb = 0; sb < 4; sb++) {
                short4v pk;
#pragma unroll
                for (int r = 0; r < 4; r++) pk[r] = (short)f2bf(accS[sb][i][r]);
                *(short4v*)&sPw[(i * 16 + lm) * PSTR + sb * 16 + lq * 4] = pk;
            }

        // O^T += V^T P^T  (A = Vt rows, B = sPw rows; wave-local, no barrier)
#pragma unroll
        for (int ks = 0; ks < 2; ks++) {
            short8 pf[2];
#pragma unroll
            for (int i = 0; i < 2; i++)
                pf[i] = *(const short8*)&sPw[(i * 16 + lm) * PSTR + ks * 32 + lq * 8];
#pragma unroll
            for (int dk = 0; dk < 4; dk++) {
                short8 vf = *(const short8*)&sVt[(dk * 16 + lm) * PSTR + ks * 32 + lq * 8];
#pragma unroll
                for (int i = 0; i < 2; i++)
                    accO[dk][i] = __builtin_amdgcn_mfma_f32_16x16x32_bf16(
                        vf, pf[i], accO[dk][i], 0, 0, 0);
            }
        }
    }

    // epilogue: O = (O^T)^T / l, vector b64 stores (4 consecutive d per lane)
    float invl[2];
    invl[0] = 1.0f / lrun[0];
    invl[1] = 1.0f / lrun[1];
#pragma unroll
    for (int i = 0; i < 2; i++) {
        int row = qt * 128 + wm + i * 16 + lm;
        __hip_bfloat16* dst = av + (size_t)(b * S_ + row) * D_ + h * DH_;
#pragma unroll
        for (int dk = 0; dk < 4; dk++) {
            short4v ok;
#pragma unroll
            for (int r = 0; r < 4; r++) ok[r] = (short)f2bf(accO[dk][i][r] * invl[i]);
            *(short4v*)(dst + dk * 16 + lq * 4) = ok;
        }
    }
}

// ----------------------------- residual + layernorm (bf16 stream) ----------
// xb <- LN(xb + r) in bf16; all loads/stores as packed 2xbf16 (uint).
// Thread t handles elems {2t,2t+1} and, for t<128, {512+2t, 512+2t+1}.
__global__ __launch_bounds__(256) void add_ln(
    __hip_bfloat16* __restrict__ xb,
    const __hip_bfloat16* __restrict__ r, const float* __restrict__ g,
    const float* __restrict__ bta)
{
    __shared__ float sred[256];
    int row = blockIdx.x, t = threadIdx.x;
    uint* xu = (uint*)(xb + (size_t)row * D_);
    const uint* ru = (const uint*)(r + (size_t)row * D_);
    uint ux0 = xu[t], ur0 = ru[t];
    float a0 = bflo(ux0) + bflo(ur0);
    float a1 = bfhi(ux0) + bfhi(ur0);
    float a2 = 0.f, a3 = 0.f;
    if (t < 128) {
        uint ux1 = xu[256 + t], ur1 = ru[256 + t];
        a2 = bflo(ux1) + bflo(ur1);
        a3 = bfhi(ux1) + bfhi(ur1);
    }
    sred[t] = a0 + a1 + a2 + a3;
    __syncthreads();
    for (int o = 128; o > 0; o >>= 1) { if (t < o) sred[t] += sred[t + o]; __syncthreads(); }
    float mean = sred[0] * (1.0f / D_);
    __syncthreads();
    float d0 = a0 - mean, d1 = a1 - mean;
    float d2 = a2 - mean, d3 = a3 - mean;
    sred[t] = d0 * d0 + d1 * d1 + (t < 128 ? d2 * d2 + d3 * d3 : 0.f);
    __syncthreads();
    for (int o = 128; o > 0; o >>= 1) { if (t < o) sred[t] += sred[t + o]; __syncthreads(); }
    float rstd = rsqrtf(sred[0] * (1.0f / D_) + 1e-6f);
    {
        float2 gv = ((const float2*)g)[t];
        float2 bv = ((const float2*)bta)[t];
        float o0 = gv.x * d0 * rstd + bv.x;
        float o1 = gv.y * d1 * rstd + bv.y;
        xu[t] = (uint)f2bf(o0) | ((uint)f2bf(o1) << 16);
    }
    if (t < 128) {
        float2 gv = ((const float2*)g)[256 + t];
        float2 bv = ((const float2*)bta)[256 + t];
        float o2 = gv.x * d2 * rstd + bv.x;
        float o3 = gv.y * d3 * rstd + bv.y;
        xu[256 + t] = (uint)f2bf(o2) | ((uint)f2bf(o3) << 16);
    }
}

// ----------------------------- mean pool over S (bf16 in) ------------------
__global__ void pool_kernel(const __hip_bfloat16* __restrict__ xb,
                            float* __restrict__ pooled) {
    int idx = blockIdx.x * 256 + threadIdx.x;   // b*768 + d
    int b = idx / D_, d = idx % D_;
    float acc = 0.f;
    const __hip_bfloat16* p = xb + (size_t)b * S_ * D_ + d;
    for (int s = 0; s < S_; s++) acc += __bfloat162float(p[(size_t)s * D_]);
    pooled[idx] = acc * (1.0f / S_);
}

// ----------------------------- classifier head -----------------------------
__global__ void head_kernel(const float* __restrict__ pooled,
                            const float* __restrict__ wl,
                            const float* __restrict__ bl,
                            const float* __restrict__ wout,
                            const float* __restrict__ bout,
                            float* __restrict__ out)
{
    __shared__ float hb[32];
    int b = blockIdx.x, t = threadIdx.x;
    if (t < 32) {
        float z = bl[t];
        for (int d = 0; d < D_; d++) z += pooled[b * D_ + d] * wl[d * 32 + t];
        hb[t] = 0.5f * z * (1.0f + erff(z * 0.70710678118654752f));
    }
    __syncthreads();
    if (t == 0) {
        float z = bout[0];
        for (int j = 0; j < 32; j++) z += hb[j] * wout[j];
        out[b] = 1.0f / (1.0f + expf(-z));
    }
}

// ---------------------------------------------------------------------------
extern "C" void kernel_launch(void* const* d_in, const int* in_sizes, int n_in,
                              void* d_out, int out_size, void* d_ws, size_t ws_size,
                              hipStream_t stream)
{
    (void)in_sizes; (void)n_in; (void)out_size; (void)ws_size;
    const int*   tokens = (const int*)  d_in[0];
    const float* emb    = (const float*)d_in[1];
    const float* wq     = (const float*)d_in[2];
    const float* bq     = (const float*)d_in[3];
    const float* wk     = (const float*)d_in[4];
    const float* bk     = (const float*)d_in[5];
    const float* wv     = (const float*)d_in[6];
    const float* bv     = (const float*)d_in[7];
    const float* wo     = (const float*)d_in[8];
    const float* bo     = (const float*)d_in[9];
    const float* w1     = (const float*)d_in[10];
    const float* b1     = (const float*)d_in[11];
    const float* w2     = (const float*)d_in[12];
    const float* b2     = (const float*)d_in[13];
    const float* ln1g   = (const float*)d_in[14];
    const float* ln1b   = (const float*)d_in[15];
    const float* ln2g   = (const float*)d_in[16];
    const float* ln2b   = (const float*)d_in[17];
    const float* wl     = (const float*)d_in[18];
    const float* bl     = (const float*)d_in[19];
    const float* wout   = (const float*)d_in[20];
    const float* bout   = (const float*)d_in[21];
    float* out = (float*)d_out;

    char* ws = (char*)d_ws;
    size_t off = 0;
    auto alloc = [&](size_t n) -> void* {
        char* p = ws + off;
        off = (off + n + 255) & ~(size_t)255;
        return (void*)p;
    };
    const size_t XBYTES = (size_t)B_ * S_ * D_ * 4;        // 50.33 MB
    const size_t XBF    = XBYTES / 2;                      // 25.17 MB
    float*          pe     = (float*)alloc((size_t)S_ * D_ * 4);
    __hip_bfloat16* xb     = (__hip_bfloat16*)alloc(XBF);
    __hip_bfloat16* r_bf   = (__hip_bfloat16*)alloc(XBF);  // residual branch
    char*           arena  = (char*)alloc(4 * XBF);        // 100.66 MB
    __hip_bfloat16* qkv_bf = (__hip_bfloat16*)arena;       // [M][2304]
    __hip_bfloat16* av_bf  = (__hip_bfloat16*)(arena + 3 * XBF);
    __hip_bfloat16* h_bf   = (__hip_bfloat16*)arena;       // [M][3072] aliases qkv+av
    __hip_bfloat16* wT     = (__hip_bfloat16*)alloc((size_t)L_ * 7077888 * 2);
    float*          qkvbias= (float*)alloc((size_t)L_ * QKVSTR * 4);
    float*          pooled = (float*)alloc((size_t)B_ * D_ * 4);

    const int M = B_ * S_;                                 // 16384
    const size_t DD = (size_t)D_ * D_;
    const size_t DF = (size_t)D_ * FF_;
    const size_t LSTRIDE = 4 * DD + 2 * DF;

    // weights: per layer [qkvT(3*DD) | woT(DD) | w1T(DF) | w2T(DF)]
    transpose_bf16_l<<<dim3(D_ / 32, D_ / 32, L_), 256, 0, stream>>>(
        wq, wT + 0 * DD, D_, D_, DD, LSTRIDE);
    transpose_bf16_l<<<dim3(D_ / 32, D_ / 32, L_), 256, 0, stream>>>(
        wk, wT + 1 * DD, D_, D_, DD, LSTRIDE);
    transpose_bf16_l<<<dim3(D_ / 32, D_ / 32, L_), 256, 0, stream>>>(
        wv, wT + 2 * DD, D_, D_, DD, LSTRIDE);
    transpose_bf16_l<<<dim3(D_ / 32, D_ / 32, L_), 256, 0, stream>>>(
        wo, wT + 3 * DD, D_, D_, DD, LSTRIDE);
    transpose_bf16_l<<<dim3(FF_ / 32, D_ / 32, L_), 256, 0, stream>>>(
        w1, wT + 4 * DD, D_, FF_, DF, LSTRIDE);
    transpose_bf16_l<<<dim3(D_ / 32, FF_ / 32, L_), 256, 0, stream>>>(
        w2, wT + 4 * DD + DF, FF_, D_, DF, LSTRIDE);
    biascat<<<(L_ * QKVSTR) / 256, 256, 0, stream>>>(bq, bk, bv, qkvbias);

    pe_kernel<<<(S_ * D_ + 255) / 256, 256, 0, stream>>>(pe);
    embed_kernel<<<M, 256, 0, stream>>>(tokens, emb, pe, xb);

    for (int l = 0; l < L_; l++) {
        __hip_bfloat16* wl_base = wT + (size_t)l * LSTRIDE;
        const ushort* qkvT = (const ushort*)(wl_base + 0 * DD);
        const ushort* woT  = (const ushort*)(wl_base + 3 * DD);
        const ushort* w1T  = (const ushort*)(wl_base + 4 * DD);
        const ushort* w2T  = (const ushort*)(wl_base + 4 * DD + DF);

        gemm256<0><<<dim3((QKVSTR / 256) * (M / 256)), 512, 0, stream>>>(
            (const ushort*)xb, qkvT, qkvbias + (size_t)l * QKVSTR, qkv_bf,
            M, QKVSTR, D_, QKVSTR / 256);

        attn_mfma<<<dim3(S_ / 128, H_, B_), 256, 0, stream>>>(
            (const ushort*)qkv_bf, av_bf);

        gemm256<0><<<dim3((D_ / 256) * (M / 256)), 512, 0, stream>>>(
            (const ushort*)av_bf, woT, bo + l * D_, r_bf, M, D_, D_, D_ / 256);
        add_ln<<<M, 256, 0, stream>>>(xb, r_bf, ln1g + l * D_, ln1b + l * D_);

        gemm256<1><<<dim3((FF_ / 256) * (M / 256)), 512, 0, stream>>>(
            (const ushort*)xb, w1T, b1 + l * FF_, h_bf, M, FF_, D_, FF_ / 256);
        gemm256<0><<<dim3((D_ / 256) * (M / 256)), 512, 0, stream>>>(
            (const ushort*)h_bf, w2T, b2 + l * D_, r_bf, M, D_, FF_, D_ / 256);
        add_ln<<<M, 256, 0, stream>>>(xb, r_bf, ln2g + l * D_, ln2b + l * D_);
    }

    pool_kernel<<<(B_ * D_) / 256, 256, 0, stream>>>(xb, pooled);
    head_kernel<<<B_, 64, 0, stream>>>(pooled, wl, bl, wout, bout, out);
}

// Round 6
// 1885.729 us; speedup vs baseline: 1.2663x; 1.0265x over previous
//
#include <hip/hip_runtime.h>
#include <hip/hip_bf16.h>
#include <math.h>

// ---------------------------------------------------------------------------
// TextTransformer forward on MI355X — Round 9 (resubmit; R5 bench was an
// infra timeout): fix T4 regression (drain0 was inside the K-loop in R8;
// restore VM4, single VM0 after loop) + swizzle the epilogue LDS repack
// (4-way floor). Everything else unchanged from R8.
// B=32 S=512 D=768 H=12 DH=64 FF=3072 L=4.
// ---------------------------------------------------------------------------

#define B_  32
#define S_  512
#define D_  768
#define H_  12
#define DH_ 64
#define FF_ 3072
#define L_  4
#define QKVSTR 2304

typedef __attribute__((ext_vector_type(8))) short short8;   // 8 x bf16
typedef __attribute__((ext_vector_type(4))) short short4v;  // 4 x bf16 (b64)
typedef __attribute__((ext_vector_type(4))) float f32x4;

__device__ __forceinline__ void async16(const void* g, void* l) {
    __builtin_amdgcn_global_load_lds(
        (const __attribute__((address_space(1))) void*)g,
        (__attribute__((address_space(3))) void*)l, 16, 0, 0);
}

__device__ __forceinline__ ushort f2bf(float f) {
    __hip_bfloat16 h = __float2bfloat16(f);
    return __builtin_bit_cast(ushort, h);
}
__device__ __forceinline__ float bflo(uint u) { return __uint_as_float(u << 16); }
__device__ __forceinline__ float bfhi(uint u) { return __uint_as_float(u & 0xffff0000u); }

// multiply a bf16 by 0.125 exactly: exponent -= 3 (flush tiny to signed 0)
__device__ __forceinline__ short8 scale8_eighth(short8 v) {
    short8 r;
#pragma unroll
    for (int e = 0; e < 8; e++) {
        ushort u = (ushort)v[e];
        ushort ex = u & 0x7f80;
        r[e] = (short)(ex > 0x0180 ? (ushort)(u - 0x0180) : (ushort)(u & 0x8000));
    }
    return r;
}

// ----------------------------- positional encoding -------------------------
__global__ void pe_kernel(float* __restrict__ pe) {
    int idx = blockIdx.x * 256 + threadIdx.x;
    if (idx >= S_ * D_) return;
    int s = idx / D_, j = idx % D_;
    double e = (2.0 * (double)(j >> 1)) / (double)D_;
    double denom = pow(10000.0, e);
    double ang = (double)s / denom;
    pe[idx] = (j & 1) ? (float)cos(ang) : (float)sin(ang);
}

// ----------------------------- embedding + PE ------------------------------
__global__ void embed_kernel(const int* __restrict__ tokens,
                             const float* __restrict__ emb,
                             const float* __restrict__ pe,
                             __hip_bfloat16* __restrict__ xb) {
    int row = blockIdx.x;              // b*S + s
    int s = row & (S_ - 1);
    int tok = tokens[row];
    float scale = sqrtf((float)D_);
    for (int i = threadIdx.x; i < D_; i += 256) {
        float v = emb[(size_t)tok * D_ + i] * scale + pe[s * D_ + i];
        xb[(size_t)row * D_ + i] = __float2bfloat16(v);
    }
}

// ----------------------------- batched weight transpose fp32->bf16 ---------
// out[z][c][r] = (bf16) in[z][r][c].  Grid (C/32, R/32, L).
__global__ __launch_bounds__(256) void transpose_bf16_l(
    const float* __restrict__ in, __hip_bfloat16* __restrict__ out,
    int R, int C, size_t inL, size_t outL)
{
    __shared__ float tile[32][33];
    in  += (size_t)blockIdx.z * inL;
    out += (size_t)blockIdx.z * outL;
    int tx = threadIdx.x & 31, ty = threadIdx.x >> 5;   // 32 x 8
    int c0 = blockIdx.x * 32, r0 = blockIdx.y * 32;
#pragma unroll
    for (int d = 0; d < 32; d += 8)
        tile[ty + d][tx] = in[(size_t)(r0 + ty + d) * C + c0 + tx];
    __syncthreads();
#pragma unroll
    for (int d = 0; d < 32; d += 8)
        out[(size_t)(c0 + ty + d) * R + r0 + tx] = __float2bfloat16(tile[tx][ty + d]);
}

// ----------------------------- qkv bias concat -----------------------------
__global__ void biascat(const float* __restrict__ bq, const float* __restrict__ bk,
                        const float* __restrict__ bv, float* __restrict__ o) {
    int i = blockIdx.x * 256 + threadIdx.x;          // [L_*2304)
    int ll = i / QKVSTR, j = i % QKVSTR;
    o[i] = j < 768 ? bq[ll * 768 + j]
         : j < 1536 ? bk[ll * 768 + j - 768]
                    : bv[ll * 768 + j - 1536];
}

// ----------------------------- 256x256 8-phase bf16 MFMA GEMM --------------
// C[M,N] = A[M,K] @ Bt[N,K]^T + bias[N].  M%256==0, N%256==0, K%128==0.
// 512 threads = 8 waves (2Mx4N); per-wave output 128x64; BK=64, dbuf LDS 128KB.
// T2 swizzle (3-bit): within each 128B LDS row, byte_col ^= ((row&7)<<4),
// applied via inverse-swizzled global SOURCE + swizzled ds_read columns.
// Counted vmcnt(4) at phases 4/8 (T4); single vmcnt(0) drain AFTER the loop
// (epilogue reuses LDS). Epilogue repack swizzled (ushort idx ^ (row&7)<<3).
#define BAR()   __builtin_amdgcn_s_barrier()
#define LGKM0() asm volatile("s_waitcnt lgkmcnt(0)" ::: "memory")
#define VM4()   asm volatile("s_waitcnt vmcnt(4)" ::: "memory")
#define VM0()   asm volatile("s_waitcnt vmcnt(0)" ::: "memory")

#define STAGE_A(buf, h, kt) do { \
    async16(aSrc[h][0] + (kt) * 64, &lds[(buf) * 2][dOff[h][0]]); \
    async16(aSrc[h][1] + (kt) * 64, &lds[(buf) * 2][dOff[h][1]]); } while (0)
#define STAGE_B(buf, h, kt) do { \
    async16(bSrc[h][0] + (kt) * 64, &lds[(buf) * 2 + 1][dOff[h][0]]); \
    async16(bSrc[h][1] + (kt) * 64, &lds[(buf) * 2 + 1][dOff[h][1]]); } while (0)

#define LDA(buf, m, ks) (*(const short8*)((const char*)(&lds[(buf) * 2][0]) + \
    (size_t)((arow + (m) * 16) * 128 + cswz[ks])))
#define LDB(buf, n, ks) (*(const short8*)((const char*)(&lds[(buf) * 2 + 1][0]) + \
    (size_t)((brow + (n) * 16) * 128 + cswz[ks])))

#define MFMA_Q(mh, nh) do { \
    __builtin_amdgcn_s_setprio(1); \
    _Pragma("unroll") \
    for (int ks_ = 0; ks_ < 2; ks_++) { \
      _Pragma("unroll") \
      for (int n_ = 0; n_ < 2; n_++) { \
        _Pragma("unroll") \
        for (int m_ = 0; m_ < 4; m_++) { \
          acc[(mh) * 4 + m_][(nh) * 2 + n_] = \
              __builtin_amdgcn_mfma_f32_16x16x32_bf16( \
                  a[m_][ks_], b[(nh) * 2 + n_][ks_], \
                  acc[(mh) * 4 + m_][(nh) * 2 + n_], 0, 0, 0); \
        } } } \
    __builtin_amdgcn_s_setprio(0); \
} while (0)

template<int RELU>
__global__ __launch_bounds__(512, 2) void gemm256(
    const ushort* __restrict__ A,   // bf16 [M][K]
    const ushort* __restrict__ Bt,  // bf16 [N][K]
    const float* __restrict__ bias, // fp32 [N]
    __hip_bfloat16* __restrict__ C, // bf16 [M][N]
    int M, int N, int K, int NX)    // NX = N/256
{
    __shared__ alignas(16) ushort lds[4][16384];  // [buf*2 + (0=A,1=B)][256*64]

    int t = threadIdx.x;
    int l = t & 63, w = t >> 6;
    int wmi = w >> 2, wni = w & 3;            // 2 x 4 wave grid
    int lm = l & 15, lo = l >> 4;

    // T1: XCD-aware block swizzle (all our grids are %8 == 0)
    int nwg = gridDim.x;
    int bid = blockIdx.x;
    int lid = (nwg & 7) ? bid : ((bid & 7) * (nwg >> 3) + (bid >> 3));
    int bn = lid % NX, bm = lid / NX;
    int row0 = bm << 8, col0 = bn << 8;

    // staging geometry: thread t stages 16B chunks; LDS dest is linear,
    // global source column is inverse-swizzled: col ^= ((row&7)<<4).
    const ushort* aSrc[2][2];
    const ushort* bSrc[2][2];
    int dOff[2][2];
#pragma unroll
    for (int h = 0; h < 2; h++) {
#pragma unroll
        for (int c = 0; c < 2; c++) {
            int p = h * 16384 + c * 8192 + t * 16;     // byte off in 32KB tile
            int prow = p >> 7;                         // tile row (0..255)
            int scolb = (p & 127) ^ ((prow & 7) << 4); // inverse-swz byte col
            dOff[h][c] = p >> 1;
            aSrc[h][c] = A  + (size_t)(row0 + prow) * K + (scolb >> 1);
            bSrc[h][c] = Bt + (size_t)(col0 + prow) * K + (scolb >> 1);
        }
    }

    // ds_read addressing: fragment rows are ...+lm (mod 16), so row&7 = lm&7
    // is lane-constant; precompute swizzled byte col per ks half.
    int arow = wmi * 128 + lm;
    int brow = wni * 64 + lm;
    int swz = (lm & 7) << 4;
    int cswz[2];
    cswz[0] = (lo * 16) ^ swz;
    cswz[1] = (64 + lo * 16) ^ swz;

    f32x4 acc[8][4];
#pragma unroll
    for (int i = 0; i < 8; i++)
#pragma unroll
        for (int j = 0; j < 4; j++) acc[i][j] = (f32x4){0.f, 0.f, 0.f, 0.f};
    short8 a[4][2], b[4][2];

    const int NK = K >> 6;        // 64-wide K-tiles (even; K%128==0)
    const int NI = NK >> 1;

    // prologue: kt0 fully into buf0; kt1's B-halves into buf1 (12 loads)
    STAGE_A(0, 0, 0); STAGE_A(0, 1, 0);
    STAGE_B(0, 0, 0); STAGE_B(0, 1, 0);
    STAGE_B(1, 0, 1); STAGE_B(1, 1, 1);
    VM4();            // kt0's 8 loads landed; kt1 B (4) still in flight
    BAR();

    for (int i = 0; i < NI; i++) {
        int kt  = 2 * i;
        int ktA = (kt + 2 <= NK - 2) ? kt + 2 : NK - 2;   // clamp: last iter
        int ktB = (kt + 3 <= NK - 1) ? kt + 3 : NK - 1;   // re-stages same data

        // ---- phase 1: Q(0,0) of buf0 | stage A-half0(kt+1) -> buf1
#pragma unroll
        for (int m = 0; m < 4; m++) { a[m][0] = LDA(0, m, 0); a[m][1] = LDA(0, m, 1); }
#pragma unroll
        for (int n = 0; n < 2; n++) { b[n][0] = LDB(0, n, 0); b[n][1] = LDB(0, n, 1); }
        STAGE_A(1, 0, kt + 1);
        BAR(); LGKM0();
        MFMA_Q(0, 0);
        BAR();

        // ---- phase 2: Q(0,1) | stage A-half1(kt+1) -> buf1
#pragma unroll
        for (int n = 0; n < 2; n++) { b[2 + n][0] = LDB(0, 2 + n, 0); b[2 + n][1] = LDB(0, 2 + n, 1); }
        STAGE_A(1, 1, kt + 1);
        BAR(); LGKM0();
        MFMA_Q(0, 1);
        BAR();

        // ---- phase 3: Q(1,0) | stage B-half0(kt+2) -> buf0 (B reads done ph2)
#pragma unroll
        for (int m = 0; m < 4; m++) { a[m][0] = LDA(0, 4 + m, 0); a[m][1] = LDA(0, 4 + m, 1); }
        STAGE_B(0, 0, ktA);
        BAR(); LGKM0();
        MFMA_Q(1, 0);
        BAR();

        // ---- phase 4: Q(1,1) | stage B-half1(kt+2); gate buf1 (kt+1) ready
        STAGE_B(0, 1, ktA);
        BAR(); LGKM0();
        MFMA_Q(1, 1);
        VM4();        // all but ph3/ph4's 4 loads landed -> buf1 complete
        BAR();

        // ---- phase 5: Q(0,0) of buf1 | stage A-half0(kt+2) -> buf0
#pragma unroll
        for (int m = 0; m < 4; m++) { a[m][0] = LDA(1, m, 0); a[m][1] = LDA(1, m, 1); }
#pragma unroll
        for (int n = 0; n < 2; n++) { b[n][0] = LDB(1, n, 0); b[n][1] = LDB(1, n, 1); }
        STAGE_A(0, 0, ktA);
        BAR(); LGKM0();
        MFMA_Q(0, 0);
        BAR();

        // ---- phase 6: Q(0,1) | stage A-half1(kt+2) -> buf0
#pragma unroll
        for (int n = 0; n < 2; n++) { b[2 + n][0] = LDB(1, 2 + n, 0); b[2 + n][1] = LDB(1, 2 + n, 1); }
        STAGE_A(0, 1, ktA);
        BAR(); LGKM0();
        MFMA_Q(0, 1);
        BAR();

        // ---- phase 7: Q(1,0) | stage B-half0(kt+3) -> buf1 (B reads done ph6)
#pragma unroll
        for (int m = 0; m < 4; m++) { a[m][0] = LDA(1, 4 + m, 0); a[m][1] = LDA(1, 4 + m, 1); }
        STAGE_B(1, 0, ktB);
        BAR(); LGKM0();
        MFMA_Q(1, 0);
        BAR();

        // ---- phase 8: Q(1,1) | stage B-half1(kt+3); gate buf0 (kt+2) ready
        STAGE_B(1, 1, ktB);
        BAR(); LGKM0();
        MFMA_Q(1, 1);
        VM4();        // counted wait (T4): ph7/ph8's 4 loads stay in flight
        BAR();
    }

    // drain once: epilogue reuses the staging LDS. Every wave drains its own
    // vmcnt; barrier ensures all waves' global_load_lds writes have landed.
    VM0();
    BAR();

    // ---- epilogue: acc -> LDS bf16 [256][256] (swizzled) -> coalesced stores
    // swizzle: ushort idx c ^= ((row&7)<<3) (byte bits 4-6); read applies same.
    ushort* eL = &lds[0][0];                      // 128 KB, exactly the tile
    {
        int crow = wmi * 128;                     // tile-local
        int ccol = wni * 64;
#pragma unroll
        for (int n = 0; n < 4; n++) {
            int c = ccol + n * 16 + lm;
            float bs = bias[col0 + c];
#pragma unroll
            for (int m = 0; m < 8; m++) {
#pragma unroll
                for (int r = 0; r < 4; r++) {
                    float v = acc[m][n][r] + bs;
                    if (RELU) v = fmaxf(v, 0.f);
                    int row = crow + m * 16 + lo * 4 + r;
                    int sc = c ^ (((lo * 4 + r) & 7) << 3);
                    eL[row * 256 + sc] = f2bf(v);
                }
            }
        }
    }
    __syncthreads();
    {
        int rsw = ((t >> 5) & 7) << 3;            // rr&7 is thread-constant
#pragma unroll
        for (int i = 0; i < 16; i++) {
            int byteoff = i * 8192 + t * 16;      // 512 thr x 16B = 8KB/pass
            int rr = byteoff >> 9;                // tile row (512B rows)
            int cc = (byteoff & 511) >> 1;        // linear ushort col
            uint4 v = *(const uint4*)(eL + rr * 256 + (cc ^ rsw));
            *(uint4*)(C + (size_t)(row0 + rr) * N + col0 + cc) = v;
        }
    }
    (void)M;
}

// ----------------------------- MFMA flash attention (operand-swapped) ------
// Block: (qt of 128 rows, h, b); 4 waves; wave w owns q-rows wm=w*32..+32.
// S^T = mfma(A=K, B=Q/8): lane(lm,lq) holds S^T[s=sblk*16+lq*4+r][q=qblk*16+lm]
//   -> softmax column q is lane-local across (sblk,r); cross-lane reduce is
//      shfl_xor 16/32 only (lanes sharing lm).
// P^T C-layout stores r-consecutive s -> sPw[q][s] via b64 writes.
// O^T = mfma(A=Vt, B=P): lane holds O^T[d=dblk*16+lq*4+r][q=qblk*16+lm]
//   -> epilogue writes 4 consecutive d per lane = global b64 stores.
// sP aliases sQ (Q register-resident after prologue). LDS ~36.9 KB.
#define PSTR 72
__global__ __launch_bounds__(256) void attn_mfma(
    const ushort* __restrict__ qkv,
    __hip_bfloat16* __restrict__ av)
{
    __shared__ alignas(16) ushort sQP[128 * PSTR];   // Q tile, then P (per-wave)
    __shared__ alignas(16) ushort sK[64 * PSTR];
    __shared__ alignas(16) ushort sVt[64 * PSTR];    // Vt[d][s]

    int t = threadIdx.x;
    int qt = blockIdx.x, h = blockIdx.y, b = blockIdx.z;
    int w = t >> 6, l = t & 63;
    int lm = l & 15, lq = l >> 4;
    int wm = w * 32;

    const ushort* qbase = qkv + (size_t)(b * S_ + qt * 128) * QKVSTR + h * DH_;
    const ushort* kbase = qkv + (size_t)b * S_ * QKVSTR + 768 + h * DH_;
    const ushort* vbase = qkv + (size_t)b * S_ * QKVSTR + 1536 + h * DH_;

    // stage Q tile [128][64]
    {
        int r = t >> 1, c0 = (t & 1) * 32;
        const ushort* src = qbase + (size_t)r * QKVSTR + c0;
        ushort* dst = &sQP[r * PSTR + c0];
        *(uint4*)(dst + 0)  = *(const uint4*)(src + 0);
        *(uint4*)(dst + 8)  = *(const uint4*)(src + 8);
        *(uint4*)(dst + 16) = *(const uint4*)(src + 16);
        *(uint4*)(dst + 24) = *(const uint4*)(src + 24);
    }
    __syncthreads();
    short8 qf[2][2];   // [qblk][ks] — B-fragments (Q/8)
#pragma unroll
    for (int i = 0; i < 2; i++)
#pragma unroll
        for (int ks = 0; ks < 2; ks++)
            qf[i][ks] = scale8_eighth(
                *(const short8*)&sQP[(wm + i * 16 + lm) * PSTR + ks * 32 + lq * 8]);

    ushort* sPw = &sQP[(size_t)wm * PSTR];           // wave-local P region [32q][64s]

    f32x4 accO[4][2];          // O^T: [dblk][qblk]
    float mrun[2], lrun[2];    // per q-col (q = qblk*16+lm)
#pragma unroll
    for (int dk = 0; dk < 4; dk++)
#pragma unroll
        for (int i = 0; i < 2; i++) accO[dk][i] = (f32x4){0.f, 0.f, 0.f, 0.f};
    mrun[0] = mrun[1] = -1e30f;
    lrun[0] = lrun[1] = 0.f;

    for (int kt = 0; kt < S_ / 64; kt++) {
        __syncthreads();   // prior reads of sK/sVt done; first iter: qf loads done
        {
            // K stage: thread t covers row r = t>>2, 32B chunk (t&3)
            int r = t >> 2, c0 = (t & 3) * 16;
            const ushort* ksrc = kbase + (size_t)(kt * 64 + r) * QKVSTR + c0;
            ushort* kdst = &sK[r * PSTR + c0];
            *(uint4*)(kdst + 0) = *(const uint4*)(ksrc + 0);
            *(uint4*)(kdst + 8) = *(const uint4*)(ksrc + 8);
            // V stage (transposed, vectorized): thread t covers s-pair p=t&31,
            // d-chunk d0=(t>>5)*8; writes 8 x b32 (ushort2), banks (4j+p)%32.
            int p = t & 31, d0 = (t >> 5) * 8;
            const ushort* vsrc = vbase + (size_t)(kt * 64 + 2 * p) * QKVSTR + d0;
            uint4 v0 = *(const uint4*)(vsrc);
            uint4 v1 = *(const uint4*)(vsrc + QKVSTR);
            const ushort* e0 = (const ushort*)&v0;
            const ushort* e1 = (const ushort*)&v1;
#pragma unroll
            for (int j = 0; j < 8; j++) {
                uint pk = (uint)e0[j] | ((uint)e1[j] << 16);
                *(uint*)&sVt[(d0 + j) * PSTR + 2 * p] = pk;
            }
        }
        __syncthreads();

        // S^T = K (Q/8):  accS[sblk][qblk]
        f32x4 accS[4][2];
#pragma unroll
        for (int sb = 0; sb < 4; sb++)
#pragma unroll
            for (int i = 0; i < 2; i++) accS[sb][i] = (f32x4){0.f, 0.f, 0.f, 0.f};
#pragma unroll
        for (int ks = 0; ks < 2; ks++) {
#pragma unroll
            for (int sb = 0; sb < 4; sb++) {
                short8 kf = *(const short8*)&sK[(sb * 16 + lm) * PSTR + ks * 32 + lq * 8];
#pragma unroll
                for (int i = 0; i < 2; i++)
                    accS[sb][i] = __builtin_amdgcn_mfma_f32_16x16x32_bf16(
                        kf, qf[i][ks], accS[sb][i], 0, 0, 0);
            }
        }

        // online softmax over s (lane-local + 2-round shfl across lq groups)
        float pmax[2];
#pragma unroll
        for (int i = 0; i < 2; i++) {
            float m0 = accS[0][i][0];
#pragma unroll
            for (int sb = 0; sb < 4; sb++)
#pragma unroll
                for (int r = 0; r < 4; r++) m0 = fmaxf(m0, accS[sb][i][r]);
            m0 = fmaxf(m0, __shfl_xor(m0, 16));
            m0 = fmaxf(m0, __shfl_xor(m0, 32));
            pmax[i] = m0;
        }
        float alpha[2];
#pragma unroll
        for (int i = 0; i < 2; i++) {
            float mn = fmaxf(mrun[i], pmax[i]);
            alpha[i] = __expf(mrun[i] - mn);
            mrun[i] = mn;
        }
        float rsum[2] = {0.f, 0.f};
#pragma unroll
        for (int sb = 0; sb < 4; sb++)
#pragma unroll
            for (int i = 0; i < 2; i++)
#pragma unroll
                for (int r = 0; r < 4; r++) {
                    float p = __expf(accS[sb][i][r] - mrun[i]);
                    accS[sb][i][r] = p;
                    rsum[i] += p;
                }
#pragma unroll
        for (int i = 0; i < 2; i++) {
            rsum[i] += __shfl_xor(rsum[i], 16);
            rsum[i] += __shfl_xor(rsum[i], 32);
            lrun[i] = lrun[i] * alpha[i] + rsum[i];
        }

        // rescale O^T
#pragma unroll
        for (int dk = 0; dk < 4; dk++)
#pragma unroll
            for (int i = 0; i < 2; i++)
#pragma unroll
                for (int r = 0; r < 4; r++) accO[dk][i][r] *= alpha[i];

        // P^T C-layout -> sPw[q][s]: 4 r-consecutive s per (qblk,sblk) = b64
#pragma unroll
        for (int i = 0; i < 2; i++)
#pragma unroll
            for (int sb = 0; sb < 4; sb++) {
                short4v pk;
#pragma unroll
                for (int r = 0; r < 4; r++) pk[r] = (short)f2bf(accS[sb][i][r]);
                *(short4v*)&sPw[(i * 16 + lm) * PSTR + sb * 16 + lq * 4] = pk;
            }

        // O^T += V^T P^T  (A = Vt rows, B = sPw rows; wave-local, no barrier)
#pragma unroll
        for (int ks = 0; ks < 2; ks++) {
            short8 pf[2];
#pragma unroll
            for (int i = 0; i < 2; i++)
                pf[i] = *(const short8*)&sPw[(i * 16 + lm) * PSTR + ks * 32 + lq * 8];
#pragma unroll
            for (int dk = 0; dk < 4; dk++) {
                short8 vf = *(const short8*)&sVt[(dk * 16 + lm) * PSTR + ks * 32 + lq * 8];
#pragma unroll
                for (int i = 0; i < 2; i++)
                    accO[dk][i] = __builtin_amdgcn_mfma_f32_16x16x32_bf16(
                        vf, pf[i], accO[dk][i], 0, 0, 0);
            }
        }
    }

    // epilogue: O = (O^T)^T / l, vector b64 stores (4 consecutive d per lane)
    float invl[2];
    invl[0] = 1.0f / lrun[0];
    invl[1] = 1.0f / lrun[1];
#pragma unroll
    for (int i = 0; i < 2; i++) {
        int row = qt * 128 + wm + i * 16 + lm;
        __hip_bfloat16* dst = av + (size_t)(b * S_ + row) * D_ + h * DH_;
#pragma unroll
        for (int dk = 0; dk < 4; dk++) {
            short4v ok;
#pragma unroll
            for (int r = 0; r < 4; r++) ok[r] = (short)f2bf(accO[dk][i][r] * invl[i]);
            *(short4v*)(dst + dk * 16 + lq * 4) = ok;
        }
    }
}

// ----------------------------- residual + layernorm (bf16 stream) ----------
// xb <- LN(xb + r) in bf16; all loads/stores as packed 2xbf16 (uint).
// Thread t handles elems {2t,2t+1} and, for t<128, {512+2t, 512+2t+1}.
__global__ __launch_bounds__(256) void add_ln(
    __hip_bfloat16* __restrict__ xb,
    const __hip_bfloat16* __restrict__ r, const float* __restrict__ g,
    const float* __restrict__ bta)
{
    __shared__ float sred[256];
    int row = blockIdx.x, t = threadIdx.x;
    uint* xu = (uint*)(xb + (size_t)row * D_);
    const uint* ru = (const uint*)(r + (size_t)row * D_);
    uint ux0 = xu[t], ur0 = ru[t];
    float a0 = bflo(ux0) + bflo(ur0);
    float a1 = bfhi(ux0) + bfhi(ur0);
    float a2 = 0.f, a3 = 0.f;
    if (t < 128) {
        uint ux1 = xu[256 + t], ur1 = ru[256 + t];
        a2 = bflo(ux1) + bflo(ur1);
        a3 = bfhi(ux1) + bfhi(ur1);
    }
    sred[t] = a0 + a1 + a2 + a3;
    __syncthreads();
    for (int o = 128; o > 0; o >>= 1) { if (t < o) sred[t] += sred[t + o]; __syncthreads(); }
    float mean = sred[0] * (1.0f / D_);
    __syncthreads();
    float d0 = a0 - mean, d1 = a1 - mean;
    float d2 = a2 - mean, d3 = a3 - mean;
    sred[t] = d0 * d0 + d1 * d1 + (t < 128 ? d2 * d2 + d3 * d3 : 0.f);
    __syncthreads();
    for (int o = 128; o > 0; o >>= 1) { if (t < o) sred[t] += sred[t + o]; __syncthreads(); }
    float rstd = rsqrtf(sred[0] * (1.0f / D_) + 1e-6f);
    {
        float2 gv = ((const float2*)g)[t];
        float2 bv = ((const float2*)bta)[t];
        float o0 = gv.x * d0 * rstd + bv.x;
        float o1 = gv.y * d1 * rstd + bv.y;
        xu[t] = (uint)f2bf(o0) | ((uint)f2bf(o1) << 16);
    }
    if (t < 128) {
        float2 gv = ((const float2*)g)[256 + t];
        float2 bv = ((const float2*)bta)[256 + t];
        float o2 = gv.x * d2 * rstd + bv.x;
        float o3 = gv.y * d3 * rstd + bv.y;
        xu[256 + t] = (uint)f2bf(o2) | ((uint)f2bf(o3) << 16);
    }
}

// ----------------------------- mean pool over S (bf16 in) ------------------
__global__ void pool_kernel(const __hip_bfloat16* __restrict__ xb,
                            float* __restrict__ pooled) {
    int idx = blockIdx.x * 256 + threadIdx.x;   // b*768 + d
    int b = idx / D_, d = idx % D_;
    float acc = 0.f;
    const __hip_bfloat16* p = xb + (size_t)b * S_ * D_ + d;
    for (int s = 0; s < S_; s++) acc += __bfloat162float(p[(size_t)s * D_]);
    pooled[idx] = acc * (1.0f / S_);
}

// ----------------------------- classifier head -----------------------------
__global__ void head_kernel(const float* __restrict__ pooled,
                            const float* __restrict__ wl,
                            const float* __restrict__ bl,
                            const float* __restrict__ wout,
                            const float* __restrict__ bout,
                            float* __restrict__ out)
{
    __shared__ float hb[32];
    int b = blockIdx.x, t = threadIdx.x;
    if (t < 32) {
        float z = bl[t];
        for (int d = 0; d < D_; d++) z += pooled[b * D_ + d] * wl[d * 32 + t];
        hb[t] = 0.5f * z * (1.0f + erff(z * 0.70710678118654752f));
    }
    __syncthreads();
    if (t == 0) {
        float z = bout[0];
        for (int j = 0; j < 32; j++) z += hb[j] * wout[j];
        out[b] = 1.0f / (1.0f + expf(-z));
    }
}

// ---------------------------------------------------------------------------
extern "C" void kernel_launch(void* const* d_in, const int* in_sizes, int n_in,
                              void* d_out, int out_size, void* d_ws, size_t ws_size,
                              hipStream_t stream)
{
    (void)in_sizes; (void)n_in; (void)out_size; (void)ws_size;
    const int*   tokens = (const int*)  d_in[0];
    const float* emb    = (const float*)d_in[1];
    const float* wq     = (const float*)d_in[2];
    const float* bq     = (const float*)d_in[3];
    const float* wk     = (const float*)d_in[4];
    const float* bk     = (const float*)d_in[5];
    const float* wv     = (const float*)d_in[6];
    const float* bv     = (const float*)d_in[7];
    const float* wo     = (const float*)d_in[8];
    const float* bo     = (const float*)d_in[9];
    const float* w1     = (const float*)d_in[10];
    const float* b1     = (const float*)d_in[11];
    const float* w2     = (const float*)d_in[12];
    const float* b2     = (const float*)d_in[13];
    const float* ln1g   = (const float*)d_in[14];
    const float* ln1b   = (const float*)d_in[15];
    const float* ln2g   = (const float*)d_in[16];
    const float* ln2b   = (const float*)d_in[17];
    const float* wl     = (const float*)d_in[18];
    const float* bl     = (const float*)d_in[19];
    const float* wout   = (const float*)d_in[20];
    const float* bout   = (const float*)d_in[21];
    float* out = (float*)d_out;

    char* ws = (char*)d_ws;
    size_t off = 0;
    auto alloc = [&](size_t n) -> void* {
        char* p = ws + off;
        off = (off + n + 255) & ~(size_t)255;
        return (void*)p;
    };
    const size_t XBYTES = (size_t)B_ * S_ * D_ * 4;        // 50.33 MB
    const size_t XBF    = XBYTES / 2;                      // 25.17 MB
    float*          pe     = (float*)alloc((size_t)S_ * D_ * 4);
    __hip_bfloat16* xb     = (__hip_bfloat16*)alloc(XBF);
    __hip_bfloat16* r_bf   = (__hip_bfloat16*)alloc(XBF);  // residual branch
    char*           arena  = (char*)alloc(4 * XBF);        // 100.66 MB
    __hip_bfloat16* qkv_bf = (__hip_bfloat16*)arena;       // [M][2304]
    __hip_bfloat16* av_bf  = (__hip_bfloat16*)(arena + 3 * XBF);
    __hip_bfloat16* h_bf   = (__hip_bfloat16*)arena;       // [M][3072] aliases qkv+av
    __hip_bfloat16* wT     = (__hip_bfloat16*)alloc((size_t)L_ * 7077888 * 2);
    float*          qkvbias= (float*)alloc((size_t)L_ * QKVSTR * 4);
    float*          pooled = (float*)alloc((size_t)B_ * D_ * 4);

    const int M = B_ * S_;                                 // 16384
    const size_t DD = (size_t)D_ * D_;
    const size_t DF = (size_t)D_ * FF_;
    const size_t LSTRIDE = 4 * DD + 2 * DF;

    // weights: per layer [qkvT(3*DD) | woT(DD) | w1T(DF) | w2T(DF)]
    transpose_bf16_l<<<dim3(D_ / 32, D_ / 32, L_), 256, 0, stream>>>(
        wq, wT + 0 * DD, D_, D_, DD, LSTRIDE);
    transpose_bf16_l<<<dim3(D_ / 32, D_ / 32, L_), 256, 0, stream>>>(
        wk, wT + 1 * DD, D_, D_, DD, LSTRIDE);
    transpose_bf16_l<<<dim3(D_ / 32, D_ / 32, L_), 256, 0, stream>>>(
        wv, wT + 2 * DD, D_, D_, DD, LSTRIDE);
    transpose_bf16_l<<<dim3(D_ / 32, D_ / 32, L_), 256, 0, stream>>>(
        wo, wT + 3 * DD, D_, D_, DD, LSTRIDE);
    transpose_bf16_l<<<dim3(FF_ / 32, D_ / 32, L_), 256, 0, stream>>>(
        w1, wT + 4 * DD, D_, FF_, DF, LSTRIDE);
    transpose_bf16_l<<<dim3(D_ / 32, FF_ / 32, L_), 256, 0, stream>>>(
        w2, wT + 4 * DD + DF, FF_, D_, DF, LSTRIDE);
    biascat<<<(L_ * QKVSTR) / 256, 256, 0, stream>>>(bq, bk, bv, qkvbias);

    pe_kernel<<<(S_ * D_ + 255) / 256, 256, 0, stream>>>(pe);
    embed_kernel<<<M, 256, 0, stream>>>(tokens, emb, pe, xb);

    for (int l = 0; l < L_; l++) {
        __hip_bfloat16* wl_base = wT + (size_t)l * LSTRIDE;
        const ushort* qkvT = (const ushort*)(wl_base + 0 * DD);
        const ushort* woT  = (const ushort*)(wl_base + 3 * DD);
        const ushort* w1T  = (const ushort*)(wl_base + 4 * DD);
        const ushort* w2T  = (const ushort*)(wl_base + 4 * DD + DF);

        gemm256<0><<<dim3((QKVSTR / 256) * (M / 256)), 512, 0, stream>>>(
            (const ushort*)xb, qkvT, qkvbias + (size_t)l * QKVSTR, qkv_bf,
            M, QKVSTR, D_, QKVSTR / 256);

        attn_mfma<<<dim3(S_ / 128, H_, B_), 256, 0, stream>>>(
            (const ushort*)qkv_bf, av_bf);

        gemm256<0><<<dim3((D_ / 256) * (M / 256)), 512, 0, stream>>>(
            (const ushort*)av_bf, woT, bo + l * D_, r_bf, M, D_, D_, D_ / 256);
        add_ln<<<M, 256, 0, stream>>>(xb, r_bf, ln1g + l * D_, ln1b + l * D_);

        gemm256<1><<<dim3((FF_ / 256) * (M / 256)), 512, 0, stream>>>(
            (const ushort*)xb, w1T, b1 + l * FF_, h_bf, M, FF_, D_, FF_ / 256);
        gemm256<0><<<dim3((D_ / 256) * (M / 256)), 512, 0, stream>>>(
            (const ushort*)h_bf, w2T, b2 + l * D_, r_bf, M, D_, FF_, D_ / 256);
        add_ln<<<M, 256, 0, stream>>>(xb, r_bf, ln2g + l * D_, ln2b + l * D_);
    }

    pool_kernel<<<(B_ * D_) / 256, 256, 0, stream>>>(xb, pooled);
    head_kernel<<<B_, 64, 0, stream>>>(pooled, wl, bl, wout, bout, out);
}

// Round 7
// 1766.483 us; speedup vs baseline: 1.3518x; 1.0675x over previous
//
#include <hip/hip_runtime.h>
#include <hip/hip_bf16.h>
#include <math.h>

// ---------------------------------------------------------------------------
// TextTransformer forward on MI355X — Round 10: attention T14 async-stage
// (register ping-pong K/V prefetch, loads hide under compute) + T13 defer-max
// (RESCALE_THRESHOLD=8). GEMM unchanged from Round 9 (conflicts=0, counted
// vmcnt verified).  B=32 S=512 D=768 H=12 DH=64 FF=3072 L=4.
// ---------------------------------------------------------------------------

#define B_  32
#define S_  512
#define D_  768
#define H_  12
#define DH_ 64
#define FF_ 3072
#define L_  4
#define QKVSTR 2304

typedef __attribute__((ext_vector_type(8))) short short8;   // 8 x bf16
typedef __attribute__((ext_vector_type(4))) short short4v;  // 4 x bf16 (b64)
typedef __attribute__((ext_vector_type(4))) float f32x4;

__device__ __forceinline__ void async16(const void* g, void* l) {
    __builtin_amdgcn_global_load_lds(
        (const __attribute__((address_space(1))) void*)g,
        (__attribute__((address_space(3))) void*)l, 16, 0, 0);
}

__device__ __forceinline__ ushort f2bf(float f) {
    __hip_bfloat16 h = __float2bfloat16(f);
    return __builtin_bit_cast(ushort, h);
}
__device__ __forceinline__ float bflo(uint u) { return __uint_as_float(u << 16); }
__device__ __forceinline__ float bfhi(uint u) { return __uint_as_float(u & 0xffff0000u); }

// multiply a bf16 by 0.125 exactly: exponent -= 3 (flush tiny to signed 0)
__device__ __forceinline__ short8 scale8_eighth(short8 v) {
    short8 r;
#pragma unroll
    for (int e = 0; e < 8; e++) {
        ushort u = (ushort)v[e];
        ushort ex = u & 0x7f80;
        r[e] = (short)(ex > 0x0180 ? (ushort)(u - 0x0180) : (ushort)(u & 0x8000));
    }
    return r;
}

// ----------------------------- positional encoding -------------------------
__global__ void pe_kernel(float* __restrict__ pe) {
    int idx = blockIdx.x * 256 + threadIdx.x;
    if (idx >= S_ * D_) return;
    int s = idx / D_, j = idx % D_;
    double e = (2.0 * (double)(j >> 1)) / (double)D_;
    double denom = pow(10000.0, e);
    double ang = (double)s / denom;
    pe[idx] = (j & 1) ? (float)cos(ang) : (float)sin(ang);
}

// ----------------------------- embedding + PE ------------------------------
__global__ void embed_kernel(const int* __restrict__ tokens,
                             const float* __restrict__ emb,
                             const float* __restrict__ pe,
                             __hip_bfloat16* __restrict__ xb) {
    int row = blockIdx.x;              // b*S + s
    int s = row & (S_ - 1);
    int tok = tokens[row];
    float scale = sqrtf((float)D_);
    for (int i = threadIdx.x; i < D_; i += 256) {
        float v = emb[(size_t)tok * D_ + i] * scale + pe[s * D_ + i];
        xb[(size_t)row * D_ + i] = __float2bfloat16(v);
    }
}

// ----------------------------- batched weight transpose fp32->bf16 ---------
// out[z][c][r] = (bf16) in[z][r][c].  Grid (C/32, R/32, L).
__global__ __launch_bounds__(256) void transpose_bf16_l(
    const float* __restrict__ in, __hip_bfloat16* __restrict__ out,
    int R, int C, size_t inL, size_t outL)
{
    __shared__ float tile[32][33];
    in  += (size_t)blockIdx.z * inL;
    out += (size_t)blockIdx.z * outL;
    int tx = threadIdx.x & 31, ty = threadIdx.x >> 5;   // 32 x 8
    int c0 = blockIdx.x * 32, r0 = blockIdx.y * 32;
#pragma unroll
    for (int d = 0; d < 32; d += 8)
        tile[ty + d][tx] = in[(size_t)(r0 + ty + d) * C + c0 + tx];
    __syncthreads();
#pragma unroll
    for (int d = 0; d < 32; d += 8)
        out[(size_t)(c0 + ty + d) * R + r0 + tx] = __float2bfloat16(tile[tx][ty + d]);
}

// ----------------------------- qkv bias concat -----------------------------
__global__ void biascat(const float* __restrict__ bq, const float* __restrict__ bk,
                        const float* __restrict__ bv, float* __restrict__ o) {
    int i = blockIdx.x * 256 + threadIdx.x;          // [L_*2304)
    int ll = i / QKVSTR, j = i % QKVSTR;
    o[i] = j < 768 ? bq[ll * 768 + j]
         : j < 1536 ? bk[ll * 768 + j - 768]
                    : bv[ll * 768 + j - 1536];
}

// ----------------------------- 256x256 8-phase bf16 MFMA GEMM --------------
// C[M,N] = A[M,K] @ Bt[N,K]^T + bias[N].  M%256==0, N%256==0, K%128==0.
// 512 threads = 8 waves (2Mx4N); per-wave output 128x64; BK=64, dbuf LDS 128KB.
// T2 swizzle (3-bit): within each 128B LDS row, byte_col ^= ((row&7)<<4),
// applied via inverse-swizzled global SOURCE + swizzled ds_read columns.
// Counted vmcnt(4) at phases 4/8 (T4); single vmcnt(0) drain AFTER the loop
// (epilogue reuses LDS). Epilogue repack swizzled (ushort idx ^ (row&7)<<3).
#define BAR()   __builtin_amdgcn_s_barrier()
#define LGKM0() asm volatile("s_waitcnt lgkmcnt(0)" ::: "memory")
#define VM4()   asm volatile("s_waitcnt vmcnt(4)" ::: "memory")
#define VM0()   asm volatile("s_waitcnt vmcnt(0)" ::: "memory")

#define STAGE_A(buf, h, kt) do { \
    async16(aSrc[h][0] + (kt) * 64, &lds[(buf) * 2][dOff[h][0]]); \
    async16(aSrc[h][1] + (kt) * 64, &lds[(buf) * 2][dOff[h][1]]); } while (0)
#define STAGE_B(buf, h, kt) do { \
    async16(bSrc[h][0] + (kt) * 64, &lds[(buf) * 2 + 1][dOff[h][0]]); \
    async16(bSrc[h][1] + (kt) * 64, &lds[(buf) * 2 + 1][dOff[h][1]]); } while (0)

#define LDA(buf, m, ks) (*(const short8*)((const char*)(&lds[(buf) * 2][0]) + \
    (size_t)((arow + (m) * 16) * 128 + cswz[ks])))
#define LDB(buf, n, ks) (*(const short8*)((const char*)(&lds[(buf) * 2 + 1][0]) + \
    (size_t)((brow + (n) * 16) * 128 + cswz[ks])))

#define MFMA_Q(mh, nh) do { \
    __builtin_amdgcn_s_setprio(1); \
    _Pragma("unroll") \
    for (int ks_ = 0; ks_ < 2; ks_++) { \
      _Pragma("unroll") \
      for (int n_ = 0; n_ < 2; n_++) { \
        _Pragma("unroll") \
        for (int m_ = 0; m_ < 4; m_++) { \
          acc[(mh) * 4 + m_][(nh) * 2 + n_] = \
              __builtin_amdgcn_mfma_f32_16x16x32_bf16( \
                  a[m_][ks_], b[(nh) * 2 + n_][ks_], \
                  acc[(mh) * 4 + m_][(nh) * 2 + n_], 0, 0, 0); \
        } } } \
    __builtin_amdgcn_s_setprio(0); \
} while (0)

template<int RELU>
__global__ __launch_bounds__(512, 2) void gemm256(
    const ushort* __restrict__ A,   // bf16 [M][K]
    const ushort* __restrict__ Bt,  // bf16 [N][K]
    const float* __restrict__ bias, // fp32 [N]
    __hip_bfloat16* __restrict__ C, // bf16 [M][N]
    int M, int N, int K, int NX)    // NX = N/256
{
    __shared__ alignas(16) ushort lds[4][16384];  // [buf*2 + (0=A,1=B)][256*64]

    int t = threadIdx.x;
    int l = t & 63, w = t >> 6;
    int wmi = w >> 2, wni = w & 3;            // 2 x 4 wave grid
    int lm = l & 15, lo = l >> 4;

    // T1: XCD-aware block swizzle (all our grids are %8 == 0)
    int nwg = gridDim.x;
    int bid = blockIdx.x;
    int lid = (nwg & 7) ? bid : ((bid & 7) * (nwg >> 3) + (bid >> 3));
    int bn = lid % NX, bm = lid / NX;
    int row0 = bm << 8, col0 = bn << 8;

    // staging geometry: thread t stages 16B chunks; LDS dest is linear,
    // global source column is inverse-swizzled: col ^= ((row&7)<<4).
    const ushort* aSrc[2][2];
    const ushort* bSrc[2][2];
    int dOff[2][2];
#pragma unroll
    for (int h = 0; h < 2; h++) {
#pragma unroll
        for (int c = 0; c < 2; c++) {
            int p = h * 16384 + c * 8192 + t * 16;     // byte off in 32KB tile
            int prow = p >> 7;                         // tile row (0..255)
            int scolb = (p & 127) ^ ((prow & 7) << 4); // inverse-swz byte col
            dOff[h][c] = p >> 1;
            aSrc[h][c] = A  + (size_t)(row0 + prow) * K + (scolb >> 1);
            bSrc[h][c] = Bt + (size_t)(col0 + prow) * K + (scolb >> 1);
        }
    }

    // ds_read addressing: fragment rows are ...+lm (mod 16), so row&7 = lm&7
    // is lane-constant; precompute swizzled byte col per ks half.
    int arow = wmi * 128 + lm;
    int brow = wni * 64 + lm;
    int swz = (lm & 7) << 4;
    int cswz[2];
    cswz[0] = (lo * 16) ^ swz;
    cswz[1] = (64 + lo * 16) ^ swz;

    f32x4 acc[8][4];
#pragma unroll
    for (int i = 0; i < 8; i++)
#pragma unroll
        for (int j = 0; j < 4; j++) acc[i][j] = (f32x4){0.f, 0.f, 0.f, 0.f};
    short8 a[4][2], b[4][2];

    const int NK = K >> 6;        // 64-wide K-tiles (even; K%128==0)
    const int NI = NK >> 1;

    // prologue: kt0 fully into buf0; kt1's B-halves into buf1 (12 loads)
    STAGE_A(0, 0, 0); STAGE_A(0, 1, 0);
    STAGE_B(0, 0, 0); STAGE_B(0, 1, 0);
    STAGE_B(1, 0, 1); STAGE_B(1, 1, 1);
    VM4();            // kt0's 8 loads landed; kt1 B (4) still in flight
    BAR();

    for (int i = 0; i < NI; i++) {
        int kt  = 2 * i;
        int ktA = (kt + 2 <= NK - 2) ? kt + 2 : NK - 2;   // clamp: last iter
        int ktB = (kt + 3 <= NK - 1) ? kt + 3 : NK - 1;   // re-stages same data

        // ---- phase 1: Q(0,0) of buf0 | stage A-half0(kt+1) -> buf1
#pragma unroll
        for (int m = 0; m < 4; m++) { a[m][0] = LDA(0, m, 0); a[m][1] = LDA(0, m, 1); }
#pragma unroll
        for (int n = 0; n < 2; n++) { b[n][0] = LDB(0, n, 0); b[n][1] = LDB(0, n, 1); }
        STAGE_A(1, 0, kt + 1);
        BAR(); LGKM0();
        MFMA_Q(0, 0);
        BAR();

        // ---- phase 2: Q(0,1) | stage A-half1(kt+1) -> buf1
#pragma unroll
        for (int n = 0; n < 2; n++) { b[2 + n][0] = LDB(0, 2 + n, 0); b[2 + n][1] = LDB(0, 2 + n, 1); }
        STAGE_A(1, 1, kt + 1);
        BAR(); LGKM0();
        MFMA_Q(0, 1);
        BAR();

        // ---- phase 3: Q(1,0) | stage B-half0(kt+2) -> buf0 (B reads done ph2)
#pragma unroll
        for (int m = 0; m < 4; m++) { a[m][0] = LDA(0, 4 + m, 0); a[m][1] = LDA(0, 4 + m, 1); }
        STAGE_B(0, 0, ktA);
        BAR(); LGKM0();
        MFMA_Q(1, 0);
        BAR();

        // ---- phase 4: Q(1,1) | stage B-half1(kt+2); gate buf1 (kt+1) ready
        STAGE_B(0, 1, ktA);
        BAR(); LGKM0();
        MFMA_Q(1, 1);
        VM4();        // all but ph3/ph4's 4 loads landed -> buf1 complete
        BAR();

        // ---- phase 5: Q(0,0) of buf1 | stage A-half0(kt+2) -> buf0
#pragma unroll
        for (int m = 0; m < 4; m++) { a[m][0] = LDA(1, m, 0); a[m][1] = LDA(1, m, 1); }
#pragma unroll
        for (int n = 0; n < 2; n++) { b[n][0] = LDB(1, n, 0); b[n][1] = LDB(1, n, 1); }
        STAGE_A(0, 0, ktA);
        BAR(); LGKM0();
        MFMA_Q(0, 0);
        BAR();

        // ---- phase 6: Q(0,1) | stage A-half1(kt+2) -> buf0
#pragma unroll
        for (int n = 0; n < 2; n++) { b[2 + n][0] = LDB(1, 2 + n, 0); b[2 + n][1] = LDB(1, 2 + n, 1); }
        STAGE_A(0, 1, ktA);
        BAR(); LGKM0();
        MFMA_Q(0, 1);
        BAR();

        // ---- phase 7: Q(1,0) | stage B-half0(kt+3) -> buf1 (B reads done ph6)
#pragma unroll
        for (int m = 0; m < 4; m++) { a[m][0] = LDA(1, 4 + m, 0); a[m][1] = LDA(1, 4 + m, 1); }
        STAGE_B(1, 0, ktB);
        BAR(); LGKM0();
        MFMA_Q(1, 0);
        BAR();

        // ---- phase 8: Q(1,1) | stage B-half1(kt+3); gate buf0 (kt+2) ready
        STAGE_B(1, 1, ktB);
        BAR(); LGKM0();
        MFMA_Q(1, 1);
        VM4();        // counted wait (T4): ph7/ph8's 4 loads stay in flight
        BAR();
    }

    // drain once: epilogue reuses the staging LDS. Every wave drains its own
    // vmcnt; barrier ensures all waves' global_load_lds writes have landed.
    VM0();
    BAR();

    // ---- epilogue: acc -> LDS bf16 [256][256] (swizzled) -> coalesced stores
    // swizzle: ushort idx c ^= ((row&7)<<3) (byte bits 4-6); read applies same.
    ushort* eL = &lds[0][0];                      // 128 KB, exactly the tile
    {
        int crow = wmi * 128;                     // tile-local
        int ccol = wni * 64;
#pragma unroll
        for (int n = 0; n < 4; n++) {
            int c = ccol + n * 16 + lm;
            float bs = bias[col0 + c];
#pragma unroll
            for (int m = 0; m < 8; m++) {
#pragma unroll
                for (int r = 0; r < 4; r++) {
                    float v = acc[m][n][r] + bs;
                    if (RELU) v = fmaxf(v, 0.f);
                    int row = crow + m * 16 + lo * 4 + r;
                    int sc = c ^ (((lo * 4 + r) & 7) << 3);
                    eL[row * 256 + sc] = f2bf(v);
                }
            }
        }
    }
    __syncthreads();
    {
        int rsw = ((t >> 5) & 7) << 3;            // rr&7 is thread-constant
#pragma unroll
        for (int i = 0; i < 16; i++) {
            int byteoff = i * 8192 + t * 16;      // 512 thr x 16B = 8KB/pass
            int rr = byteoff >> 9;                // tile row (512B rows)
            int cc = (byteoff & 511) >> 1;        // linear ushort col
            uint4 v = *(const uint4*)(eL + rr * 256 + (cc ^ rsw));
            *(uint4*)(C + (size_t)(row0 + rr) * N + col0 + cc) = v;
        }
    }
    (void)M;
}

// ----------------------------- MFMA flash attention (operand-swapped) ------
// Block: (qt of 128 rows, h, b); 4 waves; wave w owns q-rows wm=w*32..+32.
// S^T = mfma(A=K, B=Q/8); O^T = mfma(A=Vt, B=P); lane-local softmax columns.
// R10: T14 async-stage (register ping-pong: kt+1's K/V global loads issued
// between the staging barriers, drain under kt's compute) + T13 defer-max
// (skip O-rescale when __all(pmax - mrun <= 8); P bounded by e^8).
// sP aliases sQ (Q register-resident after prologue). LDS ~36.9 KB.
#define PSTR 72
__global__ __launch_bounds__(256) void attn_mfma(
    const ushort* __restrict__ qkv,
    __hip_bfloat16* __restrict__ av)
{
    __shared__ alignas(16) ushort sQP[128 * PSTR];   // Q tile, then P (per-wave)
    __shared__ alignas(16) ushort sK[64 * PSTR];
    __shared__ alignas(16) ushort sVt[64 * PSTR];    // Vt[d][s]

    int t = threadIdx.x;
    int qt = blockIdx.x, h = blockIdx.y, b = blockIdx.z;
    int w = t >> 6, l = t & 63;
    int lm = l & 15, lq = l >> 4;
    int wm = w * 32;

    const ushort* qbase = qkv + (size_t)(b * S_ + qt * 128) * QKVSTR + h * DH_;
    const ushort* kbase = qkv + (size_t)b * S_ * QKVSTR + 768 + h * DH_;
    const ushort* vbase = qkv + (size_t)b * S_ * QKVSTR + 1536 + h * DH_;

    // per-thread staging geometry
    int kr = t >> 2, kc0 = (t & 3) * 16;     // K: row, 32B chunk (2 x uint4)
    int vp = t & 31, vd0 = (t >> 5) * 8;     // V: s-pair, 8-d chunk
    const ushort* kptr = kbase + (size_t)kr * QKVSTR + kc0;
    const ushort* vptr = vbase + (size_t)(2 * vp) * QKVSTR + vd0;
    const size_t KTS = (size_t)64 * QKVSTR;  // kt stride (ushorts)

    // stage Q tile [128][64]
    {
        int r = t >> 1, c0 = (t & 1) * 32;
        const ushort* src = qbase + (size_t)r * QKVSTR + c0;
        ushort* dst = &sQP[r * PSTR + c0];
        *(uint4*)(dst + 0)  = *(const uint4*)(src + 0);
        *(uint4*)(dst + 8)  = *(const uint4*)(src + 8);
        *(uint4*)(dst + 16) = *(const uint4*)(src + 16);
        *(uint4*)(dst + 24) = *(const uint4*)(src + 24);
    }
    // preload kt=0 K/V into regset A (overlaps Q LDS settle)
    uint4 kA0 = *(const uint4*)(kptr);
    uint4 kA1 = *(const uint4*)(kptr + 8);
    uint4 vA0 = *(const uint4*)(vptr);
    uint4 vA1 = *(const uint4*)(vptr + QKVSTR);
    uint4 kB0, kB1, vB0, vB1;

    __syncthreads();
    short8 qf[2][2];   // [qblk][ks] — B-fragments (Q/8)
#pragma unroll
    for (int i = 0; i < 2; i++)
#pragma unroll
        for (int ks = 0; ks < 2; ks++)
            qf[i][ks] = scale8_eighth(
                *(const short8*)&sQP[(wm + i * 16 + lm) * PSTR + ks * 32 + lq * 8]);

    ushort* sPw = &sQP[(size_t)wm * PSTR];           // wave-local P region [32q][64s]

    f32x4 accO[4][2];          // O^T: [dblk][qblk]
    float mrun[2], lrun[2];    // per q-col (q = qblk*16+lm)
#pragma unroll
    for (int dk = 0; dk < 4; dk++)
#pragma unroll
        for (int i = 0; i < 2; i++) accO[dk][i] = (f32x4){0.f, 0.f, 0.f, 0.f};
    mrun[0] = mrun[1] = -1e30f;
    lrun[0] = lrun[1] = 0.f;

    // write one K/V regset into sK/sVt (V transposed+packed)
    auto stage_write = [&](const uint4& k0, const uint4& k1,
                           const uint4& v0, const uint4& v1) {
        *(uint4*)&sK[kr * PSTR + kc0]     = k0;
        *(uint4*)&sK[kr * PSTR + kc0 + 8] = k1;
        const ushort* e0 = (const ushort*)&v0;
        const ushort* e1 = (const ushort*)&v1;
#pragma unroll
        for (int jj = 0; jj < 8; jj++) {
            uint pk = (uint)e0[jj] | ((uint)e1[jj] << 16);
            *(uint*)&sVt[(vd0 + jj) * PSTR + 2 * vp] = pk;
        }
    };

    // one kt step: QK^T, online softmax (defer-max), P store, PV
    auto compute = [&]() {
        // S^T = K (Q/8):  accS[sblk][qblk]
        f32x4 accS[4][2];
#pragma unroll
        for (int sb = 0; sb < 4; sb++)
#pragma unroll
            for (int i = 0; i < 2; i++) accS[sb][i] = (f32x4){0.f, 0.f, 0.f, 0.f};
#pragma unroll
        for (int ks = 0; ks < 2; ks++) {
#pragma unroll
            for (int sb = 0; sb < 4; sb++) {
                short8 kf = *(const short8*)&sK[(sb * 16 + lm) * PSTR + ks * 32 + lq * 8];
#pragma unroll
                for (int i = 0; i < 2; i++)
                    accS[sb][i] = __builtin_amdgcn_mfma_f32_16x16x32_bf16(
                        kf, qf[i][ks], accS[sb][i], 0, 0, 0);
            }
        }

        // online softmax: per-q-column max (lane-local + shfl 16/32)
        float pmax[2];
#pragma unroll
        for (int i = 0; i < 2; i++) {
            float m0 = accS[0][i][0];
#pragma unroll
            for (int sb = 0; sb < 4; sb++)
#pragma unroll
                for (int r = 0; r < 4; r++) m0 = fmaxf(m0, accS[sb][i][r]);
            m0 = fmaxf(m0, __shfl_xor(m0, 16));
            m0 = fmaxf(m0, __shfl_xor(m0, 32));
            pmax[i] = m0;
        }
        // T13 defer-max: rescale only when some column grew past THR=8
#pragma unroll
        for (int i = 0; i < 2; i++) {
            if (!__all(pmax[i] - mrun[i] <= 8.0f)) {
                float mn = fmaxf(mrun[i], pmax[i]);
                float al = __expf(mrun[i] - mn);
                mrun[i] = mn;
                lrun[i] *= al;
#pragma unroll
                for (int dk = 0; dk < 4; dk++)
#pragma unroll
                    for (int r = 0; r < 4; r++) accO[dk][i][r] *= al;
            }
        }
        float rsum[2] = {0.f, 0.f};
#pragma unroll
        for (int sb = 0; sb < 4; sb++)
#pragma unroll
            for (int i = 0; i < 2; i++)
#pragma unroll
                for (int r = 0; r < 4; r++) {
                    float p = __expf(accS[sb][i][r] - mrun[i]);
                    accS[sb][i][r] = p;
                    rsum[i] += p;
                }
#pragma unroll
        for (int i = 0; i < 2; i++) {
            rsum[i] += __shfl_xor(rsum[i], 16);
            rsum[i] += __shfl_xor(rsum[i], 32);
            lrun[i] += rsum[i];
        }

        // P^T C-layout -> sPw[q][s]: 4 r-consecutive s per (qblk,sblk) = b64
#pragma unroll
        for (int i = 0; i < 2; i++)
#pragma unroll
            for (int sb = 0; sb < 4; sb++) {
                short4v pk;
#pragma unroll
                for (int r = 0; r < 4; r++) pk[r] = (short)f2bf(accS[sb][i][r]);
                *(short4v*)&sPw[(i * 16 + lm) * PSTR + sb * 16 + lq * 4] = pk;
            }

        // O^T += V^T P^T  (A = Vt rows, B = sPw rows; wave-local, no barrier)
#pragma unroll
        for (int ks = 0; ks < 2; ks++) {
            short8 pf[2];
#pragma unroll
            for (int i = 0; i < 2; i++)
                pf[i] = *(const short8*)&sPw[(i * 16 + lm) * PSTR + ks * 32 + lq * 8];
#pragma unroll
            for (int dk = 0; dk < 4; dk++) {
                short8 vf = *(const short8*)&sVt[(dk * 16 + lm) * PSTR + ks * 32 + lq * 8];
#pragma unroll
                for (int i = 0; i < 2; i++)
                    accO[dk][i] = __builtin_amdgcn_mfma_f32_16x16x32_bf16(
                        vf, pf[i], accO[dk][i], 0, 0, 0);
            }
        }
    };

    // kt loop, 2x unrolled ping-pong (S_/64 = 8 iterations total)
    for (int j = 0; j < S_ / 128; j++) {
        // ---- kt = 2j: write regset A, prefetch kt=2j+1 into B
        __syncthreads();                 // prior compute's sK/sVt reads done
        stage_write(kA0, kA1, vA0, vA1);
        {
            const ushort* kp = kptr + (size_t)(2 * j + 1) * KTS;
            const ushort* vq = vptr + (size_t)(2 * j + 1) * KTS;
            kB0 = *(const uint4*)(kp);
            kB1 = *(const uint4*)(kp + 8);
            vB0 = *(const uint4*)(vq);
            vB1 = *(const uint4*)(vq + QKVSTR);
        }
        __syncthreads();
        compute();

        // ---- kt = 2j+1: write regset B, prefetch kt=2j+2 into A
        __syncthreads();
        stage_write(kB0, kB1, vB0, vB1);
        if (j < S_ / 128 - 1) {
            const ushort* kp = kptr + (size_t)(2 * j + 2) * KTS;
            const ushort* vq = vptr + (size_t)(2 * j + 2) * KTS;
            kA0 = *(const uint4*)(kp);
            kA1 = *(const uint4*)(kp + 8);
            vA0 = *(const uint4*)(vq);
            vA1 = *(const uint4*)(vq + QKVSTR);
        }
        __syncthreads();
        compute();
    }

    // epilogue: O = (O^T)^T / l, vector b64 stores (4 consecutive d per lane)
    float invl[2];
    invl[0] = 1.0f / lrun[0];
    invl[1] = 1.0f / lrun[1];
#pragma unroll
    for (int i = 0; i < 2; i++) {
        int row = qt * 128 + wm + i * 16 + lm;
        __hip_bfloat16* dst = av + (size_t)(b * S_ + row) * D_ + h * DH_;
#pragma unroll
        for (int dk = 0; dk < 4; dk++) {
            short4v ok;
#pragma unroll
            for (int r = 0; r < 4; r++) ok[r] = (short)f2bf(accO[dk][i][r] * invl[i]);
            *(short4v*)(dst + dk * 16 + lq * 4) = ok;
        }
    }
}

// ----------------------------- residual + layernorm (bf16 stream) ----------
// xb <- LN(xb + r) in bf16; all loads/stores as packed 2xbf16 (uint).
// Thread t handles elems {2t,2t+1} and, for t<128, {512+2t, 512+2t+1}.
__global__ __launch_bounds__(256) void add_ln(
    __hip_bfloat16* __restrict__ xb,
    const __hip_bfloat16* __restrict__ r, const float* __restrict__ g,
    const float* __restrict__ bta)
{
    __shared__ float sred[256];
    int row = blockIdx.x, t = threadIdx.x;
    uint* xu = (uint*)(xb + (size_t)row * D_);
    const uint* ru = (const uint*)(r + (size_t)row * D_);
    uint ux0 = xu[t], ur0 = ru[t];
    float a0 = bflo(ux0) + bflo(ur0);
    float a1 = bfhi(ux0) + bfhi(ur0);
    float a2 = 0.f, a3 = 0.f;
    if (t < 128) {
        uint ux1 = xu[256 + t], ur1 = ru[256 + t];
        a2 = bflo(ux1) + bflo(ur1);
        a3 = bfhi(ux1) + bfhi(ur1);
    }
    sred[t] = a0 + a1 + a2 + a3;
    __syncthreads();
    for (int o = 128; o > 0; o >>= 1) { if (t < o) sred[t] += sred[t + o]; __syncthreads(); }
    float mean = sred[0] * (1.0f / D_);
    __syncthreads();
    float d0 = a0 - mean, d1 = a1 - mean;
    float d2 = a2 - mean, d3 = a3 - mean;
    sred[t] = d0 * d0 + d1 * d1 + (t < 128 ? d2 * d2 + d3 * d3 : 0.f);
    __syncthreads();
    for (int o = 128; o > 0; o >>= 1) { if (t < o) sred[t] += sred[t + o]; __syncthreads(); }
    float rstd = rsqrtf(sred[0] * (1.0f / D_) + 1e-6f);
    {
        float2 gv = ((const float2*)g)[t];
        float2 bv = ((const float2*)bta)[t];
        float o0 = gv.x * d0 * rstd + bv.x;
        float o1 = gv.y * d1 * rstd + bv.y;
        xu[t] = (uint)f2bf(o0) | ((uint)f2bf(o1) << 16);
    }
    if (t < 128) {
        float2 gv = ((const float2*)g)[256 + t];
        float2 bv = ((const float2*)bta)[256 + t];
        float o2 = gv.x * d2 * rstd + bv.x;
        float o3 = gv.y * d3 * rstd + bv.y;
        xu[256 + t] = (uint)f2bf(o2) | ((uint)f2bf(o3) << 16);
    }
}

// ----------------------------- mean pool over S (bf16 in) ------------------
__global__ void pool_kernel(const __hip_bfloat16* __restrict__ xb,
                            float* __restrict__ pooled) {
    int idx = blockIdx.x * 256 + threadIdx.x;   // b*768 + d
    int b = idx / D_, d = idx % D_;
    float acc = 0.f;
    const __hip_bfloat16* p = xb + (size_t)b * S_ * D_ + d;
    for (int s = 0; s < S_; s++) acc += __bfloat162float(p[(size_t)s * D_]);
    pooled[idx] = acc * (1.0f / S_);
}

// ----------------------------- classifier head -----------------------------
__global__ void head_kernel(const float* __restrict__ pooled,
                            const float* __restrict__ wl,
                            const float* __restrict__ bl,
                            const float* __restrict__ wout,
                            const float* __restrict__ bout,
                            float* __restrict__ out)
{
    __shared__ float hb[32];
    int b = blockIdx.x, t = threadIdx.x;
    if (t < 32) {
        float z = bl[t];
        for (int d = 0; d < D_; d++) z += pooled[b * D_ + d] * wl[d * 32 + t];
        hb[t] = 0.5f * z * (1.0f + erff(z * 0.70710678118654752f));
    }
    __syncthreads();
    if (t == 0) {
        float z = bout[0];
        for (int j = 0; j < 32; j++) z += hb[j] * wout[j];
        out[b] = 1.0f / (1.0f + expf(-z));
    }
}

// ---------------------------------------------------------------------------
extern "C" void kernel_launch(void* const* d_in, const int* in_sizes, int n_in,
                              void* d_out, int out_size, void* d_ws, size_t ws_size,
                              hipStream_t stream)
{
    (void)in_sizes; (void)n_in; (void)out_size; (void)ws_size;
    const int*   tokens = (const int*)  d_in[0];
    const float* emb    = (const float*)d_in[1];
    const float* wq     = (const float*)d_in[2];
    const float* bq     = (const float*)d_in[3];
    const float* wk     = (const float*)d_in[4];
    const float* bk     = (const float*)d_in[5];
    const float* wv     = (const float*)d_in[6];
    const float* bv     = (const float*)d_in[7];
    const float* wo     = (const float*)d_in[8];
    const float* bo     = (const float*)d_in[9];
    const float* w1     = (const float*)d_in[10];
    const float* b1     = (const float*)d_in[11];
    const float* w2     = (const float*)d_in[12];
    const float* b2     = (const float*)d_in[13];
    const float* ln1g   = (const float*)d_in[14];
    const float* ln1b   = (const float*)d_in[15];
    const float* ln2g   = (const float*)d_in[16];
    const float* ln2b   = (const float*)d_in[17];
    const float* wl     = (const float*)d_in[18];
    const float* bl     = (const float*)d_in[19];
    const float* wout   = (const float*)d_in[20];
    const float* bout   = (const float*)d_in[21];
    float* out = (float*)d_out;

    char* ws = (char*)d_ws;
    size_t off = 0;
    auto alloc = [&](size_t n) -> void* {
        char* p = ws + off;
        off = (off + n + 255) & ~(size_t)255;
        return (void*)p;
    };
    const size_t XBYTES = (size_t)B_ * S_ * D_ * 4;        // 50.33 MB
    const size_t XBF    = XBYTES / 2;                      // 25.17 MB
    float*          pe     = (float*)alloc((size_t)S_ * D_ * 4);
    __hip_bfloat16* xb     = (__hip_bfloat16*)alloc(XBF);
    __hip_bfloat16* r_bf   = (__hip_bfloat16*)alloc(XBF);  // residual branch
    char*           arena  = (char*)alloc(4 * XBF);        // 100.66 MB
    __hip_bfloat16* qkv_bf = (__hip_bfloat16*)arena;       // [M][2304]
    __hip_bfloat16* av_bf  = (__hip_bfloat16*)(arena + 3 * XBF);
    __hip_bfloat16* h_bf   = (__hip_bfloat16*)arena;       // [M][3072] aliases qkv+av
    __hip_bfloat16* wT     = (__hip_bfloat16*)alloc((size_t)L_ * 7077888 * 2);
    float*          qkvbias= (float*)alloc((size_t)L_ * QKVSTR * 4);
    float*          pooled = (float*)alloc((size_t)B_ * D_ * 4);

    const int M = B_ * S_;                                 // 16384
    const size_t DD = (size_t)D_ * D_;
    const size_t DF = (size_t)D_ * FF_;
    const size_t LSTRIDE = 4 * DD + 2 * DF;

    // weights: per layer [qkvT(3*DD) | woT(DD) | w1T(DF) | w2T(DF)]
    transpose_bf16_l<<<dim3(D_ / 32, D_ / 32, L_), 256, 0, stream>>>(
        wq, wT + 0 * DD, D_, D_, DD, LSTRIDE);
    transpose_bf16_l<<<dim3(D_ / 32, D_ / 32, L_), 256, 0, stream>>>(
        wk, wT + 1 * DD, D_, D_, DD, LSTRIDE);
    transpose_bf16_l<<<dim3(D_ / 32, D_ / 32, L_), 256, 0, stream>>>(
        wv, wT + 2 * DD, D_, D_, DD, LSTRIDE);
    transpose_bf16_l<<<dim3(D_ / 32, D_ / 32, L_), 256, 0, stream>>>(
        wo, wT + 3 * DD, D_, D_, DD, LSTRIDE);
    transpose_bf16_l<<<dim3(FF_ / 32, D_ / 32, L_), 256, 0, stream>>>(
        w1, wT + 4 * DD, D_, FF_, DF, LSTRIDE);
    transpose_bf16_l<<<dim3(D_ / 32, FF_ / 32, L_), 256, 0, stream>>>(
        w2, wT + 4 * DD + DF, FF_, D_, DF, LSTRIDE);
    biascat<<<(L_ * QKVSTR) / 256, 256, 0, stream>>>(bq, bk, bv, qkvbias);

    pe_kernel<<<(S_ * D_ + 255) / 256, 256, 0, stream>>>(pe);
    embed_kernel<<<M, 256, 0, stream>>>(tokens, emb, pe, xb);

    for (int l = 0; l < L_; l++) {
        __hip_bfloat16* wl_base = wT + (size_t)l * LSTRIDE;
        const ushort* qkvT = (const ushort*)(wl_base + 0 * DD);
        const ushort* woT  = (const ushort*)(wl_base + 3 * DD);
        const ushort* w1T  = (const ushort*)(wl_base + 4 * DD);
        const ushort* w2T  = (const ushort*)(wl_base + 4 * DD + DF);

        gemm256<0><<<dim3((QKVSTR / 256) * (M / 256)), 512, 0, stream>>>(
            (const ushort*)xb, qkvT, qkvbias + (size_t)l * QKVSTR, qkv_bf,
            M, QKVSTR, D_, QKVSTR / 256);

        attn_mfma<<<dim3(S_ / 128, H_, B_), 256, 0, stream>>>(
            (const ushort*)qkv_bf, av_bf);

        gemm256<0><<<dim3((D_ / 256) * (M / 256)), 512, 0, stream>>>(
            (const ushort*)av_bf, woT, bo + l * D_, r_bf, M, D_, D_, D_ / 256);
        add_ln<<<M, 256, 0, stream>>>(xb, r_bf, ln1g + l * D_, ln1b + l * D_);

        gemm256<1><<<dim3((FF_ / 256) * (M / 256)), 512, 0, stream>>>(
            (const ushort*)xb, w1T, b1 + l * FF_, h_bf, M, FF_, D_, FF_ / 256);
        gemm256<0><<<dim3((D_ / 256) * (M / 256)), 512, 0, stream>>>(
            (const ushort*)h_bf, w2T, b2 + l * D_, r_bf, M, D_, FF_, D_ / 256);
        add_ln<<<M, 256, 0, stream>>>(xb, r_bf, ln2g + l * D_, ln2b + l * D_);
    }

    pool_kernel<<<(B_ * D_) / 256, 256, 0, stream>>>(xb, pooled);
    head_kernel<<<B_, 64, 0, stream>>>(pooled, wl, bl, wout, bout, out);
}